// Round 2
// baseline (5065.712 us; speedup 1.0000x reference)
//
#include <hip/hip_runtime.h>
#include <hip/hip_bf16.h>
#include <cstdint>
#include <cstddef>

#define INVS 0.99999500003749968f  // 1/sqrt(1+1e-5)
#define G_GRAPHS 256

using bf16 = __hip_bfloat16;

// ---------- helpers ----------
__device__ __forceinline__ float ldv(const float* p, long long i) { return p[i]; }
__device__ __forceinline__ float ldv(const bf16* p, long long i) { return __bfloat162float(p[i]); }
__device__ __forceinline__ void stv(float* p, long long i, float v) { p[i] = v; }
__device__ __forceinline__ void stv(bf16* p, long long i, float v) { p[i] = __float2bfloat16(v); }

__device__ __forceinline__ unsigned fenc(float f) {
    unsigned b = __float_as_uint(f);
    return (b & 0x80000000u) ? ~b : (b | 0x80000000u);
}
__device__ __forceinline__ float fdec(unsigned u) {
    unsigned b = (u & 0x80000000u) ? (u & 0x7fffffffu) : ~u;
    return __uint_as_float(b);
}

// ---------- Edge MLP 1: in=144 (x[s]64 | x[d]64 | ea16), h=64 relu, out=128 (bf16) ----------
__global__ void edge_mlp1_k(const float* __restrict__ x, const float* __restrict__ ea,
                            const int* __restrict__ src, const int* __restrict__ dst,
                            const float* __restrict__ w1, const float* __restrict__ b1,
                            const float* __restrict__ w2, const float* __restrict__ b2,
                            bf16* __restrict__ out, int E) {
    __shared__ float in[4][144];
    __shared__ float h[4][64];
    int t = threadIdx.x;
    int le = t >> 6, lane = t & 63;
    long long e = (long long)blockIdx.x * 4 + le;
    bool ok = e < E;
    int s = ok ? src[e] : 0, d = ok ? dst[e] : 0;
    in[le][lane]      = ok ? x[(long long)s * 64 + lane] : 0.f;
    in[le][64 + lane] = ok ? x[(long long)d * 64 + lane] : 0.f;
    if (lane < 16) in[le][128 + lane] = ok ? ea[e * 16 + lane] : 0.f;
    __syncthreads();
    float acc = b1[lane];
    for (int k = 0; k < 144; ++k) acc += in[le][k] * w1[k * 64 + lane];
    h[le][lane] = fmaxf(acc, 0.f);
    __syncthreads();
    float a0 = b2[lane], a1 = b2[64 + lane];
    for (int k = 0; k < 64; ++k) {
        float hv = h[le][k];
        a0 += hv * w2[k * 128 + lane];
        a1 += hv * w2[k * 128 + 64 + lane];
    }
    if (ok) {
        stv(out, e * 128 + lane, a0);
        stv(out, e * 128 + 64 + lane, a1);
    }
}

// ---------- degree count ----------
__global__ void deg_count_k(const int* __restrict__ dst, float* __restrict__ deg, int E) {
    int gid = blockIdx.x * 256 + threadIdx.x;
    if (gid < E) atomicAdd(&deg[dst[gid]], 1.f);
}

// ---------- loop_ea accumulation: acc[dst] += ea[e]  (128 ch) ----------
__global__ void loop_accum_k(const bf16* __restrict__ ea, const int* __restrict__ dst,
                             float* __restrict__ acc, int E) {
    long long gid = (long long)blockIdx.x * 256 + threadIdx.x;
    if (gid >= (long long)E * 128) return;
    long long e = gid >> 7;
    atomicAdd(&acc[(long long)dst[e] * 128 + (gid & 127)], ldv(ea, gid));
}

__global__ void loop_div_k(float* __restrict__ acc, const float* __restrict__ deg, int N) {
    long long gid = (long long)blockIdx.x * 256 + threadIdx.x;
    if (gid >= (long long)N * 128) return;
    acc[gid] /= fmaxf(deg[gid >> 7], 1.f);
}

// ---------- node linear: xl = x@wl+bl, xr = x@wr+br  (out 256 ch, bf16), 4 nodes/block ----------
template <int K, typename T>
__global__ void node_linear_k(const T* __restrict__ x,
                              const float* __restrict__ wl, const float* __restrict__ bl,
                              const float* __restrict__ wr, const float* __restrict__ br,
                              bf16* __restrict__ xl, bf16* __restrict__ xr, int N) {
    __shared__ float xs[4][K];
    int t = threadIdx.x;
    long long n0 = (long long)blockIdx.x * 4;
    for (int i = t; i < 4 * K; i += 256) {
        int ln = i / K, k = i % K;
        long long n = n0 + ln;
        xs[ln][k] = (n < N) ? ldv(x, n * K + k) : 0.f;
    }
    __syncthreads();
    float accl[4], accr[4];
    float blv = bl[t], brv = br[t];
    for (int i = 0; i < 4; ++i) { accl[i] = blv; accr[i] = brv; }
    for (int k = 0; k < K; ++k) {
        float wlv = wl[k * 256 + t], wrv = wr[k * 256 + t];
        for (int i = 0; i < 4; ++i) { accl[i] += xs[i][k] * wlv; accr[i] += xs[i][k] * wrv; }
    }
    for (int i = 0; i < 4; ++i) {
        long long n = n0 + i;
        if (n < N) { stv(xl, n * 256 + t, accl[i]); stv(xr, n * 256 + t, accr[i]); }
    }
}

// ---------- GATv2 attention logits + segment max. 4 edges/block. ----------
__global__ void gat_logits_k(const bf16* __restrict__ ea_e, const float* __restrict__ loop_ea,
                             const bf16* __restrict__ xl, const bf16* __restrict__ xr,
                             const int* __restrict__ src, const int* __restrict__ dst,
                             const float* __restrict__ ew, const float* __restrict__ att,
                             float* __restrict__ alog, unsigned* __restrict__ amax,
                             int E, int NT) {
    __shared__ float eav[4][128];
    __shared__ int sd[4][2];
    int t = threadIdx.x;
    long long e0 = (long long)blockIdx.x * 4;
    for (int i = t; i < 4 * 128; i += 256) {
        int le = i >> 7, c = i & 127;
        long long e = e0 + le;
        float v = 0.f;
        if (e < NT) v = (e < E) ? ldv(ea_e, e * 128 + c) : loop_ea[(e - E) * 128 + c];
        eav[le][c] = v;
    }
    if (t < 4) {
        long long e = e0 + t;
        int s = 0, d = 0;
        if (e < NT) {
            if (e < E) { s = src[e]; d = dst[e]; }
            else { s = d = (int)(e - E); }
        }
        sd[t][0] = s; sd[t][1] = d;
    }
    __syncthreads();
    float ee0 = 0.f, ee1 = 0.f, ee2 = 0.f, ee3 = 0.f;
    for (int k = 0; k < 128; ++k) {
        float w = ew[k * 256 + t];
        ee0 += eav[0][k] * w; ee1 += eav[1][k] * w; ee2 += eav[2][k] * w; ee3 += eav[3][k] * w;
    }
    float av = att[t];  // att is (4,64) flat; t = h*64+c exactly
    int h = t >> 6;
    float ees[4] = {ee0, ee1, ee2, ee3};
    for (int i = 0; i < 4; ++i) {
        long long e = e0 + i;
        if (e >= NT) break;
        int s = sd[i][0], d = sd[i][1];
        float m = ldv(xl, (long long)s * 256 + t) + ldv(xr, (long long)d * 256 + t) + ees[i];
        m = m > 0.f ? m : 0.2f * m;
        float p = m * av;
        for (int off = 32; off; off >>= 1) p += __shfl_down(p, off, 64);
        if ((t & 63) == 0) {
            alog[e * 4 + h] = p;
            atomicMax(&amax[(long long)d * 4 + h], fenc(p));
        }
    }
}

// ---------- softmax accumulation: num[d] += exp(a-amax)*xl[s], den[d][h] += exp ----------
__global__ void gat_accum_k(const float* __restrict__ alog, const unsigned* __restrict__ amax,
                            const bf16* __restrict__ xl,
                            const int* __restrict__ src, const int* __restrict__ dst,
                            float* __restrict__ den, float* __restrict__ num, int E, int NT) {
    long long gid = (long long)blockIdx.x * 256 + threadIdx.x;
    if (gid >= (long long)NT * 256) return;
    long long e = gid >> 8;
    int t = (int)(gid & 255), h = t >> 6;
    int s, d;
    if (e < E) { s = src[e]; d = dst[e]; }
    else { s = d = (int)(e - E); }
    float a = alog[e * 4 + h];
    float ex = expf(a - fdec(amax[(long long)d * 4 + h]));
    atomicAdd(&num[(long long)d * 256 + t], ex * ldv(xl, (long long)s * 256 + t));
    if ((t & 63) == 0) atomicAdd(&den[(long long)d * 4 + h], ex);
}

// ---------- finalize layer1: xn=relu(num/den+bias); pool; x1bn = BN(xn) (bf16) ----------
__global__ void finalize1_k(const float* __restrict__ num, const float* __restrict__ den,
                            const float* __restrict__ bias,
                            const float* __restrict__ bng, const float* __restrict__ bnb,
                            const int* __restrict__ batch,
                            bf16* __restrict__ x1bn, float* __restrict__ pooled, int N) {
    long long gid = (long long)blockIdx.x * 256 + threadIdx.x;
    if (gid >= (long long)N * 256) return;
    long long n = gid >> 8;
    int t = (int)(gid & 255);
    float xn = fmaxf(num[gid] / den[n * 4 + (t >> 6)] + bias[t], 0.f);
    atomicAdd(&pooled[(long long)batch[n] * 256 + t], xn);
    stv(x1bn, gid, bng[t] * (xn * INVS) + bnb[t]);
}

// ---------- finalize layer2: pool only ----------
__global__ void finalize2_k(const float* __restrict__ num, const float* __restrict__ den,
                            const float* __restrict__ bias, const int* __restrict__ batch,
                            float* __restrict__ pooled, int N) {
    long long gid = (long long)blockIdx.x * 256 + threadIdx.x;
    if (gid >= (long long)N * 256) return;
    long long n = gid >> 8;
    int t = (int)(gid & 255);
    float xn = fmaxf(num[gid] / den[n * 4 + (t >> 6)] + bias[t], 0.f);
    atomicAdd(&pooled[(long long)batch[n] * 256 + t], xn);
}

// ---------- global MLP layer1 (u0 = 0): u1bn = BN(mlp(pooled part)) ----------
__global__ void global_mlp1_k(const float* __restrict__ pooled,
                              const float* __restrict__ w1, const float* __restrict__ b1,
                              const float* __restrict__ w2, const float* __restrict__ b2,
                              const float* __restrict__ bng, const float* __restrict__ bnb,
                              float* __restrict__ u1bn) {
    __shared__ float pr[256];
    __shared__ float h[256];
    int t = threadIdx.x, g = blockIdx.x;
    pr[t] = pooled[g * 256 + t];
    __syncthreads();
    float acc = b1[t];
    for (int k = 0; k < 256; ++k) acc += pr[k] * w1[(256 + k) * 256 + t];
    h[t] = fmaxf(acc, 0.f);
    __syncthreads();
    float a2 = b2[t];
    for (int k = 0; k < 256; ++k) a2 += h[k] * w2[k * 256 + t];
    u1bn[g * 256 + t] = bng[t] * (a2 * INVS) + bnb[t];
}

// ---------- Edge MLP 2: in=640 (x1bn[s]256 | x1bn[d]256 | BN(ea1)128), h=128, out=128 ----------
// 8 edges per 256-thread block; out aliases ea1 (read-then-write within block only).
__global__ void edge_mlp2_k(const bf16* __restrict__ xb, const bf16* __restrict__ ea1,
                            const float* __restrict__ bg, const float* __restrict__ bb,
                            const int* __restrict__ src, const int* __restrict__ dst,
                            const float* __restrict__ w1, const float* __restrict__ b1,
                            const float* __restrict__ w2, const float* __restrict__ b2,
                            bf16* __restrict__ out, int E) {
    __shared__ float in[8][640];
    __shared__ float h[8][128];
    __shared__ int sd[8][2];
    int t = threadIdx.x;
    long long e0 = (long long)blockIdx.x * 8;
    if (t < 8) {
        long long e = e0 + t;
        sd[t][0] = (e < E) ? src[e] : 0;
        sd[t][1] = (e < E) ? dst[e] : 0;
    }
    __syncthreads();
    for (int i = t; i < 8 * 640; i += 256) {
        int le = i / 640, k = i % 640;
        long long e = e0 + le;
        float v = 0.f;
        if (e < E) {
            if (k < 256) v = ldv(xb, (long long)sd[le][0] * 256 + k);
            else if (k < 512) v = ldv(xb, (long long)sd[le][1] * 256 + (k - 256));
            else {
                int c = k - 512;
                v = bg[c] * (ldv(ea1, e * 128 + c) * INVS) + bb[c];
            }
        }
        in[le][k] = v;
    }
    __syncthreads();
    int j = t & 127, half = t >> 7;
    float acc0 = b1[j], acc1 = acc0, acc2 = acc0, acc3 = acc0;
    for (int k = 0; k < 640; ++k) {
        float w = w1[k * 128 + j];
        acc0 += in[half][k] * w;
        acc1 += in[half + 2][k] * w;
        acc2 += in[half + 4][k] * w;
        acc3 += in[half + 6][k] * w;
    }
    h[half][j]     = fmaxf(acc0, 0.f);
    h[half + 2][j] = fmaxf(acc1, 0.f);
    h[half + 4][j] = fmaxf(acc2, 0.f);
    h[half + 6][j] = fmaxf(acc3, 0.f);
    __syncthreads();
    float o0 = b2[j], o1 = o0, o2 = o0, o3 = o0;
    for (int k = 0; k < 128; ++k) {
        float w = w2[k * 128 + j];
        o0 += h[half][k] * w;
        o1 += h[half + 2][k] * w;
        o2 += h[half + 4][k] * w;
        o3 += h[half + 6][k] * w;
    }
    float os[4] = {o0, o1, o2, o3};
    for (int i = 0; i < 4; ++i) {
        long long e = e0 + half + 2 * i;
        if (e < E) stv(out, e * 128 + j, os[i]);
    }
}

// ---------- final: u2 = mlp([u1bn,pooled2]); h=relu(u2@fc1+b); out = h@fc2+b ----------
__global__ void final_mlp_k(const float* __restrict__ u1bn, const float* __restrict__ pooled,
                            const float* __restrict__ w1, const float* __restrict__ b1,
                            const float* __restrict__ w2, const float* __restrict__ b2,
                            const float* __restrict__ f1w, const float* __restrict__ f1b,
                            const float* __restrict__ f2w, const float* __restrict__ f2b,
                            float* __restrict__ out) {
    __shared__ float ub[256], pb[256], h[256], u2[256];
    int t = threadIdx.x, g = blockIdx.x;
    ub[t] = u1bn[g * 256 + t];
    pb[t] = pooled[g * 256 + t];
    __syncthreads();
    float acc = b1[t];
    for (int k = 0; k < 256; ++k)
        acc += ub[k] * w1[k * 256 + t] + pb[k] * w1[(256 + k) * 256 + t];
    h[t] = fmaxf(acc, 0.f);
    __syncthreads();
    float a2 = b2[t];
    for (int k = 0; k < 256; ++k) a2 += h[k] * w2[k * 256 + t];
    u2[t] = a2;
    __syncthreads();
    float fv = 0.f;
    if (t < 64) {
        float a3 = f1b[t];
        for (int k = 0; k < 256; ++k) a3 += u2[k] * f1w[k * 64 + t];
        fv = fmaxf(a3, 0.f) * f2w[t];
    }
    for (int off = 32; off; off >>= 1) fv += __shfl_down(fv, off, 64);
    if (t == 0) out[g] = fv + f2b[0];
}

// ---------- launch ----------
extern "C" void kernel_launch(void* const* d_in, const int* in_sizes, int n_in,
                              void* d_out, int out_size, void* d_ws, size_t ws_size,
                              hipStream_t stream) {
    const float* x         = (const float*)d_in[0];
    const float* edge_attr = (const float*)d_in[1];
    const float* e1_w1 = (const float*)d_in[2];
    const float* e1_b1 = (const float*)d_in[3];
    const float* e1_w2 = (const float*)d_in[4];
    const float* e1_b2 = (const float*)d_in[5];
    const float* g1_lw = (const float*)d_in[6];
    const float* g1_lb = (const float*)d_in[7];
    const float* g1_rw = (const float*)d_in[8];
    const float* g1_rb = (const float*)d_in[9];
    const float* g1_ew = (const float*)d_in[10];
    const float* g1_att = (const float*)d_in[11];
    const float* g1_bias = (const float*)d_in[12];
    const float* u1_w1 = (const float*)d_in[13];
    const float* u1_b1 = (const float*)d_in[14];
    const float* u1_w2 = (const float*)d_in[15];
    const float* u1_b2 = (const float*)d_in[16];
    const float* bn_n_g = (const float*)d_in[17];
    const float* bn_n_b = (const float*)d_in[18];
    const float* bn_e_g = (const float*)d_in[19];
    const float* bn_e_b = (const float*)d_in[20];
    const float* bn_u_g = (const float*)d_in[21];
    const float* bn_u_b = (const float*)d_in[22];
    const float* e2_w1 = (const float*)d_in[23];
    const float* e2_b1 = (const float*)d_in[24];
    const float* e2_w2 = (const float*)d_in[25];
    const float* e2_b2 = (const float*)d_in[26];
    const float* g2_lw = (const float*)d_in[27];
    const float* g2_lb = (const float*)d_in[28];
    const float* g2_rw = (const float*)d_in[29];
    const float* g2_rb = (const float*)d_in[30];
    const float* g2_ew = (const float*)d_in[31];
    const float* g2_att = (const float*)d_in[32];
    const float* g2_bias = (const float*)d_in[33];
    const float* u2_w1 = (const float*)d_in[34];
    const float* u2_b1 = (const float*)d_in[35];
    const float* u2_w2 = (const float*)d_in[36];
    const float* u2_b2 = (const float*)d_in[37];
    const float* fc1_w = (const float*)d_in[38];
    const float* fc1_b = (const float*)d_in[39];
    const float* fc2_w = (const float*)d_in[40];
    const float* fc2_b = (const float*)d_in[41];
    const int* edge_index = (const int*)d_in[42];
    const int* batch = (const int*)d_in[43];

    const int N = in_sizes[0] / 64;
    const int E = in_sizes[1] / 16;
    const int NT = E + N;
    const int G = G_GRAPHS;
    const int* src = edge_index;
    const int* dst = edge_index + E;

    // workspace carve (~244 MB total)
    char* p = (char*)d_ws;
    auto alloc = [&](size_t bytes) { char* r = p; p += (bytes + 255) & ~(size_t)255; return r; };
    bf16* eabuf = (bf16*)alloc((size_t)E * 128 * 2);   // ea1, overwritten in-place by ea2
    bf16* xl    = (bf16*)alloc((size_t)N * 256 * 2);
    bf16* xr    = (bf16*)alloc((size_t)N * 256 * 2);
    bf16* x1bn  = (bf16*)alloc((size_t)N * 256 * 2);
    float* num  = (float*)alloc((size_t)N * 256 * 4);
    float* loop = (float*)alloc((size_t)N * 128 * 4);
    float* deg  = (float*)alloc((size_t)N * 4);
    float* alog = (float*)alloc((size_t)NT * 4 * 4);
    unsigned* amax = (unsigned*)alloc((size_t)N * 4 * 4);
    float* den  = (float*)alloc((size_t)N * 4 * 4);
    float* pooled = (float*)alloc((size_t)G * 256 * 4);
    float* u1bn = (float*)alloc((size_t)G * 256 * 4);

    // ===== layer 1 =====
    hipMemsetAsync(deg, 0, (size_t)N * 4, stream);
    hipMemsetAsync(loop, 0, (size_t)N * 128 * 4, stream);
    hipMemsetAsync(amax, 0, (size_t)N * 4 * 4, stream);
    hipMemsetAsync(den, 0, (size_t)N * 4 * 4, stream);
    hipMemsetAsync(num, 0, (size_t)N * 256 * 4, stream);
    hipMemsetAsync(pooled, 0, (size_t)G * 256 * 4, stream);

    edge_mlp1_k<<<(E + 3) / 4, 256, 0, stream>>>(x, edge_attr, src, dst,
                                                 e1_w1, e1_b1, e1_w2, e1_b2, eabuf, E);
    deg_count_k<<<(E + 255) / 256, 256, 0, stream>>>(dst, deg, E);
    loop_accum_k<<<(int)(((long long)E * 128 + 255) / 256), 256, 0, stream>>>(eabuf, dst, loop, E);
    loop_div_k<<<(int)(((long long)N * 128 + 255) / 256), 256, 0, stream>>>(loop, deg, N);
    node_linear_k<64, float><<<(N + 3) / 4, 256, 0, stream>>>(x, g1_lw, g1_lb, g1_rw, g1_rb, xl, xr, N);
    gat_logits_k<<<(NT + 3) / 4, 256, 0, stream>>>(eabuf, loop, xl, xr, src, dst,
                                                   g1_ew, g1_att, alog, amax, E, NT);
    gat_accum_k<<<NT, 256, 0, stream>>>(alog, amax, xl, src, dst, den, num, E, NT);
    finalize1_k<<<N, 256, 0, stream>>>(num, den, g1_bias, bn_n_g, bn_n_b, batch, x1bn, pooled, N);
    global_mlp1_k<<<G, 256, 0, stream>>>(pooled, u1_w1, u1_b1, u1_w2, u1_b2, bn_u_g, bn_u_b, u1bn);

    // ===== layer 2 =====
    hipMemsetAsync(loop, 0, (size_t)N * 128 * 4, stream);
    hipMemsetAsync(amax, 0, (size_t)N * 4 * 4, stream);
    hipMemsetAsync(den, 0, (size_t)N * 4 * 4, stream);
    hipMemsetAsync(num, 0, (size_t)N * 256 * 4, stream);

    edge_mlp2_k<<<(E + 7) / 8, 256, 0, stream>>>(x1bn, eabuf, bn_e_g, bn_e_b, src, dst,
                                                 e2_w1, e2_b1, e2_w2, e2_b2, eabuf, E);
    loop_accum_k<<<(int)(((long long)E * 128 + 255) / 256), 256, 0, stream>>>(eabuf, dst, loop, E);
    loop_div_k<<<(int)(((long long)N * 128 + 255) / 256), 256, 0, stream>>>(loop, deg, N);
    node_linear_k<256, bf16><<<(N + 3) / 4, 256, 0, stream>>>(x1bn, g2_lw, g2_lb, g2_rw, g2_rb, xl, xr, N);
    gat_logits_k<<<(NT + 3) / 4, 256, 0, stream>>>(eabuf, loop, xl, xr, src, dst,
                                                   g2_ew, g2_att, alog, amax, E, NT);
    gat_accum_k<<<NT, 256, 0, stream>>>(alog, amax, xl, src, dst, den, num, E, NT);

    // pooled2 reuses `pooled`
    hipMemsetAsync(pooled, 0, (size_t)G * 256 * 4, stream);
    finalize2_k<<<N, 256, 0, stream>>>(num, den, g2_bias, batch, pooled, N);
    final_mlp_k<<<G, 256, 0, stream>>>(u1bn, pooled, u2_w1, u2_b1, u2_w2, u2_b2,
                                       fc1_w, fc1_b, fc2_w, fc2_b, (float*)d_out);
}

// Round 3
// 3924.061 us; speedup vs baseline: 1.2909x; 1.2909x over previous
//
#include <hip/hip_runtime.h>
#include <hip/hip_bf16.h>
#include <cstdint>
#include <cstddef>

#define INVS 0.99999500003749968f  // 1/sqrt(1+1e-5)
#define G_GRAPHS 256

using bf16 = __hip_bfloat16;
using short8 = __attribute__((ext_vector_type(8))) short;
using floatx4 = __attribute__((ext_vector_type(4))) float;

// ---------- helpers ----------
__device__ __forceinline__ float ldv(const float* p, long long i) { return p[i]; }
__device__ __forceinline__ float ldv(const bf16* p, long long i) { return __bfloat162float(p[i]); }
__device__ __forceinline__ void stv(float* p, long long i, float v) { p[i] = v; }
__device__ __forceinline__ void stv(bf16* p, long long i, float v) { p[i] = __float2bfloat16(v); }

__device__ __forceinline__ unsigned short f2bf(float v) {
    union { float f; unsigned u; } x; x.f = v;
    unsigned r = x.u + 0x7fffu + ((x.u >> 16) & 1u);
    return (unsigned short)(r >> 16);
}

__device__ __forceinline__ unsigned fenc(float f) {
    unsigned b = __float_as_uint(f);
    return (b & 0x80000000u) ? ~b : (b | 0x80000000u);
}
__device__ __forceinline__ float fdec(unsigned u) {
    unsigned b = (u & 0x80000000u) ? (u & 0x7fffffffu) : ~u;
    return __uint_as_float(b);
}

// ---------- Edge MLP 1: in=144 (x[s]64 | x[d]64 | ea16), h=64 relu, out=128 (bf16) ----------
__global__ void edge_mlp1_k(const float* __restrict__ x, const float* __restrict__ ea,
                            const int* __restrict__ src, const int* __restrict__ dst,
                            const float* __restrict__ w1, const float* __restrict__ b1,
                            const float* __restrict__ w2, const float* __restrict__ b2,
                            bf16* __restrict__ out, int E) {
    __shared__ float in[4][144];
    __shared__ float h[4][64];
    int t = threadIdx.x;
    int le = t >> 6, lane = t & 63;
    long long e = (long long)blockIdx.x * 4 + le;
    bool ok = e < E;
    int s = ok ? src[e] : 0, d = ok ? dst[e] : 0;
    in[le][lane]      = ok ? x[(long long)s * 64 + lane] : 0.f;
    in[le][64 + lane] = ok ? x[(long long)d * 64 + lane] : 0.f;
    if (lane < 16) in[le][128 + lane] = ok ? ea[e * 16 + lane] : 0.f;
    __syncthreads();
    float acc = b1[lane];
    for (int k = 0; k < 144; ++k) acc += in[le][k] * w1[k * 64 + lane];
    h[le][lane] = fmaxf(acc, 0.f);
    __syncthreads();
    float a0 = b2[lane], a1 = b2[64 + lane];
    for (int k = 0; k < 64; ++k) {
        float hv = h[le][k];
        a0 += hv * w2[k * 128 + lane];
        a1 += hv * w2[k * 128 + 64 + lane];
    }
    if (ok) {
        stv(out, e * 128 + lane, a0);
        stv(out, e * 128 + 64 + lane, a1);
    }
}

// ---------- degree count ----------
__global__ void deg_count_k(const int* __restrict__ dst, float* __restrict__ deg, int E) {
    int gid = blockIdx.x * 256 + threadIdx.x;
    if (gid < E) atomicAdd(&deg[dst[gid]], 1.f);
}

// ---------- loop_ea accumulation: acc[dst] += ea[e]  (128 ch) ----------
__global__ void loop_accum_k(const bf16* __restrict__ ea, const int* __restrict__ dst,
                             float* __restrict__ acc, int E) {
    long long gid = (long long)blockIdx.x * 256 + threadIdx.x;
    if (gid >= (long long)E * 128) return;
    long long e = gid >> 7;
    atomicAdd(&acc[(long long)dst[e] * 128 + (gid & 127)], ldv(ea, gid));
}

__global__ void loop_div_k(float* __restrict__ acc, const float* __restrict__ deg, int N) {
    long long gid = (long long)blockIdx.x * 256 + threadIdx.x;
    if (gid >= (long long)N * 128) return;
    acc[gid] /= fmaxf(deg[gid >> 7], 1.f);
}

// ---------- node linear: xl = x@wl+bl, xr = x@wr+br  (out 256 ch, bf16), 4 nodes/block ----------
template <int K, typename T>
__global__ void node_linear_k(const T* __restrict__ x,
                              const float* __restrict__ wl, const float* __restrict__ bl,
                              const float* __restrict__ wr, const float* __restrict__ br,
                              bf16* __restrict__ xl, bf16* __restrict__ xr, int N) {
    __shared__ float xs[4][K];
    int t = threadIdx.x;
    long long n0 = (long long)blockIdx.x * 4;
    for (int i = t; i < 4 * K; i += 256) {
        int ln = i / K, k = i % K;
        long long n = n0 + ln;
        xs[ln][k] = (n < N) ? ldv(x, n * K + k) : 0.f;
    }
    __syncthreads();
    float accl[4], accr[4];
    float blv = bl[t], brv = br[t];
    for (int i = 0; i < 4; ++i) { accl[i] = blv; accr[i] = brv; }
    for (int k = 0; k < K; ++k) {
        float wlv = wl[k * 256 + t], wrv = wr[k * 256 + t];
        for (int i = 0; i < 4; ++i) { accl[i] += xs[i][k] * wlv; accr[i] += xs[i][k] * wrv; }
    }
    for (int i = 0; i < 4; ++i) {
        long long n = n0 + i;
        if (n < N) { stv(xl, n * 256 + t, accl[i]); stv(xr, n * 256 + t, accr[i]); }
    }
}

// ---------- GATv2 attention logits + segment max. 4 edges/block. ----------
__global__ void gat_logits_k(const bf16* __restrict__ ea_e, const float* __restrict__ loop_ea,
                             const bf16* __restrict__ xl, const bf16* __restrict__ xr,
                             const int* __restrict__ src, const int* __restrict__ dst,
                             const float* __restrict__ ew, const float* __restrict__ att,
                             float* __restrict__ alog, unsigned* __restrict__ amax,
                             int E, int NT) {
    __shared__ float eav[4][128];
    __shared__ int sd[4][2];
    int t = threadIdx.x;
    long long e0 = (long long)blockIdx.x * 4;
    for (int i = t; i < 4 * 128; i += 256) {
        int le = i >> 7, c = i & 127;
        long long e = e0 + le;
        float v = 0.f;
        if (e < NT) v = (e < E) ? ldv(ea_e, e * 128 + c) : loop_ea[(e - E) * 128 + c];
        eav[le][c] = v;
    }
    if (t < 4) {
        long long e = e0 + t;
        int s = 0, d = 0;
        if (e < NT) {
            if (e < E) { s = src[e]; d = dst[e]; }
            else { s = d = (int)(e - E); }
        }
        sd[t][0] = s; sd[t][1] = d;
    }
    __syncthreads();
    float ee0 = 0.f, ee1 = 0.f, ee2 = 0.f, ee3 = 0.f;
    for (int k = 0; k < 128; ++k) {
        float w = ew[k * 256 + t];
        ee0 += eav[0][k] * w; ee1 += eav[1][k] * w; ee2 += eav[2][k] * w; ee3 += eav[3][k] * w;
    }
    float av = att[t];  // att is (4,64) flat; t = h*64+c exactly
    int h = t >> 6;
    float ees[4] = {ee0, ee1, ee2, ee3};
    for (int i = 0; i < 4; ++i) {
        long long e = e0 + i;
        if (e >= NT) break;
        int s = sd[i][0], d = sd[i][1];
        float m = ldv(xl, (long long)s * 256 + t) + ldv(xr, (long long)d * 256 + t) + ees[i];
        m = m > 0.f ? m : 0.2f * m;
        float p = m * av;
        for (int off = 32; off; off >>= 1) p += __shfl_down(p, off, 64);
        if ((t & 63) == 0) {
            alog[e * 4 + h] = p;
            atomicMax(&amax[(long long)d * 4 + h], fenc(p));
        }
    }
}

// ---------- softmax accumulation: num[d] += exp(a-amax)*xl[s], den[d][h] += exp ----------
__global__ void gat_accum_k(const float* __restrict__ alog, const unsigned* __restrict__ amax,
                            const bf16* __restrict__ xl,
                            const int* __restrict__ src, const int* __restrict__ dst,
                            float* __restrict__ den, float* __restrict__ num, int E, int NT) {
    long long gid = (long long)blockIdx.x * 256 + threadIdx.x;
    if (gid >= (long long)NT * 256) return;
    long long e = gid >> 8;
    int t = (int)(gid & 255), h = t >> 6;
    int s, d;
    if (e < E) { s = src[e]; d = dst[e]; }
    else { s = d = (int)(e - E); }
    float a = alog[e * 4 + h];
    float ex = expf(a - fdec(amax[(long long)d * 4 + h]));
    atomicAdd(&num[(long long)d * 256 + t], ex * ldv(xl, (long long)s * 256 + t));
    if ((t & 63) == 0) atomicAdd(&den[(long long)d * 4 + h], ex);
}

// ---------- finalize layer1: xn=relu(num/den+bias); pool; x1bn = BN(xn) (bf16) ----------
__global__ void finalize1_k(const float* __restrict__ num, const float* __restrict__ den,
                            const float* __restrict__ bias,
                            const float* __restrict__ bng, const float* __restrict__ bnb,
                            const int* __restrict__ batch,
                            bf16* __restrict__ x1bn, float* __restrict__ pooled, int N) {
    long long gid = (long long)blockIdx.x * 256 + threadIdx.x;
    if (gid >= (long long)N * 256) return;
    long long n = gid >> 8;
    int t = (int)(gid & 255);
    float xn = fmaxf(num[gid] / den[n * 4 + (t >> 6)] + bias[t], 0.f);
    atomicAdd(&pooled[(long long)batch[n] * 256 + t], xn);
    stv(x1bn, gid, bng[t] * (xn * INVS) + bnb[t]);
}

// ---------- finalize layer2: pool only ----------
__global__ void finalize2_k(const float* __restrict__ num, const float* __restrict__ den,
                            const float* __restrict__ bias, const int* __restrict__ batch,
                            float* __restrict__ pooled, int N) {
    long long gid = (long long)blockIdx.x * 256 + threadIdx.x;
    if (gid >= (long long)N * 256) return;
    long long n = gid >> 8;
    int t = (int)(gid & 255);
    float xn = fmaxf(num[gid] / den[n * 4 + (t >> 6)] + bias[t], 0.f);
    atomicAdd(&pooled[(long long)batch[n] * 256 + t], xn);
}

// ---------- global MLP layer1 (u0 = 0): u1bn = BN(mlp(pooled part)) ----------
__global__ void global_mlp1_k(const float* __restrict__ pooled,
                              const float* __restrict__ w1, const float* __restrict__ b1,
                              const float* __restrict__ w2, const float* __restrict__ b2,
                              const float* __restrict__ bng, const float* __restrict__ bnb,
                              float* __restrict__ u1bn) {
    __shared__ float pr[256];
    __shared__ float h[256];
    int t = threadIdx.x, g = blockIdx.x;
    pr[t] = pooled[g * 256 + t];
    __syncthreads();
    float acc = b1[t];
    for (int k = 0; k < 256; ++k) acc += pr[k] * w1[(256 + k) * 256 + t];
    h[t] = fmaxf(acc, 0.f);
    __syncthreads();
    float a2 = b2[t];
    for (int k = 0; k < 256; ++k) a2 += h[k] * w2[k * 256 + t];
    u1bn[g * 256 + t] = bng[t] * (a2 * INVS) + bnb[t];
}

// ---------- weight prep for MFMA edge MLP2 ----------
// w1s: fragment-major bf16 of w1[640][128] with BN scale folded into rows 512..639.
// w2s: fragment-major bf16 of w2[128][128].
// b1f: b1 + sum_c bb[c]*w1[512+c][:].
// Fragment (kk,tt): lane l, j -> W[kk*32 + (l>>4)*8 + j][tt*16 + (l&15)], stored at ((kk*8+tt)*64+l)*8+j.
__global__ void conv_weights_k(const float* __restrict__ w1, const float* __restrict__ w2,
                               const float* __restrict__ b1,
                               const float* __restrict__ bg, const float* __restrict__ bb,
                               short* __restrict__ w1s, short* __restrict__ w2s,
                               float* __restrict__ b1f) {
    int gid = blockIdx.x * 256 + threadIdx.x;
    if (gid < 10240) {  // w1: 20 kk * 8 tt * 64 lanes
        int f = gid >> 6, lane = gid & 63;
        int kk = f >> 3, tt = f & 7;
        int n = tt * 16 + (lane & 15);
        int k0 = kk * 32 + (lane >> 4) * 8;
        short8 v;
        for (int j = 0; j < 8; ++j) {
            int k = k0 + j;
            float x = w1[k * 128 + n];
            if (k >= 512) x *= bg[k - 512] * INVS;
            v[j] = (short)f2bf(x);
        }
        *(short8*)(w1s + (long long)gid * 8) = v;
    } else if (gid < 12288) {  // w2: 4 kk * 8 tt * 64 lanes
        int g2 = gid - 10240;
        int f = g2 >> 6, lane = g2 & 63;
        int kk = f >> 3, tt = f & 7;
        int n = tt * 16 + (lane & 15);
        int k0 = kk * 32 + (lane >> 4) * 8;
        short8 v;
        for (int j = 0; j < 8; ++j) v[j] = (short)f2bf(w2[(k0 + j) * 128 + n]);
        *(short8*)(w2s + (long long)g2 * 8) = v;
    } else if (gid < 12416) {  // b1f: 128 threads
        int j = gid - 12288;
        float acc = b1[j];
        for (int c = 0; c < 128; ++c) acc += bb[c] * w1[(512 + c) * 128 + j];
        b1f[j] = acc;
    }
}

// ---------- Edge MLP 2 via MFMA: [E x 640] @ [640 x 128] relu @ [128 x 128] ----------
// 32 edges / block, 4 waves; wave w: rows (w&1)*16.., cols (w>>1)*64.. (4 n-tiles of 16).
// In-place: out aliases ea1 (each block reads its own edges' ea1 before writing).
__global__ __launch_bounds__(256) void edge_mlp2_mfma_k(
    const bf16* __restrict__ xb, const bf16* __restrict__ ea1,
    const int* __restrict__ src, const int* __restrict__ dst,
    const short* __restrict__ w1s, const float* __restrict__ b1f,
    const short* __restrict__ w2s, const float* __restrict__ b2,
    bf16* __restrict__ out, int E) {
    __shared__ short At[32][648];   // A-tile (pad 640->648: 2-way-only LDS aliasing); reused as out-tile
    __shared__ short Ht[32][136];   // hidden tile bf16 (pad 128->136)
    __shared__ int sdv[32][2];
    int t = threadIdx.x;
    long long e0 = (long long)blockIdx.x * 32;
    if (t < 64) {
        int r = t & 31;
        long long e = e0 + r;
        int v = 0;
        if (e < E) v = (t < 32) ? src[e] : dst[e];
        sdv[r][t >> 5] = v;
    }
    __syncthreads();
    // stage A: 32 rows x 80 chunks of 8 bf16 (x1bn[s] | x1bn[d] | ea1[e])
    for (int i = t; i < 32 * 80; i += 256) {
        int r = i / 80, c = i - r * 80;
        long long e = e0 + r;
        short8 v = {0, 0, 0, 0, 0, 0, 0, 0};
        if (e < E) {
            if (c < 32)      v = *(const short8*)(const void*)(xb + (long long)sdv[r][0] * 256 + c * 8);
            else if (c < 64) v = *(const short8*)(const void*)(xb + (long long)sdv[r][1] * 256 + (c - 32) * 8);
            else             v = *(const short8*)(const void*)(ea1 + e * 128 + (c - 64) * 8);
        }
        *(short8*)&At[r][c * 8] = v;
    }
    __syncthreads();

    int w = t >> 6, lane = t & 63;
    int m0 = (w & 1) * 16;
    int nq = (w >> 1) * 4;          // first n-tile index (of 8)
    int lr = lane & 15, lq = lane >> 4;

    floatx4 acc[4];
    for (int i = 0; i < 4; ++i) acc[i] = (floatx4){0.f, 0.f, 0.f, 0.f};
    for (int kk = 0; kk < 20; ++kk) {
        short8 a = *(const short8*)&At[m0 + lr][kk * 32 + lq * 8];
        for (int tt = 0; tt < 4; ++tt) {
            short8 b = *(const short8*)(w1s + ((long long)((kk * 8 + nq + tt) * 64 + lane)) * 8);
            acc[tt] = __builtin_amdgcn_mfma_f32_16x16x32_bf16(a, b, acc[tt], 0, 0, 0);
        }
    }
    // bias + relu -> Ht (C/D layout: col=lane&15, row=lq*4+reg)
    for (int tt = 0; tt < 4; ++tt) {
        int col = (nq + tt) * 16 + lr;
        float bv = b1f[col];
        for (int r = 0; r < 4; ++r)
            Ht[m0 + lq * 4 + r][col] = (short)f2bf(fmaxf(acc[tt][r] + bv, 0.f));
    }
    __syncthreads();

    floatx4 acc2[4];
    for (int i = 0; i < 4; ++i) acc2[i] = (floatx4){0.f, 0.f, 0.f, 0.f};
    for (int kk = 0; kk < 4; ++kk) {
        short8 a = *(const short8*)&Ht[m0 + lr][kk * 32 + lq * 8];
        for (int tt = 0; tt < 4; ++tt) {
            short8 b = *(const short8*)(w2s + ((long long)((kk * 8 + nq + tt) * 64 + lane)) * 8);
            acc2[tt] = __builtin_amdgcn_mfma_f32_16x16x32_bf16(a, b, acc2[tt], 0, 0, 0);
        }
    }
    // + b2 -> out-tile in At (cols 0..127, row stride 648)
    for (int tt = 0; tt < 4; ++tt) {
        int col = (nq + tt) * 16 + lr;
        float bv = b2[col];
        for (int r = 0; r < 4; ++r)
            At[m0 + lq * 4 + r][col] = (short)f2bf(acc2[tt][r] + bv);
    }
    __syncthreads();
    // cooperative coalesced store: 32 rows x 16 chunks of 8 bf16
    for (int i = t; i < 512; i += 256) {
        int r = i >> 4, c = i & 15;
        long long e = e0 + r;
        if (e < E) *(short8*)(void*)(out + e * 128 + c * 8) = *(const short8*)&At[r][c * 8];
    }
}

// ---------- final: u2 = mlp([u1bn,pooled2]); h=relu(u2@fc1+b); out = h@fc2+b ----------
__global__ void final_mlp_k(const float* __restrict__ u1bn, const float* __restrict__ pooled,
                            const float* __restrict__ w1, const float* __restrict__ b1,
                            const float* __restrict__ w2, const float* __restrict__ b2,
                            const float* __restrict__ f1w, const float* __restrict__ f1b,
                            const float* __restrict__ f2w, const float* __restrict__ f2b,
                            float* __restrict__ out) {
    __shared__ float ub[256], pb[256], h[256], u2[256];
    int t = threadIdx.x, g = blockIdx.x;
    ub[t] = u1bn[g * 256 + t];
    pb[t] = pooled[g * 256 + t];
    __syncthreads();
    float acc = b1[t];
    for (int k = 0; k < 256; ++k)
        acc += ub[k] * w1[k * 256 + t] + pb[k] * w1[(256 + k) * 256 + t];
    h[t] = fmaxf(acc, 0.f);
    __syncthreads();
    float a2 = b2[t];
    for (int k = 0; k < 256; ++k) a2 += h[k] * w2[k * 256 + t];
    u2[t] = a2;
    __syncthreads();
    float fv = 0.f;
    if (t < 64) {
        float a3 = f1b[t];
        for (int k = 0; k < 256; ++k) a3 += u2[k] * f1w[k * 64 + t];
        fv = fmaxf(a3, 0.f) * f2w[t];
    }
    for (int off = 32; off; off >>= 1) fv += __shfl_down(fv, off, 64);
    if (t == 0) out[g] = fv + f2b[0];
}

// ---------- launch ----------
extern "C" void kernel_launch(void* const* d_in, const int* in_sizes, int n_in,
                              void* d_out, int out_size, void* d_ws, size_t ws_size,
                              hipStream_t stream) {
    const float* x         = (const float*)d_in[0];
    const float* edge_attr = (const float*)d_in[1];
    const float* e1_w1 = (const float*)d_in[2];
    const float* e1_b1 = (const float*)d_in[3];
    const float* e1_w2 = (const float*)d_in[4];
    const float* e1_b2 = (const float*)d_in[5];
    const float* g1_lw = (const float*)d_in[6];
    const float* g1_lb = (const float*)d_in[7];
    const float* g1_rw = (const float*)d_in[8];
    const float* g1_rb = (const float*)d_in[9];
    const float* g1_ew = (const float*)d_in[10];
    const float* g1_att = (const float*)d_in[11];
    const float* g1_bias = (const float*)d_in[12];
    const float* u1_w1 = (const float*)d_in[13];
    const float* u1_b1 = (const float*)d_in[14];
    const float* u1_w2 = (const float*)d_in[15];
    const float* u1_b2 = (const float*)d_in[16];
    const float* bn_n_g = (const float*)d_in[17];
    const float* bn_n_b = (const float*)d_in[18];
    const float* bn_e_g = (const float*)d_in[19];
    const float* bn_e_b = (const float*)d_in[20];
    const float* bn_u_g = (const float*)d_in[21];
    const float* bn_u_b = (const float*)d_in[22];
    const float* e2_w1 = (const float*)d_in[23];
    const float* e2_b1 = (const float*)d_in[24];
    const float* e2_w2 = (const float*)d_in[25];
    const float* e2_b2 = (const float*)d_in[26];
    const float* g2_lw = (const float*)d_in[27];
    const float* g2_lb = (const float*)d_in[28];
    const float* g2_rw = (const float*)d_in[29];
    const float* g2_rb = (const float*)d_in[30];
    const float* g2_ew = (const float*)d_in[31];
    const float* g2_att = (const float*)d_in[32];
    const float* g2_bias = (const float*)d_in[33];
    const float* u2_w1 = (const float*)d_in[34];
    const float* u2_b1 = (const float*)d_in[35];
    const float* u2_w2 = (const float*)d_in[36];
    const float* u2_b2 = (const float*)d_in[37];
    const float* fc1_w = (const float*)d_in[38];
    const float* fc1_b = (const float*)d_in[39];
    const float* fc2_w = (const float*)d_in[40];
    const float* fc2_b = (const float*)d_in[41];
    const int* edge_index = (const int*)d_in[42];
    const int* batch = (const int*)d_in[43];

    const int N = in_sizes[0] / 64;
    const int E = in_sizes[1] / 16;
    const int NT = E + N;
    const int G = G_GRAPHS;
    const int* src = edge_index;
    const int* dst = edge_index + E;

    // workspace carve (~244 MB total)
    char* p = (char*)d_ws;
    auto alloc = [&](size_t bytes) { char* r = p; p += (bytes + 255) & ~(size_t)255; return r; };
    bf16* eabuf = (bf16*)alloc((size_t)E * 128 * 2);   // ea1, overwritten in-place by ea2
    bf16* xl    = (bf16*)alloc((size_t)N * 256 * 2);
    bf16* xr    = (bf16*)alloc((size_t)N * 256 * 2);
    bf16* x1bn  = (bf16*)alloc((size_t)N * 256 * 2);
    float* num  = (float*)alloc((size_t)N * 256 * 4);
    float* loop = (float*)alloc((size_t)N * 128 * 4);
    float* deg  = (float*)alloc((size_t)N * 4);
    float* alog = (float*)alloc((size_t)NT * 4 * 4);
    unsigned* amax = (unsigned*)alloc((size_t)N * 4 * 4);
    float* den  = (float*)alloc((size_t)N * 4 * 4);
    float* pooled = (float*)alloc((size_t)G * 256 * 4);
    float* u1bn = (float*)alloc((size_t)G * 256 * 4);
    short* w1s  = (short*)alloc((size_t)20 * 8 * 64 * 8 * 2);  // 160 KB fragment-major
    short* w2s  = (short*)alloc((size_t)4 * 8 * 64 * 8 * 2);   // 32 KB
    float* b1f  = (float*)alloc((size_t)128 * 4);

    // ===== layer 1 =====
    hipMemsetAsync(deg, 0, (size_t)N * 4, stream);
    hipMemsetAsync(loop, 0, (size_t)N * 128 * 4, stream);
    hipMemsetAsync(amax, 0, (size_t)N * 4 * 4, stream);
    hipMemsetAsync(den, 0, (size_t)N * 4 * 4, stream);
    hipMemsetAsync(num, 0, (size_t)N * 256 * 4, stream);
    hipMemsetAsync(pooled, 0, (size_t)G * 256 * 4, stream);

    edge_mlp1_k<<<(E + 3) / 4, 256, 0, stream>>>(x, edge_attr, src, dst,
                                                 e1_w1, e1_b1, e1_w2, e1_b2, eabuf, E);
    deg_count_k<<<(E + 255) / 256, 256, 0, stream>>>(dst, deg, E);
    loop_accum_k<<<(int)(((long long)E * 128 + 255) / 256), 256, 0, stream>>>(eabuf, dst, loop, E);
    loop_div_k<<<(int)(((long long)N * 128 + 255) / 256), 256, 0, stream>>>(loop, deg, N);
    node_linear_k<64, float><<<(N + 3) / 4, 256, 0, stream>>>(x, g1_lw, g1_lb, g1_rw, g1_rb, xl, xr, N);
    gat_logits_k<<<(NT + 3) / 4, 256, 0, stream>>>(eabuf, loop, xl, xr, src, dst,
                                                   g1_ew, g1_att, alog, amax, E, NT);
    gat_accum_k<<<NT, 256, 0, stream>>>(alog, amax, xl, src, dst, den, num, E, NT);
    finalize1_k<<<N, 256, 0, stream>>>(num, den, g1_bias, bn_n_g, bn_n_b, batch, x1bn, pooled, N);
    global_mlp1_k<<<G, 256, 0, stream>>>(pooled, u1_w1, u1_b1, u1_w2, u1_b2, bn_u_g, bn_u_b, u1bn);

    // ===== layer 2 =====
    hipMemsetAsync(loop, 0, (size_t)N * 128 * 4, stream);
    hipMemsetAsync(amax, 0, (size_t)N * 4 * 4, stream);
    hipMemsetAsync(den, 0, (size_t)N * 4 * 4, stream);
    hipMemsetAsync(num, 0, (size_t)N * 256 * 4, stream);

    conv_weights_k<<<49, 256, 0, stream>>>(e2_w1, e2_w2, e2_b1, bn_e_g, bn_e_b, w1s, w2s, b1f);
    edge_mlp2_mfma_k<<<(E + 31) / 32, 256, 0, stream>>>(x1bn, eabuf, src, dst,
                                                        w1s, b1f, w2s, e2_b2, eabuf, E);
    loop_accum_k<<<(int)(((long long)E * 128 + 255) / 256), 256, 0, stream>>>(eabuf, dst, loop, E);
    loop_div_k<<<(int)(((long long)N * 128 + 255) / 256), 256, 0, stream>>>(loop, deg, N);
    node_linear_k<256, bf16><<<(N + 3) / 4, 256, 0, stream>>>(x1bn, g2_lw, g2_lb, g2_rw, g2_rb, xl, xr, N);
    gat_logits_k<<<(NT + 3) / 4, 256, 0, stream>>>(eabuf, loop, xl, xr, src, dst,
                                                   g2_ew, g2_att, alog, amax, E, NT);
    gat_accum_k<<<NT, 256, 0, stream>>>(alog, amax, xl, src, dst, den, num, E, NT);

    // pooled2 reuses `pooled`
    hipMemsetAsync(pooled, 0, (size_t)G * 256 * 4, stream);
    finalize2_k<<<N, 256, 0, stream>>>(num, den, g2_bias, batch, pooled, N);
    final_mlp_k<<<G, 256, 0, stream>>>(u1bn, pooled, u2_w1, u2_b1, u2_w2, u2_b2,
                                       fc1_w, fc1_b, fc2_w, fc2_b, (float*)d_out);
}

// Round 4
// 3371.206 us; speedup vs baseline: 1.5026x; 1.1640x over previous
//
#include <hip/hip_runtime.h>
#include <hip/hip_bf16.h>
#include <cstdint>
#include <cstddef>

#define INVS 0.99999500003749968f  // 1/sqrt(1+1e-5)
#define G_GRAPHS 256

using bf16 = __hip_bfloat16;
using short8 = __attribute__((ext_vector_type(8))) short;
using floatx4 = __attribute__((ext_vector_type(4))) float;

// ---------- helpers ----------
__device__ __forceinline__ float ldv(const float* p, long long i) { return p[i]; }
__device__ __forceinline__ float ldv(const bf16* p, long long i) { return __bfloat162float(p[i]); }
__device__ __forceinline__ void stv(float* p, long long i, float v) { p[i] = v; }
__device__ __forceinline__ void stv(bf16* p, long long i, float v) { p[i] = __float2bfloat16(v); }

__device__ __forceinline__ unsigned short f2bf(float v) {
    union { float f; unsigned u; } x; x.f = v;
    unsigned r = x.u + 0x7fffu + ((x.u >> 16) & 1u);
    return (unsigned short)(r >> 16);
}

__device__ __forceinline__ unsigned fenc(float f) {
    unsigned b = __float_as_uint(f);
    return (b & 0x80000000u) ? ~b : (b | 0x80000000u);
}
__device__ __forceinline__ float fdec(unsigned u) {
    unsigned b = (u & 0x80000000u) ? (u & 0x7fffffffu) : ~u;
    return __uint_as_float(b);
}

// ---------- weight prep for MFMA edge MLP1 ----------
// w1s: fragment-major bf16 of w1[144][64] zero-padded to K=160. 5 kk x 4 tt x 64 lanes x 8.
// w2s: fragment-major bf16 of w2[64][128]. 2 kk x 8 tt x 64 lanes x 8.
// Fragment (kk,tt): lane l, j -> W[kk*32 + (l>>4)*8 + j][tt*16 + (l&15)].
__global__ void conv_weights1_k(const float* __restrict__ w1, const float* __restrict__ w2,
                                short* __restrict__ w1s, short* __restrict__ w2s) {
    int gid = blockIdx.x * 256 + threadIdx.x;
    if (gid < 1280) {  // w1 frags
        int f = gid >> 6, lane = gid & 63;
        int kk = f >> 2, tt = f & 3;
        int n = tt * 16 + (lane & 15);
        int k0 = kk * 32 + (lane >> 4) * 8;
        short8 v;
        for (int j = 0; j < 8; ++j) {
            int k = k0 + j;
            v[j] = (k < 144) ? (short)f2bf(w1[k * 64 + n]) : (short)0;
        }
        *(short8*)(w1s + (long long)gid * 8) = v;
    } else if (gid < 2304) {  // w2 frags
        int g2 = gid - 1280;
        int f = g2 >> 6, lane = g2 & 63;
        int kk = f >> 3, tt = f & 7;
        int n = tt * 16 + (lane & 15);
        int k0 = kk * 32 + (lane >> 4) * 8;
        short8 v;
        for (int j = 0; j < 8; ++j) v[j] = (short)f2bf(w2[(k0 + j) * 128 + n]);
        *(short8*)(w2s + (long long)g2 * 8) = v;
    }
}

// ---------- Edge MLP 1 via MFMA: [E x 160(144)] @ [160 x 64] relu @ [64 x 128] ----------
// 32 edges / block, 4 waves.
__global__ __launch_bounds__(256) void edge_mlp1_mfma_k(
    const float* __restrict__ x, const float* __restrict__ ea,
    const int* __restrict__ src, const int* __restrict__ dst,
    const short* __restrict__ w1s, const float* __restrict__ b1,
    const short* __restrict__ w2s, const float* __restrict__ b2,
    bf16* __restrict__ out, int E) {
    __shared__ short At[32][168];   // 160 + 8 pad; reused as out-tile (128 cols)
    __shared__ short Ht[32][72];    // 64 + 8 pad
    __shared__ int sdv[32][2];
    int t = threadIdx.x;
    long long e0 = (long long)blockIdx.x * 32;
    if (t < 64) {
        int r = t & 31;
        long long e = e0 + r;
        int v = 0;
        if (e < E) v = (t < 32) ? src[e] : dst[e];
        sdv[r][t >> 5] = v;
    }
    __syncthreads();
    // stage A: 32 rows x 40 chunks of 4 floats -> bf16 (x[s]64 | x[d]64 | ea16 | zeros16)
    for (int i = t; i < 32 * 40; i += 256) {
        int r = i / 40, c = i - r * 40;
        long long e = e0 + r;
        float4 v = {0.f, 0.f, 0.f, 0.f};
        if (e < E) {
            if (c < 16)      v = *(const float4*)(x + (long long)sdv[r][0] * 64 + c * 4);
            else if (c < 32) v = *(const float4*)(x + (long long)sdv[r][1] * 64 + (c - 16) * 4);
            else if (c < 36) v = *(const float4*)(ea + e * 16 + (c - 32) * 4);
        }
        union { ushort4 u4; unsigned short s[4]; } pk;
        pk.s[0] = f2bf(v.x); pk.s[1] = f2bf(v.y); pk.s[2] = f2bf(v.z); pk.s[3] = f2bf(v.w);
        *(ushort4*)&At[r][c * 4] = pk.u4;
    }
    __syncthreads();

    int w = t >> 6, lane = t & 63;
    int m0 = (w & 1) * 16;
    int lr = lane & 15, lq = lane >> 4;

    // GEMM1: N=64 -> 4 n-tiles; wave handles 2
    int nq1 = (w >> 1) * 2;
    floatx4 acc[2];
    for (int i = 0; i < 2; ++i) acc[i] = (floatx4){0.f, 0.f, 0.f, 0.f};
    for (int kk = 0; kk < 5; ++kk) {
        short8 a = *(const short8*)&At[m0 + lr][kk * 32 + lq * 8];
        for (int tt = 0; tt < 2; ++tt) {
            short8 b = *(const short8*)(w1s + ((long long)((kk * 4 + nq1 + tt) * 64 + lane)) * 8);
            acc[tt] = __builtin_amdgcn_mfma_f32_16x16x32_bf16(a, b, acc[tt], 0, 0, 0);
        }
    }
    for (int tt = 0; tt < 2; ++tt) {
        int col = (nq1 + tt) * 16 + lr;
        float bv = b1[col];
        for (int r = 0; r < 4; ++r)
            Ht[m0 + lq * 4 + r][col] = (short)f2bf(fmaxf(acc[tt][r] + bv, 0.f));
    }
    __syncthreads();

    // GEMM2: N=128 -> 8 n-tiles; wave handles 4
    int nq2 = (w >> 1) * 4;
    floatx4 acc2[4];
    for (int i = 0; i < 4; ++i) acc2[i] = (floatx4){0.f, 0.f, 0.f, 0.f};
    for (int kk = 0; kk < 2; ++kk) {
        short8 a = *(const short8*)&Ht[m0 + lr][kk * 32 + lq * 8];
        for (int tt = 0; tt < 4; ++tt) {
            short8 b = *(const short8*)(w2s + ((long long)((kk * 8 + nq2 + tt) * 64 + lane)) * 8);
            acc2[tt] = __builtin_amdgcn_mfma_f32_16x16x32_bf16(a, b, acc2[tt], 0, 0, 0);
        }
    }
    for (int tt = 0; tt < 4; ++tt) {
        int col = (nq2 + tt) * 16 + lr;
        float bv = b2[col];
        for (int r = 0; r < 4; ++r)
            At[m0 + lq * 4 + r][col] = (short)f2bf(acc2[tt][r] + bv);
    }
    __syncthreads();
    for (int i = t; i < 512; i += 256) {
        int r = i >> 4, c = i & 15;
        long long e = e0 + r;
        if (e < E) *(short8*)(void*)(out + e * 128 + c * 8) = *(const short8*)&At[r][c * 8];
    }
}

// ---------- degree count ----------
__global__ void deg_count_k(const int* __restrict__ dst, float* __restrict__ deg, int E) {
    int gid = blockIdx.x * 256 + threadIdx.x;
    if (gid < E) atomicAdd(&deg[dst[gid]], 1.f);
}

// ---------- loop_ea accumulation: acc[dst] += ea[e]  (128 ch) ----------
__global__ void loop_accum_k(const bf16* __restrict__ ea, const int* __restrict__ dst,
                             float* __restrict__ acc, int E) {
    long long gid = (long long)blockIdx.x * 256 + threadIdx.x;
    if (gid >= (long long)E * 128) return;
    long long e = gid >> 7;
    atomicAdd(&acc[(long long)dst[e] * 128 + (gid & 127)], ldv(ea, gid));
}

__global__ void loop_div_k(float* __restrict__ acc, const float* __restrict__ deg, int N) {
    long long gid = (long long)blockIdx.x * 256 + threadIdx.x;
    if (gid >= (long long)N * 128) return;
    acc[gid] /= fmaxf(deg[gid >> 7], 1.f);
}

// ---------- node linear: xl = x@wl+bl, xr = x@wr+br  (out 256 ch, bf16), 4 nodes/block ----------
template <int K, typename T>
__global__ void node_linear_k(const T* __restrict__ x,
                              const float* __restrict__ wl, const float* __restrict__ bl,
                              const float* __restrict__ wr, const float* __restrict__ br,
                              bf16* __restrict__ xl, bf16* __restrict__ xr, int N) {
    __shared__ float xs[4][K];
    int t = threadIdx.x;
    long long n0 = (long long)blockIdx.x * 4;
    for (int i = t; i < 4 * K; i += 256) {
        int ln = i / K, k = i % K;
        long long n = n0 + ln;
        xs[ln][k] = (n < N) ? ldv(x, n * K + k) : 0.f;
    }
    __syncthreads();
    float accl[4], accr[4];
    float blv = bl[t], brv = br[t];
    for (int i = 0; i < 4; ++i) { accl[i] = blv; accr[i] = brv; }
    for (int k = 0; k < K; ++k) {
        float wlv = wl[k * 256 + t], wrv = wr[k * 256 + t];
        for (int i = 0; i < 4; ++i) { accl[i] += xs[i][k] * wlv; accr[i] += xs[i][k] * wrv; }
    }
    for (int i = 0; i < 4; ++i) {
        long long n = n0 + i;
        if (n < N) { stv(xl, n * 256 + t, accl[i]); stv(xr, n * 256 + t, accr[i]); }
    }
}

// ---------- GATv2 attention logits + segment max. 4 edges/block. ----------
__global__ void gat_logits_k(const bf16* __restrict__ ea_e, const float* __restrict__ loop_ea,
                             const bf16* __restrict__ xl, const bf16* __restrict__ xr,
                             const int* __restrict__ src, const int* __restrict__ dst,
                             const float* __restrict__ ew, const float* __restrict__ att,
                             float* __restrict__ alog, unsigned* __restrict__ amax,
                             int E, int NT) {
    __shared__ float eav[4][128];
    __shared__ int sd[4][2];
    int t = threadIdx.x;
    long long e0 = (long long)blockIdx.x * 4;
    for (int i = t; i < 4 * 128; i += 256) {
        int le = i >> 7, c = i & 127;
        long long e = e0 + le;
        float v = 0.f;
        if (e < NT) v = (e < E) ? ldv(ea_e, e * 128 + c) : loop_ea[(e - E) * 128 + c];
        eav[le][c] = v;
    }
    if (t < 4) {
        long long e = e0 + t;
        int s = 0, d = 0;
        if (e < NT) {
            if (e < E) { s = src[e]; d = dst[e]; }
            else { s = d = (int)(e - E); }
        }
        sd[t][0] = s; sd[t][1] = d;
    }
    __syncthreads();
    float ee0 = 0.f, ee1 = 0.f, ee2 = 0.f, ee3 = 0.f;
    for (int k = 0; k < 128; ++k) {
        float w = ew[k * 256 + t];
        ee0 += eav[0][k] * w; ee1 += eav[1][k] * w; ee2 += eav[2][k] * w; ee3 += eav[3][k] * w;
    }
    float av = att[t];  // att is (4,64) flat; t = h*64+c exactly
    int h = t >> 6;
    float ees[4] = {ee0, ee1, ee2, ee3};
    for (int i = 0; i < 4; ++i) {
        long long e = e0 + i;
        if (e >= NT) break;
        int s = sd[i][0], d = sd[i][1];
        float m = ldv(xl, (long long)s * 256 + t) + ldv(xr, (long long)d * 256 + t) + ees[i];
        m = m > 0.f ? m : 0.2f * m;
        float p = m * av;
        for (int off = 32; off; off >>= 1) p += __shfl_down(p, off, 64);
        if ((t & 63) == 0) {
            alog[e * 4 + h] = p;
            atomicMax(&amax[(long long)d * 4 + h], fenc(p));
        }
    }
}

// ---------- softmax accumulation: num[d] += exp(a-amax)*xl[s], den[d][h] += exp ----------
__global__ void gat_accum_k(const float* __restrict__ alog, const unsigned* __restrict__ amax,
                            const bf16* __restrict__ xl,
                            const int* __restrict__ src, const int* __restrict__ dst,
                            float* __restrict__ den, float* __restrict__ num, int E, int NT) {
    long long gid = (long long)blockIdx.x * 256 + threadIdx.x;
    if (gid >= (long long)NT * 256) return;
    long long e = gid >> 8;
    int t = (int)(gid & 255), h = t >> 6;
    int s, d;
    if (e < E) { s = src[e]; d = dst[e]; }
    else { s = d = (int)(e - E); }
    float a = alog[e * 4 + h];
    float ex = expf(a - fdec(amax[(long long)d * 4 + h]));
    atomicAdd(&num[(long long)d * 256 + t], ex * ldv(xl, (long long)s * 256 + t));
    if ((t & 63) == 0) atomicAdd(&den[(long long)d * 4 + h], ex);
}

// ---------- finalize layer1: xn=relu(num/den+bias); pool; x1bn = BN(xn) (bf16) ----------
__global__ void finalize1_k(const float* __restrict__ num, const float* __restrict__ den,
                            const float* __restrict__ bias,
                            const float* __restrict__ bng, const float* __restrict__ bnb,
                            const int* __restrict__ batch,
                            bf16* __restrict__ x1bn, float* __restrict__ pooled, int N) {
    long long gid = (long long)blockIdx.x * 256 + threadIdx.x;
    if (gid >= (long long)N * 256) return;
    long long n = gid >> 8;
    int t = (int)(gid & 255);
    float xn = fmaxf(num[gid] / den[n * 4 + (t >> 6)] + bias[t], 0.f);
    atomicAdd(&pooled[(long long)batch[n] * 256 + t], xn);
    stv(x1bn, gid, bng[t] * (xn * INVS) + bnb[t]);
}

// ---------- finalize layer2: pool only ----------
__global__ void finalize2_k(const float* __restrict__ num, const float* __restrict__ den,
                            const float* __restrict__ bias, const int* __restrict__ batch,
                            float* __restrict__ pooled, int N) {
    long long gid = (long long)blockIdx.x * 256 + threadIdx.x;
    if (gid >= (long long)N * 256) return;
    long long n = gid >> 8;
    int t = (int)(gid & 255);
    float xn = fmaxf(num[gid] / den[n * 4 + (t >> 6)] + bias[t], 0.f);
    atomicAdd(&pooled[(long long)batch[n] * 256 + t], xn);
}

// ---------- global MLP layer1 (u0 = 0): u1bn = BN(mlp(pooled part)) ----------
__global__ void global_mlp1_k(const float* __restrict__ pooled,
                              const float* __restrict__ w1, const float* __restrict__ b1,
                              const float* __restrict__ w2, const float* __restrict__ b2,
                              const float* __restrict__ bng, const float* __restrict__ bnb,
                              float* __restrict__ u1bn) {
    __shared__ float pr[256];
    __shared__ float h[256];
    int t = threadIdx.x, g = blockIdx.x;
    pr[t] = pooled[g * 256 + t];
    __syncthreads();
    float acc = b1[t];
    for (int k = 0; k < 256; ++k) acc += pr[k] * w1[(256 + k) * 256 + t];
    h[t] = fmaxf(acc, 0.f);
    __syncthreads();
    float a2 = b2[t];
    for (int k = 0; k < 256; ++k) a2 += h[k] * w2[k * 256 + t];
    u1bn[g * 256 + t] = bng[t] * (a2 * INVS) + bnb[t];
}

// ---------- weight prep for MFMA edge MLP2 ----------
__global__ void conv_weights_k(const float* __restrict__ w1, const float* __restrict__ w2,
                               const float* __restrict__ b1,
                               const float* __restrict__ bg, const float* __restrict__ bb,
                               short* __restrict__ w1s, short* __restrict__ w2s,
                               float* __restrict__ b1f) {
    int gid = blockIdx.x * 256 + threadIdx.x;
    if (gid < 10240) {  // w1: 20 kk * 8 tt * 64 lanes
        int f = gid >> 6, lane = gid & 63;
        int kk = f >> 3, tt = f & 7;
        int n = tt * 16 + (lane & 15);
        int k0 = kk * 32 + (lane >> 4) * 8;
        short8 v;
        for (int j = 0; j < 8; ++j) {
            int k = k0 + j;
            float x = w1[k * 128 + n];
            if (k >= 512) x *= bg[k - 512] * INVS;
            v[j] = (short)f2bf(x);
        }
        *(short8*)(w1s + (long long)gid * 8) = v;
    } else if (gid < 12288) {  // w2: 4 kk * 8 tt * 64 lanes
        int g2 = gid - 10240;
        int f = g2 >> 6, lane = g2 & 63;
        int kk = f >> 3, tt = f & 7;
        int n = tt * 16 + (lane & 15);
        int k0 = kk * 32 + (lane >> 4) * 8;
        short8 v;
        for (int j = 0; j < 8; ++j) v[j] = (short)f2bf(w2[(k0 + j) * 128 + n]);
        *(short8*)(w2s + (long long)g2 * 8) = v;
    } else if (gid < 12416) {  // b1f: 128 threads
        int j = gid - 12288;
        float acc = b1[j];
        for (int c = 0; c < 128; ++c) acc += bb[c] * w1[(512 + c) * 128 + j];
        b1f[j] = acc;
    }
}

// ---------- Edge MLP 2 via MFMA: [E x 640] @ [640 x 128] relu @ [128 x 128] ----------
__global__ __launch_bounds__(256) void edge_mlp2_mfma_k(
    const bf16* __restrict__ xb, const bf16* __restrict__ ea1,
    const int* __restrict__ src, const int* __restrict__ dst,
    const short* __restrict__ w1s, const float* __restrict__ b1f,
    const short* __restrict__ w2s, const float* __restrict__ b2,
    bf16* __restrict__ out, int E) {
    __shared__ short At[32][648];
    __shared__ short Ht[32][136];
    __shared__ int sdv[32][2];
    int t = threadIdx.x;
    long long e0 = (long long)blockIdx.x * 32;
    if (t < 64) {
        int r = t & 31;
        long long e = e0 + r;
        int v = 0;
        if (e < E) v = (t < 32) ? src[e] : dst[e];
        sdv[r][t >> 5] = v;
    }
    __syncthreads();
    for (int i = t; i < 32 * 80; i += 256) {
        int r = i / 80, c = i - r * 80;
        long long e = e0 + r;
        short8 v = {0, 0, 0, 0, 0, 0, 0, 0};
        if (e < E) {
            if (c < 32)      v = *(const short8*)(const void*)(xb + (long long)sdv[r][0] * 256 + c * 8);
            else if (c < 64) v = *(const short8*)(const void*)(xb + (long long)sdv[r][1] * 256 + (c - 32) * 8);
            else             v = *(const short8*)(const void*)(ea1 + e * 128 + (c - 64) * 8);
        }
        *(short8*)&At[r][c * 8] = v;
    }
    __syncthreads();

    int w = t >> 6, lane = t & 63;
    int m0 = (w & 1) * 16;
    int nq = (w >> 1) * 4;
    int lr = lane & 15, lq = lane >> 4;

    floatx4 acc[4];
    for (int i = 0; i < 4; ++i) acc[i] = (floatx4){0.f, 0.f, 0.f, 0.f};
    for (int kk = 0; kk < 20; ++kk) {
        short8 a = *(const short8*)&At[m0 + lr][kk * 32 + lq * 8];
        for (int tt = 0; tt < 4; ++tt) {
            short8 b = *(const short8*)(w1s + ((long long)((kk * 8 + nq + tt) * 64 + lane)) * 8);
            acc[tt] = __builtin_amdgcn_mfma_f32_16x16x32_bf16(a, b, acc[tt], 0, 0, 0);
        }
    }
    for (int tt = 0; tt < 4; ++tt) {
        int col = (nq + tt) * 16 + lr;
        float bv = b1f[col];
        for (int r = 0; r < 4; ++r)
            Ht[m0 + lq * 4 + r][col] = (short)f2bf(fmaxf(acc[tt][r] + bv, 0.f));
    }
    __syncthreads();

    floatx4 acc2[4];
    for (int i = 0; i < 4; ++i) acc2[i] = (floatx4){0.f, 0.f, 0.f, 0.f};
    for (int kk = 0; kk < 4; ++kk) {
        short8 a = *(const short8*)&Ht[m0 + lr][kk * 32 + lq * 8];
        for (int tt = 0; tt < 4; ++tt) {
            short8 b = *(const short8*)(w2s + ((long long)((kk * 8 + nq + tt) * 64 + lane)) * 8);
            acc2[tt] = __builtin_amdgcn_mfma_f32_16x16x32_bf16(a, b, acc2[tt], 0, 0, 0);
        }
    }
    for (int tt = 0; tt < 4; ++tt) {
        int col = (nq + tt) * 16 + lr;
        float bv = b2[col];
        for (int r = 0; r < 4; ++r)
            At[m0 + lq * 4 + r][col] = (short)f2bf(acc2[tt][r] + bv);
    }
    __syncthreads();
    for (int i = t; i < 512; i += 256) {
        int r = i >> 4, c = i & 15;
        long long e = e0 + r;
        if (e < E) *(short8*)(void*)(out + e * 128 + c * 8) = *(const short8*)&At[r][c * 8];
    }
}

// ---------- final: u2 = mlp([u1bn,pooled2]); h=relu(u2@fc1+b); out = h@fc2+b ----------
__global__ void final_mlp_k(const float* __restrict__ u1bn, const float* __restrict__ pooled,
                            const float* __restrict__ w1, const float* __restrict__ b1,
                            const float* __restrict__ w2, const float* __restrict__ b2,
                            const float* __restrict__ f1w, const float* __restrict__ f1b,
                            const float* __restrict__ f2w, const float* __restrict__ f2b,
                            float* __restrict__ out) {
    __shared__ float ub[256], pb[256], h[256], u2[256];
    int t = threadIdx.x, g = blockIdx.x;
    ub[t] = u1bn[g * 256 + t];
    pb[t] = pooled[g * 256 + t];
    __syncthreads();
    float acc = b1[t];
    for (int k = 0; k < 256; ++k)
        acc += ub[k] * w1[k * 256 + t] + pb[k] * w1[(256 + k) * 256 + t];
    h[t] = fmaxf(acc, 0.f);
    __syncthreads();
    float a2 = b2[t];
    for (int k = 0; k < 256; ++k) a2 += h[k] * w2[k * 256 + t];
    u2[t] = a2;
    __syncthreads();
    float fv = 0.f;
    if (t < 64) {
        float a3 = f1b[t];
        for (int k = 0; k < 256; ++k) a3 += u2[k] * f1w[k * 64 + t];
        fv = fmaxf(a3, 0.f) * f2w[t];
    }
    for (int off = 32; off; off >>= 1) fv += __shfl_down(fv, off, 64);
    if (t == 0) out[g] = fv + f2b[0];
}

// ---------- launch ----------
extern "C" void kernel_launch(void* const* d_in, const int* in_sizes, int n_in,
                              void* d_out, int out_size, void* d_ws, size_t ws_size,
                              hipStream_t stream) {
    const float* x         = (const float*)d_in[0];
    const float* edge_attr = (const float*)d_in[1];
    const float* e1_w1 = (const float*)d_in[2];
    const float* e1_b1 = (const float*)d_in[3];
    const float* e1_w2 = (const float*)d_in[4];
    const float* e1_b2 = (const float*)d_in[5];
    const float* g1_lw = (const float*)d_in[6];
    const float* g1_lb = (const float*)d_in[7];
    const float* g1_rw = (const float*)d_in[8];
    const float* g1_rb = (const float*)d_in[9];
    const float* g1_ew = (const float*)d_in[10];
    const float* g1_att = (const float*)d_in[11];
    const float* g1_bias = (const float*)d_in[12];
    const float* u1_w1 = (const float*)d_in[13];
    const float* u1_b1 = (const float*)d_in[14];
    const float* u1_w2 = (const float*)d_in[15];
    const float* u1_b2 = (const float*)d_in[16];
    const float* bn_n_g = (const float*)d_in[17];
    const float* bn_n_b = (const float*)d_in[18];
    const float* bn_e_g = (const float*)d_in[19];
    const float* bn_e_b = (const float*)d_in[20];
    const float* bn_u_g = (const float*)d_in[21];
    const float* bn_u_b = (const float*)d_in[22];
    const float* e2_w1 = (const float*)d_in[23];
    const float* e2_b1 = (const float*)d_in[24];
    const float* e2_w2 = (const float*)d_in[25];
    const float* e2_b2 = (const float*)d_in[26];
    const float* g2_lw = (const float*)d_in[27];
    const float* g2_lb = (const float*)d_in[28];
    const float* g2_rw = (const float*)d_in[29];
    const float* g2_rb = (const float*)d_in[30];
    const float* g2_ew = (const float*)d_in[31];
    const float* g2_att = (const float*)d_in[32];
    const float* g2_bias = (const float*)d_in[33];
    const float* u2_w1 = (const float*)d_in[34];
    const float* u2_b1 = (const float*)d_in[35];
    const float* u2_w2 = (const float*)d_in[36];
    const float* u2_b2 = (const float*)d_in[37];
    const float* fc1_w = (const float*)d_in[38];
    const float* fc1_b = (const float*)d_in[39];
    const float* fc2_w = (const float*)d_in[40];
    const float* fc2_b = (const float*)d_in[41];
    const int* edge_index = (const int*)d_in[42];
    const int* batch = (const int*)d_in[43];

    const int N = in_sizes[0] / 64;
    const int E = in_sizes[1] / 16;
    const int NT = E + N;
    const int G = G_GRAPHS;
    const int* src = edge_index;
    const int* dst = edge_index + E;

    // workspace carve (~244 MB total)
    char* p = (char*)d_ws;
    auto alloc = [&](size_t bytes) { char* r = p; p += (bytes + 255) & ~(size_t)255; return r; };
    bf16* eabuf = (bf16*)alloc((size_t)E * 128 * 2);   // ea1, overwritten in-place by ea2
    bf16* xl    = (bf16*)alloc((size_t)N * 256 * 2);
    bf16* xr    = (bf16*)alloc((size_t)N * 256 * 2);
    bf16* x1bn  = (bf16*)alloc((size_t)N * 256 * 2);
    float* num  = (float*)alloc((size_t)N * 256 * 4);
    float* loop = (float*)alloc((size_t)N * 128 * 4);
    float* deg  = (float*)alloc((size_t)N * 4);
    float* alog = (float*)alloc((size_t)NT * 4 * 4);
    unsigned* amax = (unsigned*)alloc((size_t)N * 4 * 4);
    float* den  = (float*)alloc((size_t)N * 4 * 4);
    float* pooled = (float*)alloc((size_t)G * 256 * 4);
    float* u1bn = (float*)alloc((size_t)G * 256 * 4);
    short* w1s  = (short*)alloc((size_t)20 * 8 * 64 * 8 * 2);  // layer2 W1 frags
    short* w2s  = (short*)alloc((size_t)4 * 8 * 64 * 8 * 2);   // layer2 W2 frags
    float* b1f  = (float*)alloc((size_t)128 * 4);
    short* w1s1 = (short*)alloc((size_t)5 * 4 * 64 * 8 * 2);   // layer1 W1 frags (padded K=160)
    short* w2s1 = (short*)alloc((size_t)2 * 8 * 64 * 8 * 2);   // layer1 W2 frags

    // ===== layer 1 =====
    hipMemsetAsync(deg, 0, (size_t)N * 4, stream);
    hipMemsetAsync(loop, 0, (size_t)N * 128 * 4, stream);
    hipMemsetAsync(amax, 0, (size_t)N * 4 * 4, stream);
    hipMemsetAsync(den, 0, (size_t)N * 4 * 4, stream);
    hipMemsetAsync(num, 0, (size_t)N * 256 * 4, stream);
    hipMemsetAsync(pooled, 0, (size_t)G * 256 * 4, stream);

    conv_weights1_k<<<9, 256, 0, stream>>>(e1_w1, e1_w2, w1s1, w2s1);
    edge_mlp1_mfma_k<<<(E + 31) / 32, 256, 0, stream>>>(x, edge_attr, src, dst,
                                                        w1s1, e1_b1, w2s1, e1_b2, eabuf, E);
    deg_count_k<<<(E + 255) / 256, 256, 0, stream>>>(dst, deg, E);
    loop_accum_k<<<(int)(((long long)E * 128 + 255) / 256), 256, 0, stream>>>(eabuf, dst, loop, E);
    loop_div_k<<<(int)(((long long)N * 128 + 255) / 256), 256, 0, stream>>>(loop, deg, N);
    node_linear_k<64, float><<<(N + 3) / 4, 256, 0, stream>>>(x, g1_lw, g1_lb, g1_rw, g1_rb, xl, xr, N);
    gat_logits_k<<<(NT + 3) / 4, 256, 0, stream>>>(eabuf, loop, xl, xr, src, dst,
                                                   g1_ew, g1_att, alog, amax, E, NT);
    gat_accum_k<<<NT, 256, 0, stream>>>(alog, amax, xl, src, dst, den, num, E, NT);
    finalize1_k<<<N, 256, 0, stream>>>(num, den, g1_bias, bn_n_g, bn_n_b, batch, x1bn, pooled, N);
    global_mlp1_k<<<G, 256, 0, stream>>>(pooled, u1_w1, u1_b1, u1_w2, u1_b2, bn_u_g, bn_u_b, u1bn);

    // ===== layer 2 =====
    hipMemsetAsync(loop, 0, (size_t)N * 128 * 4, stream);
    hipMemsetAsync(amax, 0, (size_t)N * 4 * 4, stream);
    hipMemsetAsync(den, 0, (size_t)N * 4 * 4, stream);
    hipMemsetAsync(num, 0, (size_t)N * 256 * 4, stream);

    conv_weights_k<<<49, 256, 0, stream>>>(e2_w1, e2_w2, e2_b1, bn_e_g, bn_e_b, w1s, w2s, b1f);
    edge_mlp2_mfma_k<<<(E + 31) / 32, 256, 0, stream>>>(x1bn, eabuf, src, dst,
                                                        w1s, b1f, w2s, e2_b2, eabuf, E);
    loop_accum_k<<<(int)(((long long)E * 128 + 255) / 256), 256, 0, stream>>>(eabuf, dst, loop, E);
    loop_div_k<<<(int)(((long long)N * 128 + 255) / 256), 256, 0, stream>>>(loop, deg, N);
    node_linear_k<256, bf16><<<(N + 3) / 4, 256, 0, stream>>>(x1bn, g2_lw, g2_lb, g2_rw, g2_rb, xl, xr, N);
    gat_logits_k<<<(NT + 3) / 4, 256, 0, stream>>>(eabuf, loop, xl, xr, src, dst,
                                                   g2_ew, g2_att, alog, amax, E, NT);
    gat_accum_k<<<NT, 256, 0, stream>>>(alog, amax, xl, src, dst, den, num, E, NT);

    // pooled2 reuses `pooled`
    hipMemsetAsync(pooled, 0, (size_t)G * 256 * 4, stream);
    finalize2_k<<<N, 256, 0, stream>>>(num, den, g2_bias, batch, pooled, N);
    final_mlp_k<<<G, 256, 0, stream>>>(u1bn, pooled, u2_w1, u2_b1, u2_w2, u2_b2,
                                       fc1_w, fc1_b, fc2_w, fc2_b, (float*)d_out);
}

// Round 5
// 2913.477 us; speedup vs baseline: 1.7387x; 1.1571x over previous
//
#include <hip/hip_runtime.h>
#include <hip/hip_bf16.h>
#include <cstdint>
#include <cstddef>

#define INVS 0.99999500003749968f  // 1/sqrt(1+1e-5)
#define G_GRAPHS 256

using bf16 = __hip_bfloat16;
using short8 = __attribute__((ext_vector_type(8))) short;
using floatx4 = __attribute__((ext_vector_type(4))) float;

// ---------- helpers ----------
__device__ __forceinline__ float ldv(const float* p, long long i) { return p[i]; }
__device__ __forceinline__ float ldv(const bf16* p, long long i) { return __bfloat162float(p[i]); }
__device__ __forceinline__ void stv(float* p, long long i, float v) { p[i] = v; }
__device__ __forceinline__ void stv(bf16* p, long long i, float v) { p[i] = __float2bfloat16(v); }

__device__ __forceinline__ unsigned short f2bf(float v) {
    union { float f; unsigned u; } x; x.f = v;
    unsigned r = x.u + 0x7fffu + ((x.u >> 16) & 1u);
    return (unsigned short)(r >> 16);
}

__device__ __forceinline__ unsigned fenc(float f) {
    unsigned b = __float_as_uint(f);
    return (b & 0x80000000u) ? ~b : (b | 0x80000000u);
}
__device__ __forceinline__ float fdec(unsigned u) {
    unsigned b = (u & 0x80000000u) ? (u & 0x7fffffffu) : ~u;
    return __uint_as_float(b);
}

// ---------- weight prep for MFMA edge MLP1 ----------
__global__ void conv_weights1_k(const float* __restrict__ w1, const float* __restrict__ w2,
                                short* __restrict__ w1s, short* __restrict__ w2s) {
    int gid = blockIdx.x * 256 + threadIdx.x;
    if (gid < 1280) {  // w1 frags: 5 kk x 4 tt
        int f = gid >> 6, lane = gid & 63;
        int kk = f >> 2, tt = f & 3;
        int n = tt * 16 + (lane & 15);
        int k0 = kk * 32 + (lane >> 4) * 8;
        short8 v;
        for (int j = 0; j < 8; ++j) {
            int k = k0 + j;
            v[j] = (k < 144) ? (short)f2bf(w1[k * 64 + n]) : (short)0;
        }
        *(short8*)(w1s + (long long)gid * 8) = v;
    } else if (gid < 2304) {  // w2 frags: 2 kk x 8 tt
        int g2 = gid - 1280;
        int f = g2 >> 6, lane = g2 & 63;
        int kk = f >> 3, tt = f & 7;
        int n = tt * 16 + (lane & 15);
        int k0 = kk * 32 + (lane >> 4) * 8;
        short8 v;
        for (int j = 0; j < 8; ++j) v[j] = (short)f2bf(w2[(k0 + j) * 128 + n]);
        *(short8*)(w2s + (long long)g2 * 8) = v;
    }
}

// ---------- ew prep: ew[128][256] -> frags 4 kk x 16 tt ----------
__global__ void conv_ew_k(const float* __restrict__ ew, short* __restrict__ ews) {
    int gid = blockIdx.x * 256 + threadIdx.x;
    if (gid >= 4096) return;
    int f = gid >> 6, lane = gid & 63;
    int kk = f >> 4, tt = f & 15;
    int n = tt * 16 + (lane & 15);
    int k0 = kk * 32 + (lane >> 4) * 8;
    short8 v;
    for (int j = 0; j < 8; ++j) v[j] = (short)f2bf(ew[(k0 + j) * 256 + n]);
    *(short8*)(ews + (long long)gid * 8) = v;
}

// ---------- Edge MLP 1 via MFMA ----------
__global__ __launch_bounds__(256) void edge_mlp1_mfma_k(
    const float* __restrict__ x, const float* __restrict__ ea,
    const int* __restrict__ src, const int* __restrict__ dst,
    const short* __restrict__ w1s, const float* __restrict__ b1,
    const short* __restrict__ w2s, const float* __restrict__ b2,
    bf16* __restrict__ out, int E) {
    __shared__ short At[32][168];
    __shared__ short Ht[32][72];
    __shared__ int sdv[32][2];
    int t = threadIdx.x;
    long long e0 = (long long)blockIdx.x * 32;
    if (t < 64) {
        int r = t & 31;
        long long e = e0 + r;
        int v = 0;
        if (e < E) v = (t < 32) ? src[e] : dst[e];
        sdv[r][t >> 5] = v;
    }
    __syncthreads();
    for (int i = t; i < 32 * 40; i += 256) {
        int r = i / 40, c = i - r * 40;
        long long e = e0 + r;
        float4 v = {0.f, 0.f, 0.f, 0.f};
        if (e < E) {
            if (c < 16)      v = *(const float4*)(x + (long long)sdv[r][0] * 64 + c * 4);
            else if (c < 32) v = *(const float4*)(x + (long long)sdv[r][1] * 64 + (c - 16) * 4);
            else if (c < 36) v = *(const float4*)(ea + e * 16 + (c - 32) * 4);
        }
        union { ushort4 u4; unsigned short s[4]; } pk;
        pk.s[0] = f2bf(v.x); pk.s[1] = f2bf(v.y); pk.s[2] = f2bf(v.z); pk.s[3] = f2bf(v.w);
        *(ushort4*)&At[r][c * 4] = pk.u4;
    }
    __syncthreads();

    int w = t >> 6, lane = t & 63;
    int m0 = (w & 1) * 16;
    int lr = lane & 15, lq = lane >> 4;

    int nq1 = (w >> 1) * 2;
    floatx4 acc[2];
    for (int i = 0; i < 2; ++i) acc[i] = (floatx4){0.f, 0.f, 0.f, 0.f};
    for (int kk = 0; kk < 5; ++kk) {
        short8 a = *(const short8*)&At[m0 + lr][kk * 32 + lq * 8];
        for (int tt = 0; tt < 2; ++tt) {
            short8 b = *(const short8*)(w1s + ((long long)((kk * 4 + nq1 + tt) * 64 + lane)) * 8);
            acc[tt] = __builtin_amdgcn_mfma_f32_16x16x32_bf16(a, b, acc[tt], 0, 0, 0);
        }
    }
    for (int tt = 0; tt < 2; ++tt) {
        int col = (nq1 + tt) * 16 + lr;
        float bv = b1[col];
        for (int r = 0; r < 4; ++r)
            Ht[m0 + lq * 4 + r][col] = (short)f2bf(fmaxf(acc[tt][r] + bv, 0.f));
    }
    __syncthreads();

    int nq2 = (w >> 1) * 4;
    floatx4 acc2[4];
    for (int i = 0; i < 4; ++i) acc2[i] = (floatx4){0.f, 0.f, 0.f, 0.f};
    for (int kk = 0; kk < 2; ++kk) {
        short8 a = *(const short8*)&Ht[m0 + lr][kk * 32 + lq * 8];
        for (int tt = 0; tt < 4; ++tt) {
            short8 b = *(const short8*)(w2s + ((long long)((kk * 8 + nq2 + tt) * 64 + lane)) * 8);
            acc2[tt] = __builtin_amdgcn_mfma_f32_16x16x32_bf16(a, b, acc2[tt], 0, 0, 0);
        }
    }
    for (int tt = 0; tt < 4; ++tt) {
        int col = (nq2 + tt) * 16 + lr;
        float bv = b2[col];
        for (int r = 0; r < 4; ++r)
            At[m0 + lq * 4 + r][col] = (short)f2bf(acc2[tt][r] + bv);
    }
    __syncthreads();
    for (int i = t; i < 512; i += 256) {
        int r = i >> 4, c = i & 15;
        long long e = e0 + r;
        if (e < E) *(short8*)(void*)(out + e * 128 + c * 8) = *(const short8*)&At[r][c * 8];
    }
}

// ---------- degree count ----------
__global__ void deg_count_k(const int* __restrict__ dst, float* __restrict__ deg, int E) {
    int gid = blockIdx.x * 256 + threadIdx.x;
    if (gid < E) atomicAdd(&deg[dst[gid]], 1.f);
}

// ---------- loop_ea accumulation ----------
__global__ void loop_accum_k(const bf16* __restrict__ ea, const int* __restrict__ dst,
                             float* __restrict__ acc, int E) {
    long long gid = (long long)blockIdx.x * 256 + threadIdx.x;
    if (gid >= (long long)E * 128) return;
    long long e = gid >> 7;
    atomicAdd(&acc[(long long)dst[e] * 128 + (gid & 127)], ldv(ea, gid));
}

__global__ void loop_div_k(float* __restrict__ acc, const float* __restrict__ deg, int N) {
    long long gid = (long long)blockIdx.x * 256 + threadIdx.x;
    if (gid >= (long long)N * 128) return;
    acc[gid] /= fmaxf(deg[gid >> 7], 1.f);
}

// ---------- node linear ----------
template <int K, typename T>
__global__ void node_linear_k(const T* __restrict__ x,
                              const float* __restrict__ wl, const float* __restrict__ bl,
                              const float* __restrict__ wr, const float* __restrict__ br,
                              bf16* __restrict__ xl, bf16* __restrict__ xr, int N) {
    __shared__ float xs[4][K];
    int t = threadIdx.x;
    long long n0 = (long long)blockIdx.x * 4;
    for (int i = t; i < 4 * K; i += 256) {
        int ln = i / K, k = i % K;
        long long n = n0 + ln;
        xs[ln][k] = (n < N) ? ldv(x, n * K + k) : 0.f;
    }
    __syncthreads();
    float accl[4], accr[4];
    float blv = bl[t], brv = br[t];
    for (int i = 0; i < 4; ++i) { accl[i] = blv; accr[i] = brv; }
    for (int k = 0; k < K; ++k) {
        float wlv = wl[k * 256 + t], wrv = wr[k * 256 + t];
        for (int i = 0; i < 4; ++i) { accl[i] += xs[i][k] * wlv; accr[i] += xs[i][k] * wrv; }
    }
    for (int i = 0; i < 4; ++i) {
        long long n = n0 + i;
        if (n < N) { stv(xl, n * 256 + t, accl[i]); stv(xr, n * 256 + t, accr[i]); }
    }
}

// ---------- GATv2 logits via MFMA: ee = ea_all@ew, m = xl[s]+xr[d]+ee, logit ----------
// 32 edges/block, 4 waves. Wave w: MFMA over m-half (w&1), n-half (w>>1); epilogue: head w.
__global__ __launch_bounds__(256) void gat_logits_mfma_k(
    const bf16* __restrict__ ea_e, const float* __restrict__ loop_ea,
    const bf16* __restrict__ xl, const bf16* __restrict__ xr,
    const int* __restrict__ src, const int* __restrict__ dst,
    const short* __restrict__ ews, const float* __restrict__ att,
    float* __restrict__ alog, unsigned* __restrict__ amax, int E, int NT) {
    __shared__ short At[32][136];   // ea_all tile (128 + 8 pad)
    __shared__ float Et[32][264];   // ee tile fp32 (256 + 8 pad)
    __shared__ int sdv[32][2];
    int t = threadIdx.x;
    long long e0 = (long long)blockIdx.x * 32;
    if (t < 64) {
        int r = t & 31;
        long long e = e0 + r;
        int v = 0;
        if (e < NT) v = (e < E) ? ((t < 32) ? src[e] : dst[e]) : (int)(e - E);
        sdv[r][t >> 5] = v;
    }
    // stage ea_all: 32 rows x 16 chunks of 8 bf16
    for (int i = t; i < 32 * 16; i += 256) {
        int r = i >> 4, c = i & 15;
        long long e = e0 + r;
        short8 v = {0, 0, 0, 0, 0, 0, 0, 0};
        if (e < NT) {
            if (e < E) v = *(const short8*)(const void*)(ea_e + e * 128 + c * 8);
            else {
                const float* lp = loop_ea + (e - E) * 128 + c * 8;
                for (int j = 0; j < 8; ++j) v[j] = (short)f2bf(lp[j]);
            }
        }
        *(short8*)&At[r][c * 8] = v;
    }
    __syncthreads();

    int w = t >> 6, lane = t & 63;
    int m0 = (w & 1) * 16;
    int nq = (w >> 1) * 8;          // 8 n-tiles of the 16
    int lr = lane & 15, lq = lane >> 4;

    floatx4 acc[8];
    for (int i = 0; i < 8; ++i) acc[i] = (floatx4){0.f, 0.f, 0.f, 0.f};
    for (int kk = 0; kk < 4; ++kk) {
        short8 a = *(const short8*)&At[m0 + lr][kk * 32 + lq * 8];
        for (int tt = 0; tt < 8; ++tt) {
            short8 b = *(const short8*)(ews + ((long long)((kk * 16 + nq + tt) * 64 + lane)) * 8);
            acc[tt] = __builtin_amdgcn_mfma_f32_16x16x32_bf16(a, b, acc[tt], 0, 0, 0);
        }
    }
    for (int tt = 0; tt < 8; ++tt) {
        int col = (nq + tt) * 16 + lr;
        for (int r = 0; r < 4; ++r)
            Et[m0 + lq * 4 + r][col] = acc[tt][r];
    }
    __syncthreads();

    // epilogue: wave w = head w; lane = channel within head; t = w*64+lane
    float av = att[t];
    for (int r = 0; r < 32; ++r) {
        long long e = e0 + r;
        if (e >= NT) break;
        int s = sdv[r][0], d = sdv[r][1];
        float m = ldv(xl, (long long)s * 256 + t) + ldv(xr, (long long)d * 256 + t) + Et[r][t];
        m = m > 0.f ? m : 0.2f * m;
        float p = m * av;
        for (int off = 32; off; off >>= 1) p += __shfl_down(p, off, 64);
        if (lane == 0) {
            alog[e * 4 + w] = p;
            atomicMax(&amax[(long long)d * 4 + w], fenc(p));
        }
    }
}

// ---------- softmax accumulation ----------
__global__ void gat_accum_k(const float* __restrict__ alog, const unsigned* __restrict__ amax,
                            const bf16* __restrict__ xl,
                            const int* __restrict__ src, const int* __restrict__ dst,
                            float* __restrict__ den, float* __restrict__ num, int E, int NT) {
    long long gid = (long long)blockIdx.x * 256 + threadIdx.x;
    if (gid >= (long long)NT * 256) return;
    long long e = gid >> 8;
    int t = (int)(gid & 255), h = t >> 6;
    int s, d;
    if (e < E) { s = src[e]; d = dst[e]; }
    else { s = d = (int)(e - E); }
    float a = alog[e * 4 + h];
    float ex = expf(a - fdec(amax[(long long)d * 4 + h]));
    atomicAdd(&num[(long long)d * 256 + t], ex * ldv(xl, (long long)s * 256 + t));
    if ((t & 63) == 0) atomicAdd(&den[(long long)d * 4 + h], ex);
}

// ---------- finalize layer1 ----------
__global__ void finalize1_k(const float* __restrict__ num, const float* __restrict__ den,
                            const float* __restrict__ bias,
                            const float* __restrict__ bng, const float* __restrict__ bnb,
                            const int* __restrict__ batch,
                            bf16* __restrict__ x1bn, float* __restrict__ pooled, int N) {
    long long gid = (long long)blockIdx.x * 256 + threadIdx.x;
    if (gid >= (long long)N * 256) return;
    long long n = gid >> 8;
    int t = (int)(gid & 255);
    float xn = fmaxf(num[gid] / den[n * 4 + (t >> 6)] + bias[t], 0.f);
    atomicAdd(&pooled[(long long)batch[n] * 256 + t], xn);
    stv(x1bn, gid, bng[t] * (xn * INVS) + bnb[t]);
}

// ---------- finalize layer2 ----------
__global__ void finalize2_k(const float* __restrict__ num, const float* __restrict__ den,
                            const float* __restrict__ bias, const int* __restrict__ batch,
                            float* __restrict__ pooled, int N) {
    long long gid = (long long)blockIdx.x * 256 + threadIdx.x;
    if (gid >= (long long)N * 256) return;
    long long n = gid >> 8;
    int t = (int)(gid & 255);
    float xn = fmaxf(num[gid] / den[n * 4 + (t >> 6)] + bias[t], 0.f);
    atomicAdd(&pooled[(long long)batch[n] * 256 + t], xn);
}

// ---------- global MLP layer1 ----------
__global__ void global_mlp1_k(const float* __restrict__ pooled,
                              const float* __restrict__ w1, const float* __restrict__ b1,
                              const float* __restrict__ w2, const float* __restrict__ b2,
                              const float* __restrict__ bng, const float* __restrict__ bnb,
                              float* __restrict__ u1bn) {
    __shared__ float pr[256];
    __shared__ float h[256];
    int t = threadIdx.x, g = blockIdx.x;
    pr[t] = pooled[g * 256 + t];
    __syncthreads();
    float acc = b1[t];
    for (int k = 0; k < 256; ++k) acc += pr[k] * w1[(256 + k) * 256 + t];
    h[t] = fmaxf(acc, 0.f);
    __syncthreads();
    float a2 = b2[t];
    for (int k = 0; k < 256; ++k) a2 += h[k] * w2[k * 256 + t];
    u1bn[g * 256 + t] = bng[t] * (a2 * INVS) + bnb[t];
}

// ---------- weight prep for MFMA edge MLP2 ----------
__global__ void conv_weights_k(const float* __restrict__ w1, const float* __restrict__ w2,
                               const float* __restrict__ b1,
                               const float* __restrict__ bg, const float* __restrict__ bb,
                               short* __restrict__ w1s, short* __restrict__ w2s,
                               float* __restrict__ b1f) {
    int gid = blockIdx.x * 256 + threadIdx.x;
    if (gid < 10240) {
        int f = gid >> 6, lane = gid & 63;
        int kk = f >> 3, tt = f & 7;
        int n = tt * 16 + (lane & 15);
        int k0 = kk * 32 + (lane >> 4) * 8;
        short8 v;
        for (int j = 0; j < 8; ++j) {
            int k = k0 + j;
            float x = w1[k * 128 + n];
            if (k >= 512) x *= bg[k - 512] * INVS;
            v[j] = (short)f2bf(x);
        }
        *(short8*)(w1s + (long long)gid * 8) = v;
    } else if (gid < 12288) {
        int g2 = gid - 10240;
        int f = g2 >> 6, lane = g2 & 63;
        int kk = f >> 3, tt = f & 7;
        int n = tt * 16 + (lane & 15);
        int k0 = kk * 32 + (lane >> 4) * 8;
        short8 v;
        for (int j = 0; j < 8; ++j) v[j] = (short)f2bf(w2[(k0 + j) * 128 + n]);
        *(short8*)(w2s + (long long)g2 * 8) = v;
    } else if (gid < 12416) {
        int j = gid - 12288;
        float acc = b1[j];
        for (int c = 0; c < 128; ++c) acc += bb[c] * w1[(512 + c) * 128 + j];
        b1f[j] = acc;
    }
}

// ---------- Edge MLP 2 via MFMA ----------
__global__ __launch_bounds__(256) void edge_mlp2_mfma_k(
    const bf16* __restrict__ xb, const bf16* __restrict__ ea1,
    const int* __restrict__ src, const int* __restrict__ dst,
    const short* __restrict__ w1s, const float* __restrict__ b1f,
    const short* __restrict__ w2s, const float* __restrict__ b2,
    bf16* __restrict__ out, int E) {
    __shared__ short At[32][648];
    __shared__ short Ht[32][136];
    __shared__ int sdv[32][2];
    int t = threadIdx.x;
    long long e0 = (long long)blockIdx.x * 32;
    if (t < 64) {
        int r = t & 31;
        long long e = e0 + r;
        int v = 0;
        if (e < E) v = (t < 32) ? src[e] : dst[e];
        sdv[r][t >> 5] = v;
    }
    __syncthreads();
    for (int i = t; i < 32 * 80; i += 256) {
        int r = i / 80, c = i - r * 80;
        long long e = e0 + r;
        short8 v = {0, 0, 0, 0, 0, 0, 0, 0};
        if (e < E) {
            if (c < 32)      v = *(const short8*)(const void*)(xb + (long long)sdv[r][0] * 256 + c * 8);
            else if (c < 64) v = *(const short8*)(const void*)(xb + (long long)sdv[r][1] * 256 + (c - 32) * 8);
            else             v = *(const short8*)(const void*)(ea1 + e * 128 + (c - 64) * 8);
        }
        *(short8*)&At[r][c * 8] = v;
    }
    __syncthreads();

    int w = t >> 6, lane = t & 63;
    int m0 = (w & 1) * 16;
    int nq = (w >> 1) * 4;
    int lr = lane & 15, lq = lane >> 4;

    floatx4 acc[4];
    for (int i = 0; i < 4; ++i) acc[i] = (floatx4){0.f, 0.f, 0.f, 0.f};
    for (int kk = 0; kk < 20; ++kk) {
        short8 a = *(const short8*)&At[m0 + lr][kk * 32 + lq * 8];
        for (int tt = 0; tt < 4; ++tt) {
            short8 b = *(const short8*)(w1s + ((long long)((kk * 8 + nq + tt) * 64 + lane)) * 8);
            acc[tt] = __builtin_amdgcn_mfma_f32_16x16x32_bf16(a, b, acc[tt], 0, 0, 0);
        }
    }
    for (int tt = 0; tt < 4; ++tt) {
        int col = (nq + tt) * 16 + lr;
        float bv = b1f[col];
        for (int r = 0; r < 4; ++r)
            Ht[m0 + lq * 4 + r][col] = (short)f2bf(fmaxf(acc[tt][r] + bv, 0.f));
    }
    __syncthreads();

    floatx4 acc2[4];
    for (int i = 0; i < 4; ++i) acc2[i] = (floatx4){0.f, 0.f, 0.f, 0.f};
    for (int kk = 0; kk < 4; ++kk) {
        short8 a = *(const short8*)&Ht[m0 + lr][kk * 32 + lq * 8];
        for (int tt = 0; tt < 4; ++tt) {
            short8 b = *(const short8*)(w2s + ((long long)((kk * 8 + nq + tt) * 64 + lane)) * 8);
            acc2[tt] = __builtin_amdgcn_mfma_f32_16x16x32_bf16(a, b, acc2[tt], 0, 0, 0);
        }
    }
    for (int tt = 0; tt < 4; ++tt) {
        int col = (nq + tt) * 16 + lr;
        float bv = b2[col];
        for (int r = 0; r < 4; ++r)
            At[m0 + lq * 4 + r][col] = (short)f2bf(acc2[tt][r] + bv);
    }
    __syncthreads();
    for (int i = t; i < 512; i += 256) {
        int r = i >> 4, c = i & 15;
        long long e = e0 + r;
        if (e < E) *(short8*)(void*)(out + e * 128 + c * 8) = *(const short8*)&At[r][c * 8];
    }
}

// ---------- final global MLP + head ----------
__global__ void final_mlp_k(const float* __restrict__ u1bn, const float* __restrict__ pooled,
                            const float* __restrict__ w1, const float* __restrict__ b1,
                            const float* __restrict__ w2, const float* __restrict__ b2,
                            const float* __restrict__ f1w, const float* __restrict__ f1b,
                            const float* __restrict__ f2w, const float* __restrict__ f2b,
                            float* __restrict__ out) {
    __shared__ float ub[256], pb[256], h[256], u2[256];
    int t = threadIdx.x, g = blockIdx.x;
    ub[t] = u1bn[g * 256 + t];
    pb[t] = pooled[g * 256 + t];
    __syncthreads();
    float acc = b1[t];
    for (int k = 0; k < 256; ++k)
        acc += ub[k] * w1[k * 256 + t] + pb[k] * w1[(256 + k) * 256 + t];
    h[t] = fmaxf(acc, 0.f);
    __syncthreads();
    float a2 = b2[t];
    for (int k = 0; k < 256; ++k) a2 += h[k] * w2[k * 256 + t];
    u2[t] = a2;
    __syncthreads();
    float fv = 0.f;
    if (t < 64) {
        float a3 = f1b[t];
        for (int k = 0; k < 256; ++k) a3 += u2[k] * f1w[k * 64 + t];
        fv = fmaxf(a3, 0.f) * f2w[t];
    }
    for (int off = 32; off; off >>= 1) fv += __shfl_down(fv, off, 64);
    if (t == 0) out[g] = fv + f2b[0];
}

// ---------- launch ----------
extern "C" void kernel_launch(void* const* d_in, const int* in_sizes, int n_in,
                              void* d_out, int out_size, void* d_ws, size_t ws_size,
                              hipStream_t stream) {
    const float* x         = (const float*)d_in[0];
    const float* edge_attr = (const float*)d_in[1];
    const float* e1_w1 = (const float*)d_in[2];
    const float* e1_b1 = (const float*)d_in[3];
    const float* e1_w2 = (const float*)d_in[4];
    const float* e1_b2 = (const float*)d_in[5];
    const float* g1_lw = (const float*)d_in[6];
    const float* g1_lb = (const float*)d_in[7];
    const float* g1_rw = (const float*)d_in[8];
    const float* g1_rb = (const float*)d_in[9];
    const float* g1_ew = (const float*)d_in[10];
    const float* g1_att = (const float*)d_in[11];
    const float* g1_bias = (const float*)d_in[12];
    const float* u1_w1 = (const float*)d_in[13];
    const float* u1_b1 = (const float*)d_in[14];
    const float* u1_w2 = (const float*)d_in[15];
    const float* u1_b2 = (const float*)d_in[16];
    const float* bn_n_g = (const float*)d_in[17];
    const float* bn_n_b = (const float*)d_in[18];
    const float* bn_e_g = (const float*)d_in[19];
    const float* bn_e_b = (const float*)d_in[20];
    const float* bn_u_g = (const float*)d_in[21];
    const float* bn_u_b = (const float*)d_in[22];
    const float* e2_w1 = (const float*)d_in[23];
    const float* e2_b1 = (const float*)d_in[24];
    const float* e2_w2 = (const float*)d_in[25];
    const float* e2_b2 = (const float*)d_in[26];
    const float* g2_lw = (const float*)d_in[27];
    const float* g2_lb = (const float*)d_in[28];
    const float* g2_rw = (const float*)d_in[29];
    const float* g2_rb = (const float*)d_in[30];
    const float* g2_ew = (const float*)d_in[31];
    const float* g2_att = (const float*)d_in[32];
    const float* g2_bias = (const float*)d_in[33];
    const float* u2_w1 = (const float*)d_in[34];
    const float* u2_b1 = (const float*)d_in[35];
    const float* u2_w2 = (const float*)d_in[36];
    const float* u2_b2 = (const float*)d_in[37];
    const float* fc1_w = (const float*)d_in[38];
    const float* fc1_b = (const float*)d_in[39];
    const float* fc2_w = (const float*)d_in[40];
    const float* fc2_b = (const float*)d_in[41];
    const int* edge_index = (const int*)d_in[42];
    const int* batch = (const int*)d_in[43];

    const int N = in_sizes[0] / 64;
    const int E = in_sizes[1] / 16;
    const int NT = E + N;
    const int G = G_GRAPHS;
    const int* src = edge_index;
    const int* dst = edge_index + E;

    // workspace carve (~245 MB total)
    char* p = (char*)d_ws;
    auto alloc = [&](size_t bytes) { char* r = p; p += (bytes + 255) & ~(size_t)255; return r; };
    bf16* eabuf = (bf16*)alloc((size_t)E * 128 * 2);
    bf16* xl    = (bf16*)alloc((size_t)N * 256 * 2);
    bf16* xr    = (bf16*)alloc((size_t)N * 256 * 2);
    bf16* x1bn  = (bf16*)alloc((size_t)N * 256 * 2);
    float* num  = (float*)alloc((size_t)N * 256 * 4);
    float* loop = (float*)alloc((size_t)N * 128 * 4);
    float* deg  = (float*)alloc((size_t)N * 4);
    float* alog = (float*)alloc((size_t)NT * 4 * 4);
    unsigned* amax = (unsigned*)alloc((size_t)N * 4 * 4);
    float* den  = (float*)alloc((size_t)N * 4 * 4);
    float* pooled = (float*)alloc((size_t)G * 256 * 4);
    float* u1bn = (float*)alloc((size_t)G * 256 * 4);
    short* w1s  = (short*)alloc((size_t)20 * 8 * 64 * 8 * 2);
    short* w2s  = (short*)alloc((size_t)4 * 8 * 64 * 8 * 2);
    float* b1f  = (float*)alloc((size_t)128 * 4);
    short* w1s1 = (short*)alloc((size_t)5 * 4 * 64 * 8 * 2);
    short* w2s1 = (short*)alloc((size_t)2 * 8 * 64 * 8 * 2);
    short* ews1 = (short*)alloc((size_t)4 * 16 * 64 * 8 * 2);  // 64 KB
    short* ews2 = (short*)alloc((size_t)4 * 16 * 64 * 8 * 2);  // 64 KB

    // ===== layer 1 =====
    hipMemsetAsync(deg, 0, (size_t)N * 4, stream);
    hipMemsetAsync(loop, 0, (size_t)N * 128 * 4, stream);
    hipMemsetAsync(amax, 0, (size_t)N * 4 * 4, stream);
    hipMemsetAsync(den, 0, (size_t)N * 4 * 4, stream);
    hipMemsetAsync(num, 0, (size_t)N * 256 * 4, stream);
    hipMemsetAsync(pooled, 0, (size_t)G * 256 * 4, stream);

    conv_weights1_k<<<9, 256, 0, stream>>>(e1_w1, e1_w2, w1s1, w2s1);
    conv_ew_k<<<16, 256, 0, stream>>>(g1_ew, ews1);
    conv_ew_k<<<16, 256, 0, stream>>>(g2_ew, ews2);
    edge_mlp1_mfma_k<<<(E + 31) / 32, 256, 0, stream>>>(x, edge_attr, src, dst,
                                                        w1s1, e1_b1, w2s1, e1_b2, eabuf, E);
    deg_count_k<<<(E + 255) / 256, 256, 0, stream>>>(dst, deg, E);
    loop_accum_k<<<(int)(((long long)E * 128 + 255) / 256), 256, 0, stream>>>(eabuf, dst, loop, E);
    loop_div_k<<<(int)(((long long)N * 128 + 255) / 256), 256, 0, stream>>>(loop, deg, N);
    node_linear_k<64, float><<<(N + 3) / 4, 256, 0, stream>>>(x, g1_lw, g1_lb, g1_rw, g1_rb, xl, xr, N);
    gat_logits_mfma_k<<<(NT + 31) / 32, 256, 0, stream>>>(eabuf, loop, xl, xr, src, dst,
                                                          ews1, g1_att, alog, amax, E, NT);
    gat_accum_k<<<NT, 256, 0, stream>>>(alog, amax, xl, src, dst, den, num, E, NT);
    finalize1_k<<<N, 256, 0, stream>>>(num, den, g1_bias, bn_n_g, bn_n_b, batch, x1bn, pooled, N);
    global_mlp1_k<<<G, 256, 0, stream>>>(pooled, u1_w1, u1_b1, u1_w2, u1_b2, bn_u_g, bn_u_b, u1bn);

    // ===== layer 2 =====
    hipMemsetAsync(loop, 0, (size_t)N * 128 * 4, stream);
    hipMemsetAsync(amax, 0, (size_t)N * 4 * 4, stream);
    hipMemsetAsync(den, 0, (size_t)N * 4 * 4, stream);
    hipMemsetAsync(num, 0, (size_t)N * 256 * 4, stream);

    conv_weights_k<<<49, 256, 0, stream>>>(e2_w1, e2_w2, e2_b1, bn_e_g, bn_e_b, w1s, w2s, b1f);
    edge_mlp2_mfma_k<<<(E + 31) / 32, 256, 0, stream>>>(x1bn, eabuf, src, dst,
                                                        w1s, b1f, w2s, e2_b2, eabuf, E);
    loop_accum_k<<<(int)(((long long)E * 128 + 255) / 256), 256, 0, stream>>>(eabuf, dst, loop, E);
    loop_div_k<<<(int)(((long long)N * 128 + 255) / 256), 256, 0, stream>>>(loop, deg, N);
    node_linear_k<256, bf16><<<(N + 3) / 4, 256, 0, stream>>>(x1bn, g2_lw, g2_lb, g2_rw, g2_rb, xl, xr, N);
    gat_logits_mfma_k<<<(NT + 31) / 32, 256, 0, stream>>>(eabuf, loop, xl, xr, src, dst,
                                                          ews2, g2_att, alog, amax, E, NT);
    gat_accum_k<<<NT, 256, 0, stream>>>(alog, amax, xl, src, dst, den, num, E, NT);

    hipMemsetAsync(pooled, 0, (size_t)G * 256 * 4, stream);
    finalize2_k<<<N, 256, 0, stream>>>(num, den, g2_bias, batch, pooled, N);
    final_mlp_k<<<G, 256, 0, stream>>>(u1bn, pooled, u2_w1, u2_b1, u2_w2, u2_b2,
                                       fc1_w, fc1_b, fc2_w, fc2_b, (float*)d_out);
}

// Round 6
// 2329.802 us; speedup vs baseline: 2.1743x; 1.2505x over previous
//
#include <hip/hip_runtime.h>
#include <hip/hip_bf16.h>
#include <cstdint>
#include <cstddef>

#define INVS 0.99999500003749968f  // 1/sqrt(1+1e-5)
#define G_GRAPHS 256

using bf16 = __hip_bfloat16;
using short8 = __attribute__((ext_vector_type(8))) short;
using floatx4 = __attribute__((ext_vector_type(4))) float;

// ---------- helpers ----------
__device__ __forceinline__ float ldv(const float* p, long long i) { return p[i]; }
__device__ __forceinline__ float ldv(const bf16* p, long long i) { return __bfloat162float(p[i]); }
__device__ __forceinline__ void stv(float* p, long long i, float v) { p[i] = v; }
__device__ __forceinline__ void stv(bf16* p, long long i, float v) { p[i] = __float2bfloat16(v); }

__device__ __forceinline__ unsigned short f2bf(float v) {
    union { float f; unsigned u; } x; x.f = v;
    unsigned r = x.u + 0x7fffu + ((x.u >> 16) & 1u);
    return (unsigned short)(r >> 16);
}

// ---------- weight prep for MFMA edge MLP1 ----------
__global__ void conv_weights1_k(const float* __restrict__ w1, const float* __restrict__ w2,
                                short* __restrict__ w1s, short* __restrict__ w2s) {
    int gid = blockIdx.x * 256 + threadIdx.x;
    if (gid < 1280) {  // w1 frags: 5 kk x 4 tt
        int f = gid >> 6, lane = gid & 63;
        int kk = f >> 2, tt = f & 3;
        int n = tt * 16 + (lane & 15);
        int k0 = kk * 32 + (lane >> 4) * 8;
        short8 v;
        for (int j = 0; j < 8; ++j) {
            int k = k0 + j;
            v[j] = (k < 144) ? (short)f2bf(w1[k * 64 + n]) : (short)0;
        }
        *(short8*)(w1s + (long long)gid * 8) = v;
    } else if (gid < 2304) {  // w2 frags: 2 kk x 8 tt
        int g2 = gid - 1280;
        int f = g2 >> 6, lane = g2 & 63;
        int kk = f >> 3, tt = f & 7;
        int n = tt * 16 + (lane & 15);
        int k0 = kk * 32 + (lane >> 4) * 8;
        short8 v;
        for (int j = 0; j < 8; ++j) v[j] = (short)f2bf(w2[(k0 + j) * 128 + n]);
        *(short8*)(w2s + (long long)g2 * 8) = v;
    }
}

// ---------- ew prep: ew[128][256] -> frags 4 kk x 16 tt ----------
__global__ void conv_ew_k(const float* __restrict__ ew, short* __restrict__ ews) {
    int gid = blockIdx.x * 256 + threadIdx.x;
    if (gid >= 4096) return;
    int f = gid >> 6, lane = gid & 63;
    int kk = f >> 4, tt = f & 15;
    int n = tt * 16 + (lane & 15);
    int k0 = kk * 32 + (lane >> 4) * 8;
    short8 v;
    for (int j = 0; j < 8; ++j) v[j] = (short)f2bf(ew[(k0 + j) * 256 + n]);
    *(short8*)(ews + (long long)gid * 8) = v;
}

// ---------- Edge MLP 1 via MFMA ----------
__global__ __launch_bounds__(256) void edge_mlp1_mfma_k(
    const float* __restrict__ x, const float* __restrict__ ea,
    const int* __restrict__ src, const int* __restrict__ dst,
    const short* __restrict__ w1s, const float* __restrict__ b1,
    const short* __restrict__ w2s, const float* __restrict__ b2,
    bf16* __restrict__ out, int E) {
    __shared__ short At[32][168];
    __shared__ short Ht[32][72];
    __shared__ int sdv[32][2];
    int t = threadIdx.x;
    long long e0 = (long long)blockIdx.x * 32;
    if (t < 64) {
        int r = t & 31;
        long long e = e0 + r;
        int v = 0;
        if (e < E) v = (t < 32) ? src[e] : dst[e];
        sdv[r][t >> 5] = v;
    }
    __syncthreads();
    for (int i = t; i < 32 * 40; i += 256) {
        int r = i / 40, c = i - r * 40;
        long long e = e0 + r;
        float4 v = {0.f, 0.f, 0.f, 0.f};
        if (e < E) {
            if (c < 16)      v = *(const float4*)(x + (long long)sdv[r][0] * 64 + c * 4);
            else if (c < 32) v = *(const float4*)(x + (long long)sdv[r][1] * 64 + (c - 16) * 4);
            else if (c < 36) v = *(const float4*)(ea + e * 16 + (c - 32) * 4);
        }
        union { ushort4 u4; unsigned short s[4]; } pk;
        pk.s[0] = f2bf(v.x); pk.s[1] = f2bf(v.y); pk.s[2] = f2bf(v.z); pk.s[3] = f2bf(v.w);
        *(ushort4*)&At[r][c * 4] = pk.u4;
    }
    __syncthreads();

    int w = t >> 6, lane = t & 63;
    int m0 = (w & 1) * 16;
    int lr = lane & 15, lq = lane >> 4;

    int nq1 = (w >> 1) * 2;
    floatx4 acc[2];
    for (int i = 0; i < 2; ++i) acc[i] = (floatx4){0.f, 0.f, 0.f, 0.f};
    for (int kk = 0; kk < 5; ++kk) {
        short8 a = *(const short8*)&At[m0 + lr][kk * 32 + lq * 8];
        for (int tt = 0; tt < 2; ++tt) {
            short8 b = *(const short8*)(w1s + ((long long)((kk * 4 + nq1 + tt) * 64 + lane)) * 8);
            acc[tt] = __builtin_amdgcn_mfma_f32_16x16x32_bf16(a, b, acc[tt], 0, 0, 0);
        }
    }
    for (int tt = 0; tt < 2; ++tt) {
        int col = (nq1 + tt) * 16 + lr;
        float bv = b1[col];
        for (int r = 0; r < 4; ++r)
            Ht[m0 + lq * 4 + r][col] = (short)f2bf(fmaxf(acc[tt][r] + bv, 0.f));
    }
    __syncthreads();

    int nq2 = (w >> 1) * 4;
    floatx4 acc2[4];
    for (int i = 0; i < 4; ++i) acc2[i] = (floatx4){0.f, 0.f, 0.f, 0.f};
    for (int kk = 0; kk < 2; ++kk) {
        short8 a = *(const short8*)&Ht[m0 + lr][kk * 32 + lq * 8];
        for (int tt = 0; tt < 4; ++tt) {
            short8 b = *(const short8*)(w2s + ((long long)((kk * 8 + nq2 + tt) * 64 + lane)) * 8);
            acc2[tt] = __builtin_amdgcn_mfma_f32_16x16x32_bf16(a, b, acc2[tt], 0, 0, 0);
        }
    }
    for (int tt = 0; tt < 4; ++tt) {
        int col = (nq2 + tt) * 16 + lr;
        float bv = b2[col];
        for (int r = 0; r < 4; ++r)
            At[m0 + lq * 4 + r][col] = (short)f2bf(acc2[tt][r] + bv);
    }
    __syncthreads();
    for (int i = t; i < 512; i += 256) {
        int r = i >> 4, c = i & 15;
        long long e = e0 + r;
        if (e < E) *(short8*)(void*)(out + e * 128 + c * 8) = *(const short8*)&At[r][c * 8];
    }
}

// ---------- degree count ----------
__global__ void deg_count_k(const int* __restrict__ dst, float* __restrict__ deg, int E) {
    int gid = blockIdx.x * 256 + threadIdx.x;
    if (gid < E) atomicAdd(&deg[dst[gid]], 1.f);
}

// ---------- loop_ea accumulation ----------
__global__ void loop_accum_k(const bf16* __restrict__ ea, const int* __restrict__ dst,
                             float* __restrict__ acc, int E) {
    long long gid = (long long)blockIdx.x * 256 + threadIdx.x;
    if (gid >= (long long)E * 128) return;
    long long e = gid >> 7;
    atomicAdd(&acc[(long long)dst[e] * 128 + (gid & 127)], ldv(ea, gid));
}

__global__ void loop_div_k(float* __restrict__ acc, const float* __restrict__ deg, int N) {
    long long gid = (long long)blockIdx.x * 256 + threadIdx.x;
    if (gid >= (long long)N * 128) return;
    acc[gid] /= fmaxf(deg[gid >> 7], 1.f);
}

// ---------- node linear ----------
template <int K, typename T>
__global__ void node_linear_k(const T* __restrict__ x,
                              const float* __restrict__ wl, const float* __restrict__ bl,
                              const float* __restrict__ wr, const float* __restrict__ br,
                              bf16* __restrict__ xl, bf16* __restrict__ xr, int N) {
    __shared__ float xs[4][K];
    int t = threadIdx.x;
    long long n0 = (long long)blockIdx.x * 4;
    for (int i = t; i < 4 * K; i += 256) {
        int ln = i / K, k = i % K;
        long long n = n0 + ln;
        xs[ln][k] = (n < N) ? ldv(x, n * K + k) : 0.f;
    }
    __syncthreads();
    float accl[4], accr[4];
    float blv = bl[t], brv = br[t];
    for (int i = 0; i < 4; ++i) { accl[i] = blv; accr[i] = brv; }
    for (int k = 0; k < K; ++k) {
        float wlv = wl[k * 256 + t], wrv = wr[k * 256 + t];
        for (int i = 0; i < 4; ++i) { accl[i] += xs[i][k] * wlv; accr[i] += xs[i][k] * wrv; }
    }
    for (int i = 0; i < 4; ++i) {
        long long n = n0 + i;
        if (n < N) { stv(xl, n * 256 + t, accl[i]); stv(xr, n * 256 + t, accr[i]); }
    }
}

// ---------- Fused GATv2 attention: ee = ea_all@ew (MFMA), logit, exp (no max-shift),
// num[d] += exp*xl[s], den[d] += exp. Softmax shift-invariance makes amax unnecessary. ----------
__global__ __launch_bounds__(256) void gat_attn_mfma_k(
    const bf16* __restrict__ ea_e, const float* __restrict__ loop_ea,
    const bf16* __restrict__ xl, const bf16* __restrict__ xr,
    const int* __restrict__ src, const int* __restrict__ dst,
    const short* __restrict__ ews, const float* __restrict__ att,
    float* __restrict__ den, float* __restrict__ num, int E, int NT) {
    __shared__ short At[32][136];   // ea_all tile (128 + 8 pad)
    __shared__ float Et[32][260];   // ee tile fp32; stride 260 ≡ 4 (mod 32) -> 2-way only
    __shared__ int sdv[32][2];
    int t = threadIdx.x;
    long long e0 = (long long)blockIdx.x * 32;
    if (t < 64) {
        int r = t & 31;
        long long e = e0 + r;
        int v = 0;
        if (e < NT) v = (e < E) ? ((t < 32) ? src[e] : dst[e]) : (int)(e - E);
        sdv[r][t >> 5] = v;
    }
    // stage ea_all: 32 rows x 16 chunks of 8 bf16
    for (int i = t; i < 32 * 16; i += 256) {
        int r = i >> 4, c = i & 15;
        long long e = e0 + r;
        short8 v = {0, 0, 0, 0, 0, 0, 0, 0};
        if (e < NT) {
            if (e < E) v = *(const short8*)(const void*)(ea_e + e * 128 + c * 8);
            else {
                const float* lp = loop_ea + (e - E) * 128 + c * 8;
                for (int j = 0; j < 8; ++j) v[j] = (short)f2bf(lp[j]);
            }
        }
        *(short8*)&At[r][c * 8] = v;
    }
    __syncthreads();

    int w = t >> 6, lane = t & 63;
    int m0 = (w & 1) * 16;
    int nq = (w >> 1) * 8;
    int lr = lane & 15, lq = lane >> 4;

    floatx4 acc[8];
    for (int i = 0; i < 8; ++i) acc[i] = (floatx4){0.f, 0.f, 0.f, 0.f};
    for (int kk = 0; kk < 4; ++kk) {
        short8 a = *(const short8*)&At[m0 + lr][kk * 32 + lq * 8];
        for (int tt = 0; tt < 8; ++tt) {
            short8 b = *(const short8*)(ews + ((long long)((kk * 16 + nq + tt) * 64 + lane)) * 8);
            acc[tt] = __builtin_amdgcn_mfma_f32_16x16x32_bf16(a, b, acc[tt], 0, 0, 0);
        }
    }
    for (int tt = 0; tt < 8; ++tt) {
        int col = (nq + tt) * 16 + lr;
        for (int r = 0; r < 4; ++r)
            Et[m0 + lq * 4 + r][col] = acc[tt][r];
    }
    __syncthreads();

    // epilogue: wave w = head w; lane = channel within head; t = w*64+lane
    float av = att[t];
    for (int r = 0; r < 32; ++r) {
        long long e = e0 + r;
        if (e >= NT) break;
        int s = sdv[r][0], d = sdv[r][1];
        float xlv = ldv(xl, (long long)s * 256 + t);
        float m = xlv + ldv(xr, (long long)d * 256 + t) + Et[r][t];
        m = m > 0.f ? m : 0.2f * m;
        float p = m * av;
        for (int off = 32; off; off >>= 1) p += __shfl_down(p, off, 64);
        p = __shfl(p, 0, 64);
        float ex = expf(p);
        atomicAdd(&num[(long long)d * 256 + t], ex * xlv);
        if (lane == 0) atomicAdd(&den[(long long)d * 4 + w], ex);
    }
}

// ---------- finalize layer1 ----------
__global__ void finalize1_k(const float* __restrict__ num, const float* __restrict__ den,
                            const float* __restrict__ bias,
                            const float* __restrict__ bng, const float* __restrict__ bnb,
                            const int* __restrict__ batch,
                            bf16* __restrict__ x1bn, float* __restrict__ pooled, int N) {
    long long gid = (long long)blockIdx.x * 256 + threadIdx.x;
    if (gid >= (long long)N * 256) return;
    long long n = gid >> 8;
    int t = (int)(gid & 255);
    float xn = fmaxf(num[gid] / den[n * 4 + (t >> 6)] + bias[t], 0.f);
    atomicAdd(&pooled[(long long)batch[n] * 256 + t], xn);
    stv(x1bn, gid, bng[t] * (xn * INVS) + bnb[t]);
}

// ---------- finalize layer2 ----------
__global__ void finalize2_k(const float* __restrict__ num, const float* __restrict__ den,
                            const float* __restrict__ bias, const int* __restrict__ batch,
                            float* __restrict__ pooled, int N) {
    long long gid = (long long)blockIdx.x * 256 + threadIdx.x;
    if (gid >= (long long)N * 256) return;
    long long n = gid >> 8;
    int t = (int)(gid & 255);
    float xn = fmaxf(num[gid] / den[n * 4 + (t >> 6)] + bias[t], 0.f);
    atomicAdd(&pooled[(long long)batch[n] * 256 + t], xn);
}

// ---------- global MLP layer1 ----------
__global__ void global_mlp1_k(const float* __restrict__ pooled,
                              const float* __restrict__ w1, const float* __restrict__ b1,
                              const float* __restrict__ w2, const float* __restrict__ b2,
                              const float* __restrict__ bng, const float* __restrict__ bnb,
                              float* __restrict__ u1bn) {
    __shared__ float pr[256];
    __shared__ float h[256];
    int t = threadIdx.x, g = blockIdx.x;
    pr[t] = pooled[g * 256 + t];
    __syncthreads();
    float acc = b1[t];
    for (int k = 0; k < 256; ++k) acc += pr[k] * w1[(256 + k) * 256 + t];
    h[t] = fmaxf(acc, 0.f);
    __syncthreads();
    float a2 = b2[t];
    for (int k = 0; k < 256; ++k) a2 += h[k] * w2[k * 256 + t];
    u1bn[g * 256 + t] = bng[t] * (a2 * INVS) + bnb[t];
}

// ---------- weight prep for MFMA edge MLP2 ----------
__global__ void conv_weights_k(const float* __restrict__ w1, const float* __restrict__ w2,
                               const float* __restrict__ b1,
                               const float* __restrict__ bg, const float* __restrict__ bb,
                               short* __restrict__ w1s, short* __restrict__ w2s,
                               float* __restrict__ b1f) {
    int gid = blockIdx.x * 256 + threadIdx.x;
    if (gid < 10240) {
        int f = gid >> 6, lane = gid & 63;
        int kk = f >> 3, tt = f & 7;
        int n = tt * 16 + (lane & 15);
        int k0 = kk * 32 + (lane >> 4) * 8;
        short8 v;
        for (int j = 0; j < 8; ++j) {
            int k = k0 + j;
            float x = w1[k * 128 + n];
            if (k >= 512) x *= bg[k - 512] * INVS;
            v[j] = (short)f2bf(x);
        }
        *(short8*)(w1s + (long long)gid * 8) = v;
    } else if (gid < 12288) {
        int g2 = gid - 10240;
        int f = g2 >> 6, lane = g2 & 63;
        int kk = f >> 3, tt = f & 7;
        int n = tt * 16 + (lane & 15);
        int k0 = kk * 32 + (lane >> 4) * 8;
        short8 v;
        for (int j = 0; j < 8; ++j) v[j] = (short)f2bf(w2[(k0 + j) * 128 + n]);
        *(short8*)(w2s + (long long)g2 * 8) = v;
    } else if (gid < 12416) {
        int j = gid - 12288;
        float acc = b1[j];
        for (int c = 0; c < 128; ++c) acc += bb[c] * w1[(512 + c) * 128 + j];
        b1f[j] = acc;
    }
}

// ---------- Edge MLP 2 via MFMA ----------
__global__ __launch_bounds__(256) void edge_mlp2_mfma_k(
    const bf16* __restrict__ xb, const bf16* __restrict__ ea1,
    const int* __restrict__ src, const int* __restrict__ dst,
    const short* __restrict__ w1s, const float* __restrict__ b1f,
    const short* __restrict__ w2s, const float* __restrict__ b2,
    bf16* __restrict__ out, int E) {
    __shared__ short At[32][648];
    __shared__ short Ht[32][136];
    __shared__ int sdv[32][2];
    int t = threadIdx.x;
    long long e0 = (long long)blockIdx.x * 32;
    if (t < 64) {
        int r = t & 31;
        long long e = e0 + r;
        int v = 0;
        if (e < E) v = (t < 32) ? src[e] : dst[e];
        sdv[r][t >> 5] = v;
    }
    __syncthreads();
    for (int i = t; i < 32 * 80; i += 256) {
        int r = i / 80, c = i - r * 80;
        long long e = e0 + r;
        short8 v = {0, 0, 0, 0, 0, 0, 0, 0};
        if (e < E) {
            if (c < 32)      v = *(const short8*)(const void*)(xb + (long long)sdv[r][0] * 256 + c * 8);
            else if (c < 64) v = *(const short8*)(const void*)(xb + (long long)sdv[r][1] * 256 + (c - 32) * 8);
            else             v = *(const short8*)(const void*)(ea1 + e * 128 + (c - 64) * 8);
        }
        *(short8*)&At[r][c * 8] = v;
    }
    __syncthreads();

    int w = t >> 6, lane = t & 63;
    int m0 = (w & 1) * 16;
    int nq = (w >> 1) * 4;
    int lr = lane & 15, lq = lane >> 4;

    floatx4 acc[4];
    for (int i = 0; i < 4; ++i) acc[i] = (floatx4){0.f, 0.f, 0.f, 0.f};
    for (int kk = 0; kk < 20; ++kk) {
        short8 a = *(const short8*)&At[m0 + lr][kk * 32 + lq * 8];
        for (int tt = 0; tt < 4; ++tt) {
            short8 b = *(const short8*)(w1s + ((long long)((kk * 8 + nq + tt) * 64 + lane)) * 8);
            acc[tt] = __builtin_amdgcn_mfma_f32_16x16x32_bf16(a, b, acc[tt], 0, 0, 0);
        }
    }
    for (int tt = 0; tt < 4; ++tt) {
        int col = (nq + tt) * 16 + lr;
        float bv = b1f[col];
        for (int r = 0; r < 4; ++r)
            Ht[m0 + lq * 4 + r][col] = (short)f2bf(fmaxf(acc[tt][r] + bv, 0.f));
    }
    __syncthreads();

    floatx4 acc2[4];
    for (int i = 0; i < 4; ++i) acc2[i] = (floatx4){0.f, 0.f, 0.f, 0.f};
    for (int kk = 0; kk < 4; ++kk) {
        short8 a = *(const short8*)&Ht[m0 + lr][kk * 32 + lq * 8];
        for (int tt = 0; tt < 4; ++tt) {
            short8 b = *(const short8*)(w2s + ((long long)((kk * 8 + nq + tt) * 64 + lane)) * 8);
            acc2[tt] = __builtin_amdgcn_mfma_f32_16x16x32_bf16(a, b, acc2[tt], 0, 0, 0);
        }
    }
    for (int tt = 0; tt < 4; ++tt) {
        int col = (nq + tt) * 16 + lr;
        float bv = b2[col];
        for (int r = 0; r < 4; ++r)
            At[m0 + lq * 4 + r][col] = (short)f2bf(acc2[tt][r] + bv);
    }
    __syncthreads();
    for (int i = t; i < 512; i += 256) {
        int r = i >> 4, c = i & 15;
        long long e = e0 + r;
        if (e < E) *(short8*)(void*)(out + e * 128 + c * 8) = *(const short8*)&At[r][c * 8];
    }
}

// ---------- final global MLP + head ----------
__global__ void final_mlp_k(const float* __restrict__ u1bn, const float* __restrict__ pooled,
                            const float* __restrict__ w1, const float* __restrict__ b1,
                            const float* __restrict__ w2, const float* __restrict__ b2,
                            const float* __restrict__ f1w, const float* __restrict__ f1b,
                            const float* __restrict__ f2w, const float* __restrict__ f2b,
                            float* __restrict__ out) {
    __shared__ float ub[256], pb[256], h[256], u2[256];
    int t = threadIdx.x, g = blockIdx.x;
    ub[t] = u1bn[g * 256 + t];
    pb[t] = pooled[g * 256 + t];
    __syncthreads();
    float acc = b1[t];
    for (int k = 0; k < 256; ++k)
        acc += ub[k] * w1[k * 256 + t] + pb[k] * w1[(256 + k) * 256 + t];
    h[t] = fmaxf(acc, 0.f);
    __syncthreads();
    float a2 = b2[t];
    for (int k = 0; k < 256; ++k) a2 += h[k] * w2[k * 256 + t];
    u2[t] = a2;
    __syncthreads();
    float fv = 0.f;
    if (t < 64) {
        float a3 = f1b[t];
        for (int k = 0; k < 256; ++k) a3 += u2[k] * f1w[k * 64 + t];
        fv = fmaxf(a3, 0.f) * f2w[t];
    }
    for (int off = 32; off; off >>= 1) fv += __shfl_down(fv, off, 64);
    if (t == 0) out[g] = fv + f2b[0];
}

// ---------- launch ----------
extern "C" void kernel_launch(void* const* d_in, const int* in_sizes, int n_in,
                              void* d_out, int out_size, void* d_ws, size_t ws_size,
                              hipStream_t stream) {
    const float* x         = (const float*)d_in[0];
    const float* edge_attr = (const float*)d_in[1];
    const float* e1_w1 = (const float*)d_in[2];
    const float* e1_b1 = (const float*)d_in[3];
    const float* e1_w2 = (const float*)d_in[4];
    const float* e1_b2 = (const float*)d_in[5];
    const float* g1_lw = (const float*)d_in[6];
    const float* g1_lb = (const float*)d_in[7];
    const float* g1_rw = (const float*)d_in[8];
    const float* g1_rb = (const float*)d_in[9];
    const float* g1_ew = (const float*)d_in[10];
    const float* g1_att = (const float*)d_in[11];
    const float* g1_bias = (const float*)d_in[12];
    const float* u1_w1 = (const float*)d_in[13];
    const float* u1_b1 = (const float*)d_in[14];
    const float* u1_w2 = (const float*)d_in[15];
    const float* u1_b2 = (const float*)d_in[16];
    const float* bn_n_g = (const float*)d_in[17];
    const float* bn_n_b = (const float*)d_in[18];
    const float* bn_e_g = (const float*)d_in[19];
    const float* bn_e_b = (const float*)d_in[20];
    const float* bn_u_g = (const float*)d_in[21];
    const float* bn_u_b = (const float*)d_in[22];
    const float* e2_w1 = (const float*)d_in[23];
    const float* e2_b1 = (const float*)d_in[24];
    const float* e2_w2 = (const float*)d_in[25];
    const float* e2_b2 = (const float*)d_in[26];
    const float* g2_lw = (const float*)d_in[27];
    const float* g2_lb = (const float*)d_in[28];
    const float* g2_rw = (const float*)d_in[29];
    const float* g2_rb = (const float*)d_in[30];
    const float* g2_ew = (const float*)d_in[31];
    const float* g2_att = (const float*)d_in[32];
    const float* g2_bias = (const float*)d_in[33];
    const float* u2_w1 = (const float*)d_in[34];
    const float* u2_b1 = (const float*)d_in[35];
    const float* u2_w2 = (const float*)d_in[36];
    const float* u2_b2 = (const float*)d_in[37];
    const float* fc1_w = (const float*)d_in[38];
    const float* fc1_b = (const float*)d_in[39];
    const float* fc2_w = (const float*)d_in[40];
    const float* fc2_b = (const float*)d_in[41];
    const int* edge_index = (const int*)d_in[42];
    const int* batch = (const int*)d_in[43];

    const int N = in_sizes[0] / 64;
    const int E = in_sizes[1] / 16;
    const int NT = E + N;
    const int G = G_GRAPHS;
    const int* src = edge_index;
    const int* dst = edge_index + E;

    // workspace carve (~240 MB total)
    char* p = (char*)d_ws;
    auto alloc = [&](size_t bytes) { char* r = p; p += (bytes + 255) & ~(size_t)255; return r; };
    bf16* eabuf = (bf16*)alloc((size_t)E * 128 * 2);
    bf16* xl    = (bf16*)alloc((size_t)N * 256 * 2);
    bf16* xr    = (bf16*)alloc((size_t)N * 256 * 2);
    bf16* x1bn  = (bf16*)alloc((size_t)N * 256 * 2);
    float* num  = (float*)alloc((size_t)N * 256 * 4);
    float* loop = (float*)alloc((size_t)N * 128 * 4);
    float* deg  = (float*)alloc((size_t)N * 4);
    float* den  = (float*)alloc((size_t)N * 4 * 4);
    float* pooled = (float*)alloc((size_t)G * 256 * 4);
    float* u1bn = (float*)alloc((size_t)G * 256 * 4);
    short* w1s  = (short*)alloc((size_t)20 * 8 * 64 * 8 * 2);
    short* w2s  = (short*)alloc((size_t)4 * 8 * 64 * 8 * 2);
    float* b1f  = (float*)alloc((size_t)128 * 4);
    short* w1s1 = (short*)alloc((size_t)5 * 4 * 64 * 8 * 2);
    short* w2s1 = (short*)alloc((size_t)2 * 8 * 64 * 8 * 2);
    short* ews1 = (short*)alloc((size_t)4 * 16 * 64 * 8 * 2);
    short* ews2 = (short*)alloc((size_t)4 * 16 * 64 * 8 * 2);

    // ===== layer 1 =====
    hipMemsetAsync(deg, 0, (size_t)N * 4, stream);
    hipMemsetAsync(loop, 0, (size_t)N * 128 * 4, stream);
    hipMemsetAsync(den, 0, (size_t)N * 4 * 4, stream);
    hipMemsetAsync(num, 0, (size_t)N * 256 * 4, stream);
    hipMemsetAsync(pooled, 0, (size_t)G * 256 * 4, stream);

    conv_weights1_k<<<9, 256, 0, stream>>>(e1_w1, e1_w2, w1s1, w2s1);
    conv_ew_k<<<16, 256, 0, stream>>>(g1_ew, ews1);
    conv_ew_k<<<16, 256, 0, stream>>>(g2_ew, ews2);
    edge_mlp1_mfma_k<<<(E + 31) / 32, 256, 0, stream>>>(x, edge_attr, src, dst,
                                                        w1s1, e1_b1, w2s1, e1_b2, eabuf, E);
    deg_count_k<<<(E + 255) / 256, 256, 0, stream>>>(dst, deg, E);
    loop_accum_k<<<(int)(((long long)E * 128 + 255) / 256), 256, 0, stream>>>(eabuf, dst, loop, E);
    loop_div_k<<<(int)(((long long)N * 128 + 255) / 256), 256, 0, stream>>>(loop, deg, N);
    node_linear_k<64, float><<<(N + 3) / 4, 256, 0, stream>>>(x, g1_lw, g1_lb, g1_rw, g1_rb, xl, xr, N);
    gat_attn_mfma_k<<<(NT + 31) / 32, 256, 0, stream>>>(eabuf, loop, xl, xr, src, dst,
                                                        ews1, g1_att, den, num, E, NT);
    finalize1_k<<<N, 256, 0, stream>>>(num, den, g1_bias, bn_n_g, bn_n_b, batch, x1bn, pooled, N);
    global_mlp1_k<<<G, 256, 0, stream>>>(pooled, u1_w1, u1_b1, u1_w2, u1_b2, bn_u_g, bn_u_b, u1bn);

    // ===== layer 2 =====
    hipMemsetAsync(loop, 0, (size_t)N * 128 * 4, stream);
    hipMemsetAsync(den, 0, (size_t)N * 4 * 4, stream);
    hipMemsetAsync(num, 0, (size_t)N * 256 * 4, stream);

    conv_weights_k<<<49, 256, 0, stream>>>(e2_w1, e2_w2, e2_b1, bn_e_g, bn_e_b, w1s, w2s, b1f);
    edge_mlp2_mfma_k<<<(E + 31) / 32, 256, 0, stream>>>(x1bn, eabuf, src, dst,
                                                        w1s, b1f, w2s, e2_b2, eabuf, E);
    loop_accum_k<<<(int)(((long long)E * 128 + 255) / 256), 256, 0, stream>>>(eabuf, dst, loop, E);
    loop_div_k<<<(int)(((long long)N * 128 + 255) / 256), 256, 0, stream>>>(loop, deg, N);
    node_linear_k<256, bf16><<<(N + 3) / 4, 256, 0, stream>>>(x1bn, g2_lw, g2_lb, g2_rw, g2_rb, xl, xr, N);
    gat_attn_mfma_k<<<(NT + 31) / 32, 256, 0, stream>>>(eabuf, loop, xl, xr, src, dst,
                                                        ews2, g2_att, den, num, E, NT);

    hipMemsetAsync(pooled, 0, (size_t)G * 256 * 4, stream);
    finalize2_k<<<N, 256, 0, stream>>>(num, den, g2_bias, batch, pooled, N);
    final_mlp_k<<<G, 256, 0, stream>>>(u1bn, pooled, u2_w1, u2_b1, u2_w2, u2_b2,
                                       fc1_w, fc1_b, fc2_w, fc2_b, (float*)d_out);
}

// Round 7
// 2251.843 us; speedup vs baseline: 2.2496x; 1.0346x over previous
//
#include <hip/hip_runtime.h>
#include <hip/hip_bf16.h>
#include <cstdint>
#include <cstddef>

#define INVS 0.99999500003749968f  // 1/sqrt(1+1e-5)
#define G_GRAPHS 256

using bf16 = __hip_bfloat16;
using short8 = __attribute__((ext_vector_type(8))) short;
using floatx4 = __attribute__((ext_vector_type(4))) float;

// ---------- helpers ----------
__device__ __forceinline__ float ldv(const float* p, long long i) { return p[i]; }
__device__ __forceinline__ float ldv(const bf16* p, long long i) { return __bfloat162float(p[i]); }
__device__ __forceinline__ void stv(float* p, long long i, float v) { p[i] = v; }
__device__ __forceinline__ void stv(bf16* p, long long i, float v) { p[i] = __float2bfloat16(v); }

__device__ __forceinline__ unsigned short f2bf(float v) {
    union { float f; unsigned u; } x; x.f = v;
    unsigned r = x.u + 0x7fffu + ((x.u >> 16) & 1u);
    return (unsigned short)(r >> 16);
}
__device__ __forceinline__ float bfu2f(unsigned short u) {
    return __uint_as_float((unsigned)u << 16);
}

// ---------- CSR build: degi -> exclusive scan -> fill (self-loop last per node) ----------
__global__ void degi_k(const int* __restrict__ dst, int* __restrict__ degi, int E) {
    int gid = blockIdx.x * 256 + threadIdx.x;
    if (gid < E) atomicAdd(&degi[dst[gid]], 1);
}

__global__ void scan_k(const int* __restrict__ degi, int* __restrict__ off, int N) {
    __shared__ int buf[1024];
    __shared__ int carry;
    int t = threadIdx.x;
    if (t == 0) carry = 0;
    __syncthreads();
    int nch = (N + 1023) / 1024;
    for (int ch = 0; ch < nch; ++ch) {
        int idx = ch * 1024 + t;
        int v = (idx < N) ? (degi[idx] + 1) : 0;
        buf[t] = v;
        __syncthreads();
        for (int ofs = 1; ofs < 1024; ofs <<= 1) {
            int add = (t >= ofs) ? buf[t - ofs] : 0;
            __syncthreads();
            buf[t] += add;
            __syncthreads();
        }
        int incl = buf[t];
        if (idx < N) off[idx] = carry + incl - v;
        __syncthreads();
        if (t == 1023) carry += incl;
        __syncthreads();
    }
    if (t == 0) off[N] = carry;
}

__global__ void fill_csr_k(const int* __restrict__ src, const int* __restrict__ dst,
                           const int* __restrict__ off, int* __restrict__ fillc,
                           int* __restrict__ csr_src, int* __restrict__ csr_eid,
                           int E, int N) {
    int gid = blockIdx.x * 256 + threadIdx.x;
    if (gid < E) {
        int d = dst[gid];
        int slot = off[d] + atomicAdd(&fillc[d], 1);
        csr_src[slot] = src[gid];
        csr_eid[slot] = gid;
    }
    if (gid < N) {
        int slot = off[gid + 1] - 1;   // reserved last slot = self-loop
        csr_src[slot] = gid;
        csr_eid[slot] = E + gid;
    }
}

// ---------- loop_ea via CSR: mean of incoming ea rows (replaces 41M atomics) ----------
__global__ __launch_bounds__(256) void loop_gather_k(
    const bf16* __restrict__ ea, const int* __restrict__ off,
    const int* __restrict__ csr_eid, float* __restrict__ loop, int N) {
    int t = threadIdx.x;
    int w = t >> 6, lane = t & 63;
    int n = blockIdx.x * 4 + w;
    if (n >= N) return;
    int beg = off[n], end = off[n + 1] - 1;  // exclude self-loop
    float a0 = 0.f, a1 = 0.f;
    for (int i = beg; i < end; ++i) {
        int eid = csr_eid[i];
        unsigned pk = *(const unsigned*)(const void*)(ea + (long long)eid * 128 + lane * 2);
        a0 += __uint_as_float(pk << 16);
        a1 += __uint_as_float(pk & 0xffff0000u);
    }
    float dv = fmaxf((float)(end - beg), 1.f);
    loop[(long long)n * 128 + lane * 2]     = a0 / dv;
    loop[(long long)n * 128 + lane * 2 + 1] = a1 / dv;
}

// ---------- weight prep for MFMA edge MLP1 ----------
__global__ void conv_weights1_k(const float* __restrict__ w1, const float* __restrict__ w2,
                                short* __restrict__ w1s, short* __restrict__ w2s) {
    int gid = blockIdx.x * 256 + threadIdx.x;
    if (gid < 1280) {
        int f = gid >> 6, lane = gid & 63;
        int kk = f >> 2, tt = f & 3;
        int n = tt * 16 + (lane & 15);
        int k0 = kk * 32 + (lane >> 4) * 8;
        short8 v;
        for (int j = 0; j < 8; ++j) {
            int k = k0 + j;
            v[j] = (k < 144) ? (short)f2bf(w1[k * 64 + n]) : (short)0;
        }
        *(short8*)(w1s + (long long)gid * 8) = v;
    } else if (gid < 2304) {
        int g2 = gid - 1280;
        int f = g2 >> 6, lane = g2 & 63;
        int kk = f >> 3, tt = f & 7;
        int n = tt * 16 + (lane & 15);
        int k0 = kk * 32 + (lane >> 4) * 8;
        short8 v;
        for (int j = 0; j < 8; ++j) v[j] = (short)f2bf(w2[(k0 + j) * 128 + n]);
        *(short8*)(w2s + (long long)g2 * 8) = v;
    }
}

// ---------- ew prep: ew[128][256] -> frags 4 kk x 16 tt ----------
__global__ void conv_ew_k(const float* __restrict__ ew, short* __restrict__ ews) {
    int gid = blockIdx.x * 256 + threadIdx.x;
    if (gid >= 4096) return;
    int f = gid >> 6, lane = gid & 63;
    int kk = f >> 4, tt = f & 15;
    int n = tt * 16 + (lane & 15);
    int k0 = kk * 32 + (lane >> 4) * 8;
    short8 v;
    for (int j = 0; j < 8; ++j) v[j] = (short)f2bf(ew[(k0 + j) * 256 + n]);
    *(short8*)(ews + (long long)gid * 8) = v;
}

// ---------- Edge MLP 1 via MFMA ----------
__global__ __launch_bounds__(256) void edge_mlp1_mfma_k(
    const float* __restrict__ x, const float* __restrict__ ea,
    const int* __restrict__ src, const int* __restrict__ dst,
    const short* __restrict__ w1s, const float* __restrict__ b1,
    const short* __restrict__ w2s, const float* __restrict__ b2,
    bf16* __restrict__ out, int E) {
    __shared__ short At[32][168];
    __shared__ short Ht[32][72];
    __shared__ int sdv[32][2];
    int t = threadIdx.x;
    long long e0 = (long long)blockIdx.x * 32;
    if (t < 64) {
        int r = t & 31;
        long long e = e0 + r;
        int v = 0;
        if (e < E) v = (t < 32) ? src[e] : dst[e];
        sdv[r][t >> 5] = v;
    }
    __syncthreads();
    for (int i = t; i < 32 * 40; i += 256) {
        int r = i / 40, c = i - r * 40;
        long long e = e0 + r;
        float4 v = {0.f, 0.f, 0.f, 0.f};
        if (e < E) {
            if (c < 16)      v = *(const float4*)(x + (long long)sdv[r][0] * 64 + c * 4);
            else if (c < 32) v = *(const float4*)(x + (long long)sdv[r][1] * 64 + (c - 16) * 4);
            else if (c < 36) v = *(const float4*)(ea + e * 16 + (c - 32) * 4);
        }
        union { ushort4 u4; unsigned short s[4]; } pk;
        pk.s[0] = f2bf(v.x); pk.s[1] = f2bf(v.y); pk.s[2] = f2bf(v.z); pk.s[3] = f2bf(v.w);
        *(ushort4*)&At[r][c * 4] = pk.u4;
    }
    __syncthreads();

    int w = t >> 6, lane = t & 63;
    int m0 = (w & 1) * 16;
    int lr = lane & 15, lq = lane >> 4;

    int nq1 = (w >> 1) * 2;
    floatx4 acc[2];
    for (int i = 0; i < 2; ++i) acc[i] = (floatx4){0.f, 0.f, 0.f, 0.f};
    for (int kk = 0; kk < 5; ++kk) {
        short8 a = *(const short8*)&At[m0 + lr][kk * 32 + lq * 8];
        for (int tt = 0; tt < 2; ++tt) {
            short8 b = *(const short8*)(w1s + ((long long)((kk * 4 + nq1 + tt) * 64 + lane)) * 8);
            acc[tt] = __builtin_amdgcn_mfma_f32_16x16x32_bf16(a, b, acc[tt], 0, 0, 0);
        }
    }
    for (int tt = 0; tt < 2; ++tt) {
        int col = (nq1 + tt) * 16 + lr;
        float bv = b1[col];
        for (int r = 0; r < 4; ++r)
            Ht[m0 + lq * 4 + r][col] = (short)f2bf(fmaxf(acc[tt][r] + bv, 0.f));
    }
    __syncthreads();

    int nq2 = (w >> 1) * 4;
    floatx4 acc2[4];
    for (int i = 0; i < 4; ++i) acc2[i] = (floatx4){0.f, 0.f, 0.f, 0.f};
    for (int kk = 0; kk < 2; ++kk) {
        short8 a = *(const short8*)&Ht[m0 + lr][kk * 32 + lq * 8];
        for (int tt = 0; tt < 4; ++tt) {
            short8 b = *(const short8*)(w2s + ((long long)((kk * 8 + nq2 + tt) * 64 + lane)) * 8);
            acc2[tt] = __builtin_amdgcn_mfma_f32_16x16x32_bf16(a, b, acc2[tt], 0, 0, 0);
        }
    }
    for (int tt = 0; tt < 4; ++tt) {
        int col = (nq2 + tt) * 16 + lr;
        float bv = b2[col];
        for (int r = 0; r < 4; ++r)
            At[m0 + lq * 4 + r][col] = (short)f2bf(acc2[tt][r] + bv);
    }
    __syncthreads();
    for (int i = t; i < 512; i += 256) {
        int r = i >> 4, c = i & 15;
        long long e = e0 + r;
        if (e < E) *(short8*)(void*)(out + e * 128 + c * 8) = *(const short8*)&At[r][c * 8];
    }
}

// ---------- node linear ----------
template <int K, typename T>
__global__ void node_linear_k(const T* __restrict__ x,
                              const float* __restrict__ wl, const float* __restrict__ bl,
                              const float* __restrict__ wr, const float* __restrict__ br,
                              bf16* __restrict__ xl, bf16* __restrict__ xr, int N) {
    __shared__ float xs[4][K];
    int t = threadIdx.x;
    long long n0 = (long long)blockIdx.x * 4;
    for (int i = t; i < 4 * K; i += 256) {
        int ln = i / K, k = i % K;
        long long n = n0 + ln;
        xs[ln][k] = (n < N) ? ldv(x, n * K + k) : 0.f;
    }
    __syncthreads();
    float accl[4], accr[4];
    float blv = bl[t], brv = br[t];
    for (int i = 0; i < 4; ++i) { accl[i] = blv; accr[i] = brv; }
    for (int k = 0; k < K; ++k) {
        float wlv = wl[k * 256 + t], wrv = wr[k * 256 + t];
        for (int i = 0; i < 4; ++i) { accl[i] += xs[i][k] * wlv; accr[i] += xs[i][k] * wrv; }
    }
    for (int i = 0; i < 4; ++i) {
        long long n = n0 + i;
        if (n < N) { stv(xl, n * 256 + t, accl[i]); stv(xr, n * 256 + t, accr[i]); }
    }
}

// ---------- GATv2 attention logits via MFMA -> exp per (edge,head), no atomics ----------
__global__ __launch_bounds__(256) void gat_attn_mfma_k(
    const bf16* __restrict__ ea_e, const float* __restrict__ loop_ea,
    const bf16* __restrict__ xl, const bf16* __restrict__ xr,
    const int* __restrict__ src, const int* __restrict__ dst,
    const short* __restrict__ ews, const float* __restrict__ att,
    float* __restrict__ exbuf, int E, int NT) {
    __shared__ short At[32][136];
    __shared__ float Et[32][260];   // stride 260 ≡ 4 (mod 32): 2-way only
    __shared__ int sdv[32][2];
    int t = threadIdx.x;
    long long e0 = (long long)blockIdx.x * 32;
    if (t < 64) {
        int r = t & 31;
        long long e = e0 + r;
        int v = 0;
        if (e < NT) v = (e < E) ? ((t < 32) ? src[e] : dst[e]) : (int)(e - E);
        sdv[r][t >> 5] = v;
    }
    for (int i = t; i < 32 * 16; i += 256) {
        int r = i >> 4, c = i & 15;
        long long e = e0 + r;
        short8 v = {0, 0, 0, 0, 0, 0, 0, 0};
        if (e < NT) {
            if (e < E) v = *(const short8*)(const void*)(ea_e + e * 128 + c * 8);
            else {
                const float* lp = loop_ea + (e - E) * 128 + c * 8;
                for (int j = 0; j < 8; ++j) v[j] = (short)f2bf(lp[j]);
            }
        }
        *(short8*)&At[r][c * 8] = v;
    }
    __syncthreads();

    int w = t >> 6, lane = t & 63;
    int m0 = (w & 1) * 16;
    int nq = (w >> 1) * 8;
    int lr = lane & 15, lq = lane >> 4;

    floatx4 acc[8];
    for (int i = 0; i < 8; ++i) acc[i] = (floatx4){0.f, 0.f, 0.f, 0.f};
    for (int kk = 0; kk < 4; ++kk) {
        short8 a = *(const short8*)&At[m0 + lr][kk * 32 + lq * 8];
        for (int tt = 0; tt < 8; ++tt) {
            short8 b = *(const short8*)(ews + ((long long)((kk * 16 + nq + tt) * 64 + lane)) * 8);
            acc[tt] = __builtin_amdgcn_mfma_f32_16x16x32_bf16(a, b, acc[tt], 0, 0, 0);
        }
    }
    for (int tt = 0; tt < 8; ++tt) {
        int col = (nq + tt) * 16 + lr;
        for (int r = 0; r < 4; ++r)
            Et[m0 + lq * 4 + r][col] = acc[tt][r];
    }
    __syncthreads();

    // epilogue: wave w = head w
    float av = att[t];
    for (int r = 0; r < 32; ++r) {
        long long e = e0 + r;
        if (e >= NT) break;
        int s = sdv[r][0], d = sdv[r][1];
        float m = ldv(xl, (long long)s * 256 + t) + ldv(xr, (long long)d * 256 + t) + Et[r][t];
        m = m > 0.f ? m : 0.2f * m;
        float p = m * av;
        for (int off = 32; off; off >>= 1) p += __shfl_down(p, off, 64);
        if (lane == 0) exbuf[e * 4 + w] = expf(p);
    }
}

// ---------- CSR aggregation + fused finalize: wave per node, registers only ----------
template <bool L1>
__global__ __launch_bounds__(256) void gat_agg_k(
    const float* __restrict__ exbuf, const bf16* __restrict__ xl,
    const int* __restrict__ off, const int* __restrict__ csr_src,
    const int* __restrict__ csr_eid,
    const float* __restrict__ bias,
    const float* __restrict__ bng, const float* __restrict__ bnb,
    const int* __restrict__ batch,
    bf16* __restrict__ x1bn, float* __restrict__ pooled, int N) {
    int t = threadIdx.x;
    int w = t >> 6, lane = t & 63;
    int n = blockIdx.x * 4 + w;
    if (n >= N) return;
    int h = lane >> 4;
    int c0 = lane * 4;
    float a0 = 0.f, a1 = 0.f, a2 = 0.f, a3 = 0.f, dacc = 0.f;
    int beg = off[n], end = off[n + 1];
    for (int i = beg; i < end; ++i) {
        int sid = csr_src[i];
        int eid = csr_eid[i];
        float ex = exbuf[(long long)eid * 4 + h];
        ushort4 pk = *(const ushort4*)(const void*)(xl + (long long)sid * 256 + c0);
        a0 += ex * bfu2f(pk.x);
        a1 += ex * bfu2f(pk.y);
        a2 += ex * bfu2f(pk.z);
        a3 += ex * bfu2f(pk.w);
        dacc += ex;
    }
    float inv = 1.f / dacc;
    float x0 = fmaxf(a0 * inv + bias[c0],     0.f);
    float x1 = fmaxf(a1 * inv + bias[c0 + 1], 0.f);
    float x2 = fmaxf(a2 * inv + bias[c0 + 2], 0.f);
    float x3 = fmaxf(a3 * inv + bias[c0 + 3], 0.f);
    long long pb = (long long)batch[n] * 256 + c0;
    atomicAdd(&pooled[pb],     x0);
    atomicAdd(&pooled[pb + 1], x1);
    atomicAdd(&pooled[pb + 2], x2);
    atomicAdd(&pooled[pb + 3], x3);
    if (L1) {
        ushort4 o;
        o.x = f2bf(bng[c0]     * (x0 * INVS) + bnb[c0]);
        o.y = f2bf(bng[c0 + 1] * (x1 * INVS) + bnb[c0 + 1]);
        o.z = f2bf(bng[c0 + 2] * (x2 * INVS) + bnb[c0 + 2]);
        o.w = f2bf(bng[c0 + 3] * (x3 * INVS) + bnb[c0 + 3]);
        *(ushort4*)(void*)(x1bn + (long long)n * 256 + c0) = o;
    }
}

// ---------- global MLP layer1 ----------
__global__ void global_mlp1_k(const float* __restrict__ pooled,
                              const float* __restrict__ w1, const float* __restrict__ b1,
                              const float* __restrict__ w2, const float* __restrict__ b2,
                              const float* __restrict__ bng, const float* __restrict__ bnb,
                              float* __restrict__ u1bn) {
    __shared__ float pr[256];
    __shared__ float h[256];
    int t = threadIdx.x, g = blockIdx.x;
    pr[t] = pooled[g * 256 + t];
    __syncthreads();
    float acc = b1[t];
    for (int k = 0; k < 256; ++k) acc += pr[k] * w1[(256 + k) * 256 + t];
    h[t] = fmaxf(acc, 0.f);
    __syncthreads();
    float a2 = b2[t];
    for (int k = 0; k < 256; ++k) a2 += h[k] * w2[k * 256 + t];
    u1bn[g * 256 + t] = bng[t] * (a2 * INVS) + bnb[t];
}

// ---------- weight prep for MFMA edge MLP2 ----------
__global__ void conv_weights_k(const float* __restrict__ w1, const float* __restrict__ w2,
                               const float* __restrict__ b1,
                               const float* __restrict__ bg, const float* __restrict__ bb,
                               short* __restrict__ w1s, short* __restrict__ w2s,
                               float* __restrict__ b1f) {
    int gid = blockIdx.x * 256 + threadIdx.x;
    if (gid < 10240) {
        int f = gid >> 6, lane = gid & 63;
        int kk = f >> 3, tt = f & 7;
        int n = tt * 16 + (lane & 15);
        int k0 = kk * 32 + (lane >> 4) * 8;
        short8 v;
        for (int j = 0; j < 8; ++j) {
            int k = k0 + j;
            float x = w1[k * 128 + n];
            if (k >= 512) x *= bg[k - 512] * INVS;
            v[j] = (short)f2bf(x);
        }
        *(short8*)(w1s + (long long)gid * 8) = v;
    } else if (gid < 12288) {
        int g2 = gid - 10240;
        int f = g2 >> 6, lane = g2 & 63;
        int kk = f >> 3, tt = f & 7;
        int n = tt * 16 + (lane & 15);
        int k0 = kk * 32 + (lane >> 4) * 8;
        short8 v;
        for (int j = 0; j < 8; ++j) v[j] = (short)f2bf(w2[(k0 + j) * 128 + n]);
        *(short8*)(w2s + (long long)g2 * 8) = v;
    } else if (gid < 12416) {
        int j = gid - 12288;
        float acc = b1[j];
        for (int c = 0; c < 128; ++c) acc += bb[c] * w1[(512 + c) * 128 + j];
        b1f[j] = acc;
    }
}

// ---------- Edge MLP 2 via MFMA ----------
__global__ __launch_bounds__(256) void edge_mlp2_mfma_k(
    const bf16* __restrict__ xb, const bf16* __restrict__ ea1,
    const int* __restrict__ src, const int* __restrict__ dst,
    const short* __restrict__ w1s, const float* __restrict__ b1f,
    const short* __restrict__ w2s, const float* __restrict__ b2,
    bf16* __restrict__ out, int E) {
    __shared__ short At[32][648];
    __shared__ short Ht[32][136];
    __shared__ int sdv[32][2];
    int t = threadIdx.x;
    long long e0 = (long long)blockIdx.x * 32;
    if (t < 64) {
        int r = t & 31;
        long long e = e0 + r;
        int v = 0;
        if (e < E) v = (t < 32) ? src[e] : dst[e];
        sdv[r][t >> 5] = v;
    }
    __syncthreads();
    for (int i = t; i < 32 * 80; i += 256) {
        int r = i / 80, c = i - r * 80;
        long long e = e0 + r;
        short8 v = {0, 0, 0, 0, 0, 0, 0, 0};
        if (e < E) {
            if (c < 32)      v = *(const short8*)(const void*)(xb + (long long)sdv[r][0] * 256 + c * 8);
            else if (c < 64) v = *(const short8*)(const void*)(xb + (long long)sdv[r][1] * 256 + (c - 32) * 8);
            else             v = *(const short8*)(const void*)(ea1 + e * 128 + (c - 64) * 8);
        }
        *(short8*)&At[r][c * 8] = v;
    }
    __syncthreads();

    int w = t >> 6, lane = t & 63;
    int m0 = (w & 1) * 16;
    int nq = (w >> 1) * 4;
    int lr = lane & 15, lq = lane >> 4;

    floatx4 acc[4];
    for (int i = 0; i < 4; ++i) acc[i] = (floatx4){0.f, 0.f, 0.f, 0.f};
    for (int kk = 0; kk < 20; ++kk) {
        short8 a = *(const short8*)&At[m0 + lr][kk * 32 + lq * 8];
        for (int tt = 0; tt < 4; ++tt) {
            short8 b = *(const short8*)(w1s + ((long long)((kk * 8 + nq + tt) * 64 + lane)) * 8);
            acc[tt] = __builtin_amdgcn_mfma_f32_16x16x32_bf16(a, b, acc[tt], 0, 0, 0);
        }
    }
    for (int tt = 0; tt < 4; ++tt) {
        int col = (nq + tt) * 16 + lr;
        float bv = b1f[col];
        for (int r = 0; r < 4; ++r)
            Ht[m0 + lq * 4 + r][col] = (short)f2bf(fmaxf(acc[tt][r] + bv, 0.f));
    }
    __syncthreads();

    floatx4 acc2[4];
    for (int i = 0; i < 4; ++i) acc2[i] = (floatx4){0.f, 0.f, 0.f, 0.f};
    for (int kk = 0; kk < 4; ++kk) {
        short8 a = *(const short8*)&Ht[m0 + lr][kk * 32 + lq * 8];
        for (int tt = 0; tt < 4; ++tt) {
            short8 b = *(const short8*)(w2s + ((long long)((kk * 8 + nq + tt) * 64 + lane)) * 8);
            acc2[tt] = __builtin_amdgcn_mfma_f32_16x16x32_bf16(a, b, acc2[tt], 0, 0, 0);
        }
    }
    for (int tt = 0; tt < 4; ++tt) {
        int col = (nq + tt) * 16 + lr;
        float bv = b2[col];
        for (int r = 0; r < 4; ++r)
            At[m0 + lq * 4 + r][col] = (short)f2bf(acc2[tt][r] + bv);
    }
    __syncthreads();
    for (int i = t; i < 512; i += 256) {
        int r = i >> 4, c = i & 15;
        long long e = e0 + r;
        if (e < E) *(short8*)(void*)(out + e * 128 + c * 8) = *(const short8*)&At[r][c * 8];
    }
}

// ---------- final global MLP + head ----------
__global__ void final_mlp_k(const float* __restrict__ u1bn, const float* __restrict__ pooled,
                            const float* __restrict__ w1, const float* __restrict__ b1,
                            const float* __restrict__ w2, const float* __restrict__ b2,
                            const float* __restrict__ f1w, const float* __restrict__ f1b,
                            const float* __restrict__ f2w, const float* __restrict__ f2b,
                            float* __restrict__ out) {
    __shared__ float ub[256], pb[256], h[256], u2[256];
    int t = threadIdx.x, g = blockIdx.x;
    ub[t] = u1bn[g * 256 + t];
    pb[t] = pooled[g * 256 + t];
    __syncthreads();
    float acc = b1[t];
    for (int k = 0; k < 256; ++k)
        acc += ub[k] * w1[k * 256 + t] + pb[k] * w1[(256 + k) * 256 + t];
    h[t] = fmaxf(acc, 0.f);
    __syncthreads();
    float a2 = b2[t];
    for (int k = 0; k < 256; ++k) a2 += h[k] * w2[k * 256 + t];
    u2[t] = a2;
    __syncthreads();
    float fv = 0.f;
    if (t < 64) {
        float a3 = f1b[t];
        for (int k = 0; k < 256; ++k) a3 += u2[k] * f1w[k * 64 + t];
        fv = fmaxf(a3, 0.f) * f2w[t];
    }
    for (int off = 32; off; off >>= 1) fv += __shfl_down(fv, off, 64);
    if (t == 0) out[g] = fv + f2b[0];
}

// ---------- launch ----------
extern "C" void kernel_launch(void* const* d_in, const int* in_sizes, int n_in,
                              void* d_out, int out_size, void* d_ws, size_t ws_size,
                              hipStream_t stream) {
    const float* x         = (const float*)d_in[0];
    const float* edge_attr = (const float*)d_in[1];
    const float* e1_w1 = (const float*)d_in[2];
    const float* e1_b1 = (const float*)d_in[3];
    const float* e1_w2 = (const float*)d_in[4];
    const float* e1_b2 = (const float*)d_in[5];
    const float* g1_lw = (const float*)d_in[6];
    const float* g1_lb = (const float*)d_in[7];
    const float* g1_rw = (const float*)d_in[8];
    const float* g1_rb = (const float*)d_in[9];
    const float* g1_ew = (const float*)d_in[10];
    const float* g1_att = (const float*)d_in[11];
    const float* g1_bias = (const float*)d_in[12];
    const float* u1_w1 = (const float*)d_in[13];
    const float* u1_b1 = (const float*)d_in[14];
    const float* u1_w2 = (const float*)d_in[15];
    const float* u1_b2 = (const float*)d_in[16];
    const float* bn_n_g = (const float*)d_in[17];
    const float* bn_n_b = (const float*)d_in[18];
    const float* bn_e_g = (const float*)d_in[19];
    const float* bn_e_b = (const float*)d_in[20];
    const float* bn_u_g = (const float*)d_in[21];
    const float* bn_u_b = (const float*)d_in[22];
    const float* e2_w1 = (const float*)d_in[23];
    const float* e2_b1 = (const float*)d_in[24];
    const float* e2_w2 = (const float*)d_in[25];
    const float* e2_b2 = (const float*)d_in[26];
    const float* g2_lw = (const float*)d_in[27];
    const float* g2_lb = (const float*)d_in[28];
    const float* g2_rw = (const float*)d_in[29];
    const float* g2_rb = (const float*)d_in[30];
    const float* g2_ew = (const float*)d_in[31];
    const float* g2_att = (const float*)d_in[32];
    const float* g2_bias = (const float*)d_in[33];
    const float* u2_w1 = (const float*)d_in[34];
    const float* u2_b1 = (const float*)d_in[35];
    const float* u2_w2 = (const float*)d_in[36];
    const float* u2_b2 = (const float*)d_in[37];
    const float* fc1_w = (const float*)d_in[38];
    const float* fc1_b = (const float*)d_in[39];
    const float* fc2_w = (const float*)d_in[40];
    const float* fc2_b = (const float*)d_in[41];
    const int* edge_index = (const int*)d_in[42];
    const int* batch = (const int*)d_in[43];

    const int N = in_sizes[0] / 64;
    const int E = in_sizes[1] / 16;
    const int NT = E + N;
    const int G = G_GRAPHS;
    const int* src = edge_index;
    const int* dst = edge_index + E;

    // workspace carve (~200 MB)
    char* p = (char*)d_ws;
    auto alloc = [&](size_t bytes) { char* r = p; p += (bytes + 255) & ~(size_t)255; return r; };
    bf16* eabuf = (bf16*)alloc((size_t)E * 128 * 2);
    bf16* xl    = (bf16*)alloc((size_t)N * 256 * 2);
    bf16* xr    = (bf16*)alloc((size_t)N * 256 * 2);
    bf16* x1bn  = (bf16*)alloc((size_t)N * 256 * 2);
    float* loop = (float*)alloc((size_t)N * 128 * 4);
    float* exbuf = (float*)alloc((size_t)NT * 4 * 4);
    int* degi   = (int*)alloc((size_t)N * 4);
    int* off    = (int*)alloc((size_t)(N + 1) * 4);
    int* fillc  = (int*)alloc((size_t)N * 4);
    int* csr_src = (int*)alloc((size_t)NT * 4);
    int* csr_eid = (int*)alloc((size_t)NT * 4);
    float* pooled = (float*)alloc((size_t)G * 256 * 4);
    float* u1bn = (float*)alloc((size_t)G * 256 * 4);
    short* w1s  = (short*)alloc((size_t)20 * 8 * 64 * 8 * 2);
    short* w2s  = (short*)alloc((size_t)4 * 8 * 64 * 8 * 2);
    float* b1f  = (float*)alloc((size_t)128 * 4);
    short* w1s1 = (short*)alloc((size_t)5 * 4 * 64 * 8 * 2);
    short* w2s1 = (short*)alloc((size_t)2 * 8 * 64 * 8 * 2);
    short* ews1 = (short*)alloc((size_t)4 * 16 * 64 * 8 * 2);
    short* ews2 = (short*)alloc((size_t)4 * 16 * 64 * 8 * 2);

    // ===== CSR build (graph shared by both layers) =====
    hipMemsetAsync(degi, 0, (size_t)N * 4, stream);
    hipMemsetAsync(fillc, 0, (size_t)N * 4, stream);
    hipMemsetAsync(pooled, 0, (size_t)G * 256 * 4, stream);
    degi_k<<<(E + 255) / 256, 256, 0, stream>>>(dst, degi, E);
    scan_k<<<1, 1024, 0, stream>>>(degi, off, N);
    fill_csr_k<<<(max(E, N) + 255) / 256, 256, 0, stream>>>(src, dst, off, fillc,
                                                            csr_src, csr_eid, E, N);

    // ===== layer 1 =====
    conv_weights1_k<<<9, 256, 0, stream>>>(e1_w1, e1_w2, w1s1, w2s1);
    conv_ew_k<<<16, 256, 0, stream>>>(g1_ew, ews1);
    conv_ew_k<<<16, 256, 0, stream>>>(g2_ew, ews2);
    edge_mlp1_mfma_k<<<(E + 31) / 32, 256, 0, stream>>>(x, edge_attr, src, dst,
                                                        w1s1, e1_b1, w2s1, e1_b2, eabuf, E);
    loop_gather_k<<<(N + 3) / 4, 256, 0, stream>>>(eabuf, off, csr_eid, loop, N);
    node_linear_k<64, float><<<(N + 3) / 4, 256, 0, stream>>>(x, g1_lw, g1_lb, g1_rw, g1_rb, xl, xr, N);
    gat_attn_mfma_k<<<(NT + 31) / 32, 256, 0, stream>>>(eabuf, loop, xl, xr, src, dst,
                                                        ews1, g1_att, exbuf, E, NT);
    gat_agg_k<true><<<(N + 3) / 4, 256, 0, stream>>>(exbuf, xl, off, csr_src, csr_eid,
                                                     g1_bias, bn_n_g, bn_n_b, batch,
                                                     x1bn, pooled, N);
    global_mlp1_k<<<G, 256, 0, stream>>>(pooled, u1_w1, u1_b1, u1_w2, u1_b2, bn_u_g, bn_u_b, u1bn);

    // ===== layer 2 =====
    conv_weights_k<<<49, 256, 0, stream>>>(e2_w1, e2_w2, e2_b1, bn_e_g, bn_e_b, w1s, w2s, b1f);
    edge_mlp2_mfma_k<<<(E + 31) / 32, 256, 0, stream>>>(x1bn, eabuf, src, dst,
                                                        w1s, b1f, w2s, e2_b2, eabuf, E);
    loop_gather_k<<<(N + 3) / 4, 256, 0, stream>>>(eabuf, off, csr_eid, loop, N);
    node_linear_k<256, bf16><<<(N + 3) / 4, 256, 0, stream>>>(x1bn, g2_lw, g2_lb, g2_rw, g2_rb, xl, xr, N);
    gat_attn_mfma_k<<<(NT + 31) / 32, 256, 0, stream>>>(eabuf, loop, xl, xr, src, dst,
                                                        ews2, g2_att, exbuf, E, NT);
    hipMemsetAsync(pooled, 0, (size_t)G * 256 * 4, stream);  // after global_mlp1 consumed it
    gat_agg_k<false><<<(N + 3) / 4, 256, 0, stream>>>(exbuf, xl, off, csr_src, csr_eid,
                                                      g2_bias, nullptr, nullptr, batch,
                                                      nullptr, pooled, N);
    final_mlp_k<<<G, 256, 0, stream>>>(u1bn, pooled, u2_w1, u2_b1, u2_w2, u2_b2,
                                       fc1_w, fc1_b, fc2_w, fc2_b, (float*)d_out);
}

// Round 8
// 1635.597 us; speedup vs baseline: 3.0972x; 1.3768x over previous
//
#include <hip/hip_runtime.h>
#include <hip/hip_bf16.h>
#include <cstdint>
#include <cstddef>

#define INVS 0.99999500003749968f  // 1/sqrt(1+1e-5)
#define G_GRAPHS 256

using bf16 = __hip_bfloat16;
using short8 = __attribute__((ext_vector_type(8))) short;
using floatx4 = __attribute__((ext_vector_type(4))) float;

// ---------- helpers ----------
__device__ __forceinline__ float ldv(const float* p, long long i) { return p[i]; }
__device__ __forceinline__ float ldv(const bf16* p, long long i) { return __bfloat162float(p[i]); }
__device__ __forceinline__ void stv(float* p, long long i, float v) { p[i] = v; }
__device__ __forceinline__ void stv(bf16* p, long long i, float v) { p[i] = __float2bfloat16(v); }

__device__ __forceinline__ unsigned short f2bf(float v) {
    union { float f; unsigned u; } x; x.f = v;
    unsigned r = x.u + 0x7fffu + ((x.u >> 16) & 1u);
    return (unsigned short)(r >> 16);
}
__device__ __forceinline__ float bflo(unsigned u) { return __uint_as_float(u << 16); }
__device__ __forceinline__ float bfhi(unsigned u) { return __uint_as_float(u & 0xffff0000u); }

// ---------- CSR build ----------
__global__ void degi_k(const int* __restrict__ dst, int* __restrict__ degi, int E) {
    int gid = blockIdx.x * 256 + threadIdx.x;
    if (gid < E) atomicAdd(&degi[dst[gid]], 1);
}

__global__ void scan_k(const int* __restrict__ degi, int* __restrict__ off, int N) {
    __shared__ int buf[1024];
    __shared__ int carry;
    int t = threadIdx.x;
    if (t == 0) carry = 0;
    __syncthreads();
    int nch = (N + 1023) / 1024;
    for (int ch = 0; ch < nch; ++ch) {
        int idx = ch * 1024 + t;
        int v = (idx < N) ? (degi[idx] + 1) : 0;
        buf[t] = v;
        __syncthreads();
        for (int ofs = 1; ofs < 1024; ofs <<= 1) {
            int add = (t >= ofs) ? buf[t - ofs] : 0;
            __syncthreads();
            buf[t] += add;
            __syncthreads();
        }
        int incl = buf[t];
        if (idx < N) off[idx] = carry + incl - v;
        __syncthreads();
        if (t == 1023) carry += incl;
        __syncthreads();
    }
    if (t == 0) off[N] = carry;
}

__global__ void fill_csr_k(const int* __restrict__ src, const int* __restrict__ dst,
                           const int* __restrict__ off, int* __restrict__ fillc,
                           int* __restrict__ csr_src, int* __restrict__ slot_of,
                           int E, int N) {
    int gid = blockIdx.x * 256 + threadIdx.x;
    if (gid < E) {
        int d = dst[gid];
        int slot = off[d] + atomicAdd(&fillc[d], 1);
        csr_src[slot] = src[gid];
        slot_of[gid] = slot;
    }
    if (gid < N) {
        csr_src[off[gid + 1] - 1] = gid;   // self-loop slot
    }
}

// ---------- weight prep for MFMA edge MLP1 ----------
__global__ void conv_weights1_k(const float* __restrict__ w1, const float* __restrict__ w2,
                                short* __restrict__ w1s, short* __restrict__ w2s) {
    int gid = blockIdx.x * 256 + threadIdx.x;
    if (gid < 1280) {
        int f = gid >> 6, lane = gid & 63;
        int kk = f >> 2, tt = f & 3;
        int n = tt * 16 + (lane & 15);
        int k0 = kk * 32 + (lane >> 4) * 8;
        short8 v;
        for (int j = 0; j < 8; ++j) {
            int k = k0 + j;
            v[j] = (k < 144) ? (short)f2bf(w1[k * 64 + n]) : (short)0;
        }
        *(short8*)(w1s + (long long)gid * 8) = v;
    } else if (gid < 2304) {
        int g2 = gid - 1280;
        int f = g2 >> 6, lane = g2 & 63;
        int kk = f >> 3, tt = f & 7;
        int n = tt * 16 + (lane & 15);
        int k0 = kk * 32 + (lane >> 4) * 8;
        short8 v;
        for (int j = 0; j < 8; ++j) v[j] = (short)f2bf(w2[(k0 + j) * 128 + n]);
        *(short8*)(w2s + (long long)g2 * 8) = v;
    }
}

// ---------- ew prep: ew[128][256] -> frags 4 kk x 16 tt ----------
__global__ void conv_ew_k(const float* __restrict__ ew, short* __restrict__ ews) {
    int gid = blockIdx.x * 256 + threadIdx.x;
    if (gid >= 4096) return;
    int f = gid >> 6, lane = gid & 63;
    int kk = f >> 4, tt = f & 15;
    int n = tt * 16 + (lane & 15);
    int k0 = kk * 32 + (lane >> 4) * 8;
    short8 v;
    for (int j = 0; j < 8; ++j) v[j] = (short)f2bf(ew[(k0 + j) * 256 + n]);
    *(short8*)(ews + (long long)gid * 8) = v;
}

// ---------- Edge MLP 1 via MFMA ----------
__global__ __launch_bounds__(256) void edge_mlp1_mfma_k(
    const float* __restrict__ x, const float* __restrict__ ea,
    const int* __restrict__ src, const int* __restrict__ dst,
    const short* __restrict__ w1s, const float* __restrict__ b1,
    const short* __restrict__ w2s, const float* __restrict__ b2,
    bf16* __restrict__ out, int E) {
    __shared__ short At[32][168];
    __shared__ short Ht[32][72];
    __shared__ int sdv[32][2];
    int t = threadIdx.x;
    long long e0 = (long long)blockIdx.x * 32;
    if (t < 64) {
        int r = t & 31;
        long long e = e0 + r;
        int v = 0;
        if (e < E) v = (t < 32) ? src[e] : dst[e];
        sdv[r][t >> 5] = v;
    }
    __syncthreads();
    for (int i = t; i < 32 * 40; i += 256) {
        int r = i / 40, c = i - r * 40;
        long long e = e0 + r;
        float4 v = {0.f, 0.f, 0.f, 0.f};
        if (e < E) {
            if (c < 16)      v = *(const float4*)(x + (long long)sdv[r][0] * 64 + c * 4);
            else if (c < 32) v = *(const float4*)(x + (long long)sdv[r][1] * 64 + (c - 16) * 4);
            else if (c < 36) v = *(const float4*)(ea + e * 16 + (c - 32) * 4);
        }
        union { ushort4 u4; unsigned short s[4]; } pk;
        pk.s[0] = f2bf(v.x); pk.s[1] = f2bf(v.y); pk.s[2] = f2bf(v.z); pk.s[3] = f2bf(v.w);
        *(ushort4*)&At[r][c * 4] = pk.u4;
    }
    __syncthreads();

    int w = t >> 6, lane = t & 63;
    int m0 = (w & 1) * 16;
    int lr = lane & 15, lq = lane >> 4;

    int nq1 = (w >> 1) * 2;
    floatx4 acc[2];
    for (int i = 0; i < 2; ++i) acc[i] = (floatx4){0.f, 0.f, 0.f, 0.f};
    for (int kk = 0; kk < 5; ++kk) {
        short8 a = *(const short8*)&At[m0 + lr][kk * 32 + lq * 8];
        for (int tt = 0; tt < 2; ++tt) {
            short8 b = *(const short8*)(w1s + ((long long)((kk * 4 + nq1 + tt) * 64 + lane)) * 8);
            acc[tt] = __builtin_amdgcn_mfma_f32_16x16x32_bf16(a, b, acc[tt], 0, 0, 0);
        }
    }
    for (int tt = 0; tt < 2; ++tt) {
        int col = (nq1 + tt) * 16 + lr;
        float bv = b1[col];
        for (int r = 0; r < 4; ++r)
            Ht[m0 + lq * 4 + r][col] = (short)f2bf(fmaxf(acc[tt][r] + bv, 0.f));
    }
    __syncthreads();

    int nq2 = (w >> 1) * 4;
    floatx4 acc2[4];
    for (int i = 0; i < 4; ++i) acc2[i] = (floatx4){0.f, 0.f, 0.f, 0.f};
    for (int kk = 0; kk < 2; ++kk) {
        short8 a = *(const short8*)&Ht[m0 + lr][kk * 32 + lq * 8];
        for (int tt = 0; tt < 4; ++tt) {
            short8 b = *(const short8*)(w2s + ((long long)((kk * 8 + nq2 + tt) * 64 + lane)) * 8);
            acc2[tt] = __builtin_amdgcn_mfma_f32_16x16x32_bf16(a, b, acc2[tt], 0, 0, 0);
        }
    }
    for (int tt = 0; tt < 4; ++tt) {
        int col = (nq2 + tt) * 16 + lr;
        float bv = b2[col];
        for (int r = 0; r < 4; ++r)
            At[m0 + lq * 4 + r][col] = (short)f2bf(acc2[tt][r] + bv);
    }
    __syncthreads();
    for (int i = t; i < 512; i += 256) {
        int r = i >> 4, c = i & 15;
        long long e = e0 + r;
        if (e < E) *(short8*)(void*)(out + e * 128 + c * 8) = *(const short8*)&At[r][c * 8];
    }
}

// ---------- node linear ----------
template <int K, typename T>
__global__ void node_linear_k(const T* __restrict__ x,
                              const float* __restrict__ wl, const float* __restrict__ bl,
                              const float* __restrict__ wr, const float* __restrict__ br,
                              bf16* __restrict__ xl, bf16* __restrict__ xr, int N) {
    __shared__ float xs[4][K];
    int t = threadIdx.x;
    long long n0 = (long long)blockIdx.x * 4;
    for (int i = t; i < 4 * K; i += 256) {
        int ln = i / K, k = i % K;
        long long n = n0 + ln;
        xs[ln][k] = (n < N) ? ldv(x, n * K + k) : 0.f;
    }
    __syncthreads();
    float accl[4], accr[4];
    float blv = bl[t], brv = br[t];
    for (int i = 0; i < 4; ++i) { accl[i] = blv; accr[i] = brv; }
    for (int k = 0; k < K; ++k) {
        float wlv = wl[k * 256 + t], wrv = wr[k * 256 + t];
        for (int i = 0; i < 4; ++i) { accl[i] += xs[i][k] * wlv; accr[i] += xs[i][k] * wrv; }
    }
    for (int i = 0; i < 4; ++i) {
        long long n = n0 + i;
        if (n < N) { stv(xl, n * 256 + t, accl[i]); stv(xr, n * 256 + t, accr[i]); }
    }
}

// ---------- ee GEMM (half channels): ee[slot][0:128] = ea[e] @ ew[:, PASS*128 : +128] ----------
template <int PASS>
__global__ __launch_bounds__(256) void gemm_ee_k(
    const bf16* __restrict__ ea, const short* __restrict__ ews,
    const int* __restrict__ slot_of, bf16* __restrict__ eeh, int E) {
    __shared__ short At[32][136];
    __shared__ short Et[32][136];
    __shared__ int slt[32];
    int t = threadIdx.x;
    long long e0 = (long long)blockIdx.x * 32;
    if (t < 32) {
        long long e = e0 + t;
        slt[t] = (e < E) ? slot_of[e] : -1;
    }
    for (int i = t; i < 32 * 16; i += 256) {
        int r = i >> 4, c = i & 15;
        long long e = e0 + r;
        short8 v = {0, 0, 0, 0, 0, 0, 0, 0};
        if (e < E) v = *(const short8*)(const void*)(ea + e * 128 + c * 8);
        *(short8*)&At[r][c * 8] = v;
    }
    __syncthreads();

    int w = t >> 6, lane = t & 63;
    int m0 = (w & 1) * 16, nq = (w >> 1) * 4;
    int lr = lane & 15, lq = lane >> 4;

    floatx4 acc[4];
    for (int i = 0; i < 4; ++i) acc[i] = (floatx4){0.f, 0.f, 0.f, 0.f};
    for (int kk = 0; kk < 4; ++kk) {
        short8 a = *(const short8*)&At[m0 + lr][kk * 32 + lq * 8];
        for (int tt = 0; tt < 4; ++tt) {
            short8 b = *(const short8*)(ews + ((long long)((kk * 16 + PASS * 8 + nq + tt) * 64 + lane)) * 8);
            acc[tt] = __builtin_amdgcn_mfma_f32_16x16x32_bf16(a, b, acc[tt], 0, 0, 0);
        }
    }
    for (int tt = 0; tt < 4; ++tt) {
        int col = (nq + tt) * 16 + lr;
        for (int r = 0; r < 4; ++r)
            Et[m0 + lq * 4 + r][col] = (short)f2bf(acc[tt][r]);
    }
    __syncthreads();
    // scatter rows to CSR slots (256 threads = 32 rows x 8 chunks)
    {
        int r = t >> 3, c = t & 7;
        int s = slt[r];
        if (s >= 0)
            *(short8*)(void*)(eeh + (long long)s * 128 + c * 8) = *(const short8*)&Et[r][c * 8];
    }
}

// ---------- self-loop ee = mean of incoming ee rows (sequential CSR reads) ----------
__global__ __launch_bounds__(256) void loop_ee_k(bf16* __restrict__ eeh,
                                                 const int* __restrict__ off, int N) {
    int t = threadIdx.x;
    int w = t >> 6, lane = t & 63;
    int n = blockIdx.x * 4 + w;
    if (n >= N) return;
    int beg = off[n], end = off[n + 1] - 1;
    float a0 = 0.f, a1 = 0.f;
    for (int i = beg; i < end; ++i) {
        unsigned pk = *(const unsigned*)(const void*)(eeh + (long long)i * 128 + lane * 2);
        a0 += bflo(pk);
        a1 += bfhi(pk);
    }
    float dv = fmaxf((float)(end - beg), 1.f);
    unsigned o = ((unsigned)f2bf(a1 / dv) << 16) | (unsigned)f2bf(a0 / dv);
    *(unsigned*)(void*)(eeh + (long long)end * 128 + lane * 2) = o;
}

// ---------- Fused GATv2 attention + aggregation + finalize (half channels / 2 heads) ----------
// Wave per node: xr loaded once, xl[src] gathered ONCE (used for logit AND weighted sum),
// ee read sequentially in CSR order. exp without max-shift (softmax shift-invariance).
template <int PASS, bool L1>
__global__ __launch_bounds__(256) void gat_fused_k(
    const bf16* __restrict__ eeh, const bf16* __restrict__ xl, const bf16* __restrict__ xr,
    const int* __restrict__ off, const int* __restrict__ csr_src,
    const float* __restrict__ att, const float* __restrict__ bias,
    const float* __restrict__ bng, const float* __restrict__ bnb,
    const int* __restrict__ batch,
    bf16* __restrict__ x1bn, float* __restrict__ pooled, int N) {
    int t = threadIdx.x;
    int w = t >> 6, lane = t & 63;
    int n = blockIdx.x * 4 + w;
    if (n >= N) return;
    int c = lane * 2;              // pass-local channel
    int gc = PASS * 128 + c;       // global channel
    unsigned xrp = *(const unsigned*)(const void*)(xr + (long long)n * 256 + gc);
    float xr0 = bflo(xrp), xr1 = bfhi(xrp);
    float at0 = att[gc], at1 = att[gc + 1];
    float a0 = 0.f, a1 = 0.f, dacc = 0.f;
    int beg = off[n], end = off[n + 1];
    for (int i = beg; i < end; ++i) {
        int sid = csr_src[i];
        unsigned xlp = *(const unsigned*)(const void*)(xl + (long long)sid * 256 + gc);
        unsigned eep = *(const unsigned*)(const void*)(eeh + (long long)i * 128 + c);
        float x0 = bflo(xlp), x1v = bfhi(xlp);
        float m0 = x0 + xr0 + bflo(eep);
        float m1 = x1v + xr1 + bfhi(eep);
        m0 = m0 > 0.f ? m0 : 0.2f * m0;
        m1 = m1 > 0.f ? m1 : 0.2f * m1;
        float p = at0 * m0 + at1 * m1;
        p += __shfl_xor(p, 1, 64);
        p += __shfl_xor(p, 2, 64);
        p += __shfl_xor(p, 4, 64);
        p += __shfl_xor(p, 8, 64);
        p += __shfl_xor(p, 16, 64);   // full 32-lane (one head) sum
        float ex = expf(p);
        a0 += ex * x0; a1 += ex * x1v; dacc += ex;
    }
    float inv = 1.f / dacc;
    float o0 = fmaxf(a0 * inv + bias[gc],     0.f);
    float o1 = fmaxf(a1 * inv + bias[gc + 1], 0.f);
    long long pb = (long long)batch[n] * 256 + gc;
    atomicAdd(&pooled[pb],     o0);
    atomicAdd(&pooled[pb + 1], o1);
    if (L1) {
        unsigned pk = ((unsigned)f2bf(bng[gc + 1] * (o1 * INVS) + bnb[gc + 1]) << 16)
                    | (unsigned)f2bf(bng[gc] * (o0 * INVS) + bnb[gc]);
        *(unsigned*)(void*)(x1bn + (long long)n * 256 + gc) = pk;
    }
}

// ---------- global MLP layer1 ----------
__global__ void global_mlp1_k(const float* __restrict__ pooled,
                              const float* __restrict__ w1, const float* __restrict__ b1,
                              const float* __restrict__ w2, const float* __restrict__ b2,
                              const float* __restrict__ bng, const float* __restrict__ bnb,
                              float* __restrict__ u1bn) {
    __shared__ float pr[256];
    __shared__ float h[256];
    int t = threadIdx.x, g = blockIdx.x;
    pr[t] = pooled[g * 256 + t];
    __syncthreads();
    float acc = b1[t];
    for (int k = 0; k < 256; ++k) acc += pr[k] * w1[(256 + k) * 256 + t];
    h[t] = fmaxf(acc, 0.f);
    __syncthreads();
    float a2 = b2[t];
    for (int k = 0; k < 256; ++k) a2 += h[k] * w2[k * 256 + t];
    u1bn[g * 256 + t] = bng[t] * (a2 * INVS) + bnb[t];
}

// ---------- weight prep for MFMA edge MLP2 ----------
__global__ void conv_weights_k(const float* __restrict__ w1, const float* __restrict__ w2,
                               const float* __restrict__ b1,
                               const float* __restrict__ bg, const float* __restrict__ bb,
                               short* __restrict__ w1s, short* __restrict__ w2s,
                               float* __restrict__ b1f) {
    int gid = blockIdx.x * 256 + threadIdx.x;
    if (gid < 10240) {
        int f = gid >> 6, lane = gid & 63;
        int kk = f >> 3, tt = f & 7;
        int n = tt * 16 + (lane & 15);
        int k0 = kk * 32 + (lane >> 4) * 8;
        short8 v;
        for (int j = 0; j < 8; ++j) {
            int k = k0 + j;
            float x = w1[k * 128 + n];
            if (k >= 512) x *= bg[k - 512] * INVS;
            v[j] = (short)f2bf(x);
        }
        *(short8*)(w1s + (long long)gid * 8) = v;
    } else if (gid < 12288) {
        int g2 = gid - 10240;
        int f = g2 >> 6, lane = g2 & 63;
        int kk = f >> 3, tt = f & 7;
        int n = tt * 16 + (lane & 15);
        int k0 = kk * 32 + (lane >> 4) * 8;
        short8 v;
        for (int j = 0; j < 8; ++j) v[j] = (short)f2bf(w2[(k0 + j) * 128 + n]);
        *(short8*)(w2s + (long long)g2 * 8) = v;
    } else if (gid < 12416) {
        int j = gid - 12288;
        float acc = b1[j];
        for (int c = 0; c < 128; ++c) acc += bb[c] * w1[(512 + c) * 128 + j];
        b1f[j] = acc;
    }
}

// ---------- Edge MLP 2 via MFMA ----------
__global__ __launch_bounds__(256) void edge_mlp2_mfma_k(
    const bf16* __restrict__ xb, const bf16* __restrict__ ea1,
    const int* __restrict__ src, const int* __restrict__ dst,
    const short* __restrict__ w1s, const float* __restrict__ b1f,
    const short* __restrict__ w2s, const float* __restrict__ b2,
    bf16* __restrict__ out, int E) {
    __shared__ short At[32][648];
    __shared__ short Ht[32][136];
    __shared__ int sdv[32][2];
    int t = threadIdx.x;
    long long e0 = (long long)blockIdx.x * 32;
    if (t < 64) {
        int r = t & 31;
        long long e = e0 + r;
        int v = 0;
        if (e < E) v = (t < 32) ? src[e] : dst[e];
        sdv[r][t >> 5] = v;
    }
    __syncthreads();
    for (int i = t; i < 32 * 80; i += 256) {
        int r = i / 80, c = i - r * 80;
        long long e = e0 + r;
        short8 v = {0, 0, 0, 0, 0, 0, 0, 0};
        if (e < E) {
            if (c < 32)      v = *(const short8*)(const void*)(xb + (long long)sdv[r][0] * 256 + c * 8);
            else if (c < 64) v = *(const short8*)(const void*)(xb + (long long)sdv[r][1] * 256 + (c - 32) * 8);
            else             v = *(const short8*)(const void*)(ea1 + e * 128 + (c - 64) * 8);
        }
        *(short8*)&At[r][c * 8] = v;
    }
    __syncthreads();

    int w = t >> 6, lane = t & 63;
    int m0 = (w & 1) * 16;
    int nq = (w >> 1) * 4;
    int lr = lane & 15, lq = lane >> 4;

    floatx4 acc[4];
    for (int i = 0; i < 4; ++i) acc[i] = (floatx4){0.f, 0.f, 0.f, 0.f};
    for (int kk = 0; kk < 20; ++kk) {
        short8 a = *(const short8*)&At[m0 + lr][kk * 32 + lq * 8];
        for (int tt = 0; tt < 4; ++tt) {
            short8 b = *(const short8*)(w1s + ((long long)((kk * 8 + nq + tt) * 64 + lane)) * 8);
            acc[tt] = __builtin_amdgcn_mfma_f32_16x16x32_bf16(a, b, acc[tt], 0, 0, 0);
        }
    }
    for (int tt = 0; tt < 4; ++tt) {
        int col = (nq + tt) * 16 + lr;
        float bv = b1f[col];
        for (int r = 0; r < 4; ++r)
            Ht[m0 + lq * 4 + r][col] = (short)f2bf(fmaxf(acc[tt][r] + bv, 0.f));
    }
    __syncthreads();

    floatx4 acc2[4];
    for (int i = 0; i < 4; ++i) acc2[i] = (floatx4){0.f, 0.f, 0.f, 0.f};
    for (int kk = 0; kk < 4; ++kk) {
        short8 a = *(const short8*)&Ht[m0 + lr][kk * 32 + lq * 8];
        for (int tt = 0; tt < 4; ++tt) {
            short8 b = *(const short8*)(w2s + ((long long)((kk * 8 + nq + tt) * 64 + lane)) * 8);
            acc2[tt] = __builtin_amdgcn_mfma_f32_16x16x32_bf16(a, b, acc2[tt], 0, 0, 0);
        }
    }
    for (int tt = 0; tt < 4; ++tt) {
        int col = (nq + tt) * 16 + lr;
        float bv = b2[col];
        for (int r = 0; r < 4; ++r)
            At[m0 + lq * 4 + r][col] = (short)f2bf(acc2[tt][r] + bv);
    }
    __syncthreads();
    for (int i = t; i < 512; i += 256) {
        int r = i >> 4, c = i & 15;
        long long e = e0 + r;
        if (e < E) *(short8*)(void*)(out + e * 128 + c * 8) = *(const short8*)&At[r][c * 8];
    }
}

// ---------- final global MLP + head ----------
__global__ void final_mlp_k(const float* __restrict__ u1bn, const float* __restrict__ pooled,
                            const float* __restrict__ w1, const float* __restrict__ b1,
                            const float* __restrict__ w2, const float* __restrict__ b2,
                            const float* __restrict__ f1w, const float* __restrict__ f1b,
                            const float* __restrict__ f2w, const float* __restrict__ f2b,
                            float* __restrict__ out) {
    __shared__ float ub[256], pb[256], h[256], u2[256];
    int t = threadIdx.x, g = blockIdx.x;
    ub[t] = u1bn[g * 256 + t];
    pb[t] = pooled[g * 256 + t];
    __syncthreads();
    float acc = b1[t];
    for (int k = 0; k < 256; ++k)
        acc += ub[k] * w1[k * 256 + t] + pb[k] * w1[(256 + k) * 256 + t];
    h[t] = fmaxf(acc, 0.f);
    __syncthreads();
    float a2 = b2[t];
    for (int k = 0; k < 256; ++k) a2 += h[k] * w2[k * 256 + t];
    u2[t] = a2;
    __syncthreads();
    float fv = 0.f;
    if (t < 64) {
        float a3 = f1b[t];
        for (int k = 0; k < 256; ++k) a3 += u2[k] * f1w[k * 64 + t];
        fv = fmaxf(a3, 0.f) * f2w[t];
    }
    for (int off = 32; off; off >>= 1) fv += __shfl_down(fv, off, 64);
    if (t == 0) out[g] = fv + f2b[0];
}

// ---------- launch ----------
extern "C" void kernel_launch(void* const* d_in, const int* in_sizes, int n_in,
                              void* d_out, int out_size, void* d_ws, size_t ws_size,
                              hipStream_t stream) {
    const float* x         = (const float*)d_in[0];
    const float* edge_attr = (const float*)d_in[1];
    const float* e1_w1 = (const float*)d_in[2];
    const float* e1_b1 = (const float*)d_in[3];
    const float* e1_w2 = (const float*)d_in[4];
    const float* e1_b2 = (const float*)d_in[5];
    const float* g1_lw = (const float*)d_in[6];
    const float* g1_lb = (const float*)d_in[7];
    const float* g1_rw = (const float*)d_in[8];
    const float* g1_rb = (const float*)d_in[9];
    const float* g1_ew = (const float*)d_in[10];
    const float* g1_att = (const float*)d_in[11];
    const float* g1_bias = (const float*)d_in[12];
    const float* u1_w1 = (const float*)d_in[13];
    const float* u1_b1 = (const float*)d_in[14];
    const float* u1_w2 = (const float*)d_in[15];
    const float* u1_b2 = (const float*)d_in[16];
    const float* bn_n_g = (const float*)d_in[17];
    const float* bn_n_b = (const float*)d_in[18];
    const float* bn_e_g = (const float*)d_in[19];
    const float* bn_e_b = (const float*)d_in[20];
    const float* bn_u_g = (const float*)d_in[21];
    const float* bn_u_b = (const float*)d_in[22];
    const float* e2_w1 = (const float*)d_in[23];
    const float* e2_b1 = (const float*)d_in[24];
    const float* e2_w2 = (const float*)d_in[25];
    const float* e2_b2 = (const float*)d_in[26];
    const float* g2_lw = (const float*)d_in[27];
    const float* g2_lb = (const float*)d_in[28];
    const float* g2_rw = (const float*)d_in[29];
    const float* g2_rb = (const float*)d_in[30];
    const float* g2_ew = (const float*)d_in[31];
    const float* g2_att = (const float*)d_in[32];
    const float* g2_bias = (const float*)d_in[33];
    const float* u2_w1 = (const float*)d_in[34];
    const float* u2_b1 = (const float*)d_in[35];
    const float* u2_w2 = (const float*)d_in[36];
    const float* u2_b2 = (const float*)d_in[37];
    const float* fc1_w = (const float*)d_in[38];
    const float* fc1_b = (const float*)d_in[39];
    const float* fc2_w = (const float*)d_in[40];
    const float* fc2_b = (const float*)d_in[41];
    const int* edge_index = (const int*)d_in[42];
    const int* batch = (const int*)d_in[43];

    const int N = in_sizes[0] / 64;
    const int E = in_sizes[1] / 16;
    const int NT = E + N;
    const int G = G_GRAPHS;
    const int* src = edge_index;
    const int* dst = edge_index + E;

    // workspace carve (~253 MB)
    char* p = (char*)d_ws;
    auto alloc = [&](size_t bytes) { char* r = p; p += (bytes + 255) & ~(size_t)255; return r; };
    bf16* eabuf = (bf16*)alloc((size_t)E * 128 * 2);       // ea1 (eid order); reused as ea2
    bf16* xl    = (bf16*)alloc((size_t)N * 256 * 2);
    bf16* xr    = (bf16*)alloc((size_t)N * 256 * 2);
    bf16* x1bn  = (bf16*)alloc((size_t)N * 256 * 2);
    bf16* eeh   = (bf16*)alloc((size_t)NT * 128 * 2);      // half-channel ee in CSR order
    int* degi   = (int*)alloc((size_t)N * 4);
    int* off    = (int*)alloc((size_t)(N + 1) * 4);
    int* fillc  = (int*)alloc((size_t)N * 4);
    int* csr_src = (int*)alloc((size_t)NT * 4);
    int* slot_of = (int*)alloc((size_t)E * 4);
    float* pooled = (float*)alloc((size_t)G * 256 * 4);
    float* u1bn = (float*)alloc((size_t)G * 256 * 4);
    short* w1s  = (short*)alloc((size_t)20 * 8 * 64 * 8 * 2);
    short* w2s  = (short*)alloc((size_t)4 * 8 * 64 * 8 * 2);
    float* b1f  = (float*)alloc((size_t)128 * 4);
    short* w1s1 = (short*)alloc((size_t)5 * 4 * 64 * 8 * 2);
    short* w2s1 = (short*)alloc((size_t)2 * 8 * 64 * 8 * 2);
    short* ews1 = (short*)alloc((size_t)4 * 16 * 64 * 8 * 2);
    short* ews2 = (short*)alloc((size_t)4 * 16 * 64 * 8 * 2);

    // ===== CSR build =====
    hipMemsetAsync(degi, 0, (size_t)N * 4, stream);
    hipMemsetAsync(fillc, 0, (size_t)N * 4, stream);
    hipMemsetAsync(pooled, 0, (size_t)G * 256 * 4, stream);
    degi_k<<<(E + 255) / 256, 256, 0, stream>>>(dst, degi, E);
    scan_k<<<1, 1024, 0, stream>>>(degi, off, N);
    fill_csr_k<<<(max(E, N) + 255) / 256, 256, 0, stream>>>(src, dst, off, fillc,
                                                            csr_src, slot_of, E, N);

    // ===== layer 1 =====
    conv_weights1_k<<<9, 256, 0, stream>>>(e1_w1, e1_w2, w1s1, w2s1);
    conv_ew_k<<<16, 256, 0, stream>>>(g1_ew, ews1);
    conv_ew_k<<<16, 256, 0, stream>>>(g2_ew, ews2);
    edge_mlp1_mfma_k<<<(E + 31) / 32, 256, 0, stream>>>(x, edge_attr, src, dst,
                                                        w1s1, e1_b1, w2s1, e1_b2, eabuf, E);
    node_linear_k<64, float><<<(N + 3) / 4, 256, 0, stream>>>(x, g1_lw, g1_lb, g1_rw, g1_rb, xl, xr, N);
    // pass 0 (heads 0,1)
    gemm_ee_k<0><<<(E + 31) / 32, 256, 0, stream>>>(eabuf, ews1, slot_of, eeh, E);
    loop_ee_k<<<(N + 3) / 4, 256, 0, stream>>>(eeh, off, N);
    gat_fused_k<0, true><<<(N + 3) / 4, 256, 0, stream>>>(eeh, xl, xr, off, csr_src,
                                                          g1_att, g1_bias, bn_n_g, bn_n_b,
                                                          batch, x1bn, pooled, N);
    // pass 1 (heads 2,3)
    gemm_ee_k<1><<<(E + 31) / 32, 256, 0, stream>>>(eabuf, ews1, slot_of, eeh, E);
    loop_ee_k<<<(N + 3) / 4, 256, 0, stream>>>(eeh, off, N);
    gat_fused_k<1, true><<<(N + 3) / 4, 256, 0, stream>>>(eeh, xl, xr, off, csr_src,
                                                          g1_att, g1_bias, bn_n_g, bn_n_b,
                                                          batch, x1bn, pooled, N);
    global_mlp1_k<<<G, 256, 0, stream>>>(pooled, u1_w1, u1_b1, u1_w2, u1_b2, bn_u_g, bn_u_b, u1bn);

    // ===== layer 2 =====
    conv_weights_k<<<49, 256, 0, stream>>>(e2_w1, e2_w2, e2_b1, bn_e_g, bn_e_b, w1s, w2s, b1f);
    edge_mlp2_mfma_k<<<(E + 31) / 32, 256, 0, stream>>>(x1bn, eabuf, src, dst,
                                                        w1s, b1f, w2s, e2_b2, eabuf, E);
    node_linear_k<256, bf16><<<(N + 3) / 4, 256, 0, stream>>>(x1bn, g2_lw, g2_lb, g2_rw, g2_rb, xl, xr, N);
    hipMemsetAsync(pooled, 0, (size_t)G * 256 * 4, stream);  // after global_mlp1 consumed it
    // pass 0
    gemm_ee_k<0><<<(E + 31) / 32, 256, 0, stream>>>(eabuf, ews2, slot_of, eeh, E);
    loop_ee_k<<<(N + 3) / 4, 256, 0, stream>>>(eeh, off, N);
    gat_fused_k<0, false><<<(N + 3) / 4, 256, 0, stream>>>(eeh, xl, xr, off, csr_src,
                                                           g2_att, g2_bias, nullptr, nullptr,
                                                           batch, nullptr, pooled, N);
    // pass 1
    gemm_ee_k<1><<<(E + 31) / 32, 256, 0, stream>>>(eabuf, ews2, slot_of, eeh, E);
    loop_ee_k<<<(N + 3) / 4, 256, 0, stream>>>(eeh, off, N);
    gat_fused_k<1, false><<<(N + 3) / 4, 256, 0, stream>>>(eeh, xl, xr, off, csr_src,
                                                           g2_att, g2_bias, nullptr, nullptr,
                                                           batch, nullptr, pooled, N);
    final_mlp_k<<<G, 256, 0, stream>>>(u1bn, pooled, u2_w1, u2_b1, u2_w2, u2_b2,
                                       fc1_w, fc1_b, fc2_w, fc2_b, (float*)d_out);
}

// Round 9
// 1320.657 us; speedup vs baseline: 3.8358x; 1.2385x over previous
//
#include <hip/hip_runtime.h>
#include <hip/hip_bf16.h>
#include <cstdint>
#include <cstddef>

#define INVS 0.99999500003749968f  // 1/sqrt(1+1e-5)
#define G_GRAPHS 256

using bf16 = __hip_bfloat16;
using short8 = __attribute__((ext_vector_type(8))) short;
using floatx4 = __attribute__((ext_vector_type(4))) float;

// ---------- helpers ----------
__device__ __forceinline__ float ldv(const float* p, long long i) { return p[i]; }
__device__ __forceinline__ float ldv(const bf16* p, long long i) { return __bfloat162float(p[i]); }

__device__ __forceinline__ unsigned short f2bf(float v) {
    union { float f; unsigned u; } x; x.f = v;
    unsigned r = x.u + 0x7fffu + ((x.u >> 16) & 1u);
    return (unsigned short)(r >> 16);
}
__device__ __forceinline__ float bflo(unsigned u) { return __uint_as_float(u << 16); }
__device__ __forceinline__ float bfhi(unsigned u) { return __uint_as_float(u & 0xffff0000u); }

// ---------- CSR build ----------
__global__ void degi_k(const int* __restrict__ dst, int* __restrict__ degi, int E) {
    int gid = blockIdx.x * 256 + threadIdx.x;
    if (gid < E) atomicAdd(&degi[dst[gid]], 1);
}

__global__ void scan_k(const int* __restrict__ degi, int* __restrict__ off, int N) {
    __shared__ int buf[1024];
    __shared__ int carry;
    int t = threadIdx.x;
    if (t == 0) carry = 0;
    __syncthreads();
    int nch = (N + 1023) / 1024;
    for (int ch = 0; ch < nch; ++ch) {
        int idx = ch * 1024 + t;
        int v = (idx < N) ? (degi[idx] + 1) : 0;
        buf[t] = v;
        __syncthreads();
        for (int ofs = 1; ofs < 1024; ofs <<= 1) {
            int add = (t >= ofs) ? buf[t - ofs] : 0;
            __syncthreads();
            buf[t] += add;
            __syncthreads();
        }
        int incl = buf[t];
        if (idx < N) off[idx] = carry + incl - v;
        __syncthreads();
        if (t == 1023) carry += incl;
        __syncthreads();
    }
    if (t == 0) off[N] = carry;
}

__global__ void fill_csr_k(const int* __restrict__ src, const int* __restrict__ dst,
                           const int* __restrict__ off, int* __restrict__ fillc,
                           int* __restrict__ csr_src, int* __restrict__ slot_of,
                           int E, int N) {
    int gid = blockIdx.x * 256 + threadIdx.x;
    if (gid < E) {
        int d = dst[gid];
        int slot = off[d] + atomicAdd(&fillc[d], 1);
        csr_src[slot] = src[gid];
        slot_of[gid] = slot;
    }
    if (gid < N) {
        csr_src[off[gid + 1] - 1] = gid;   // self-loop slot
    }
}

// ---------- weight prep for MFMA edge MLP1 ----------
__global__ void conv_weights1_k(const float* __restrict__ w1, const float* __restrict__ w2,
                                short* __restrict__ w1s, short* __restrict__ w2s) {
    int gid = blockIdx.x * 256 + threadIdx.x;
    if (gid < 1280) {
        int f = gid >> 6, lane = gid & 63;
        int kk = f >> 2, tt = f & 3;
        int n = tt * 16 + (lane & 15);
        int k0 = kk * 32 + (lane >> 4) * 8;
        short8 v;
        for (int j = 0; j < 8; ++j) {
            int k = k0 + j;
            v[j] = (k < 144) ? (short)f2bf(w1[k * 64 + n]) : (short)0;
        }
        *(short8*)(w1s + (long long)gid * 8) = v;
    } else if (gid < 2304) {
        int g2 = gid - 1280;
        int f = g2 >> 6, lane = g2 & 63;
        int kk = f >> 3, tt = f & 7;
        int n = tt * 16 + (lane & 15);
        int k0 = kk * 32 + (lane >> 4) * 8;
        short8 v;
        for (int j = 0; j < 8; ++j) v[j] = (short)f2bf(w2[(k0 + j) * 128 + n]);
        *(short8*)(w2s + (long long)g2 * 8) = v;
    }
}

// ---------- ew prep: ew[128][256] -> frags 4 kk x 16 tt ----------
__global__ void conv_ew_k(const float* __restrict__ ew, short* __restrict__ ews) {
    int gid = blockIdx.x * 256 + threadIdx.x;
    if (gid >= 4096) return;
    int f = gid >> 6, lane = gid & 63;
    int kk = f >> 4, tt = f & 15;
    int n = tt * 16 + (lane & 15);
    int k0 = kk * 32 + (lane >> 4) * 8;
    short8 v;
    for (int j = 0; j < 8; ++j) v[j] = (short)f2bf(ew[(k0 + j) * 256 + n]);
    *(short8*)(ews + (long long)gid * 8) = v;
}

// ---------- node-linear weight prep: [wl|wr] (K x 512) -> frags K/32 kk x 32 tt ----------
template <int K>
__global__ void conv_nodew_k(const float* __restrict__ wl, const float* __restrict__ wr,
                             short* __restrict__ out) {
    int gid = blockIdx.x * 256 + threadIdx.x;
    if (gid >= (K / 32) * 32 * 64) return;
    int f = gid >> 6, lane = gid & 63;
    int kk = f >> 5, tt = f & 31;
    int n = tt * 16 + (lane & 15);
    int k0 = kk * 32 + (lane >> 4) * 8;
    short8 v;
    for (int j = 0; j < 8; ++j) {
        int k = k0 + j;
        float x = (n < 256) ? wl[k * 256 + n] : wr[k * 256 + (n - 256)];
        v[j] = (short)f2bf(x);
    }
    *(short8*)(out + (long long)gid * 8) = v;
}

// ---------- Edge MLP 1 via MFMA ----------
__global__ __launch_bounds__(256) void edge_mlp1_mfma_k(
    const float* __restrict__ x, const float* __restrict__ ea,
    const int* __restrict__ src, const int* __restrict__ dst,
    const short* __restrict__ w1s, const float* __restrict__ b1,
    const short* __restrict__ w2s, const float* __restrict__ b2,
    bf16* __restrict__ out, int E) {
    __shared__ short At[32][168];
    __shared__ short Ht[32][72];
    __shared__ int sdv[32][2];
    int t = threadIdx.x;
    long long e0 = (long long)blockIdx.x * 32;
    if (t < 64) {
        int r = t & 31;
        long long e = e0 + r;
        int v = 0;
        if (e < E) v = (t < 32) ? src[e] : dst[e];
        sdv[r][t >> 5] = v;
    }
    __syncthreads();
    for (int i = t; i < 32 * 40; i += 256) {
        int r = i / 40, c = i - r * 40;
        long long e = e0 + r;
        float4 v = {0.f, 0.f, 0.f, 0.f};
        if (e < E) {
            if (c < 16)      v = *(const float4*)(x + (long long)sdv[r][0] * 64 + c * 4);
            else if (c < 32) v = *(const float4*)(x + (long long)sdv[r][1] * 64 + (c - 16) * 4);
            else if (c < 36) v = *(const float4*)(ea + e * 16 + (c - 32) * 4);
        }
        union { ushort4 u4; unsigned short s[4]; } pk;
        pk.s[0] = f2bf(v.x); pk.s[1] = f2bf(v.y); pk.s[2] = f2bf(v.z); pk.s[3] = f2bf(v.w);
        *(ushort4*)&At[r][c * 4] = pk.u4;
    }
    __syncthreads();

    int w = t >> 6, lane = t & 63;
    int m0 = (w & 1) * 16;
    int lr = lane & 15, lq = lane >> 4;

    int nq1 = (w >> 1) * 2;
    floatx4 acc[2];
    for (int i = 0; i < 2; ++i) acc[i] = (floatx4){0.f, 0.f, 0.f, 0.f};
    for (int kk = 0; kk < 5; ++kk) {
        short8 a = *(const short8*)&At[m0 + lr][kk * 32 + lq * 8];
        for (int tt = 0; tt < 2; ++tt) {
            short8 b = *(const short8*)(w1s + ((long long)((kk * 4 + nq1 + tt) * 64 + lane)) * 8);
            acc[tt] = __builtin_amdgcn_mfma_f32_16x16x32_bf16(a, b, acc[tt], 0, 0, 0);
        }
    }
    for (int tt = 0; tt < 2; ++tt) {
        int col = (nq1 + tt) * 16 + lr;
        float bv = b1[col];
        for (int r = 0; r < 4; ++r)
            Ht[m0 + lq * 4 + r][col] = (short)f2bf(fmaxf(acc[tt][r] + bv, 0.f));
    }
    __syncthreads();

    int nq2 = (w >> 1) * 4;
    floatx4 acc2[4];
    for (int i = 0; i < 4; ++i) acc2[i] = (floatx4){0.f, 0.f, 0.f, 0.f};
    for (int kk = 0; kk < 2; ++kk) {
        short8 a = *(const short8*)&Ht[m0 + lr][kk * 32 + lq * 8];
        for (int tt = 0; tt < 4; ++tt) {
            short8 b = *(const short8*)(w2s + ((long long)((kk * 8 + nq2 + tt) * 64 + lane)) * 8);
            acc2[tt] = __builtin_amdgcn_mfma_f32_16x16x32_bf16(a, b, acc2[tt], 0, 0, 0);
        }
    }
    for (int tt = 0; tt < 4; ++tt) {
        int col = (nq2 + tt) * 16 + lr;
        float bv = b2[col];
        for (int r = 0; r < 4; ++r)
            At[m0 + lq * 4 + r][col] = (short)f2bf(acc2[tt][r] + bv);
    }
    __syncthreads();
    for (int i = t; i < 512; i += 256) {
        int r = i >> 4, c = i & 15;
        long long e = e0 + r;
        if (e < E) *(short8*)(void*)(out + e * 128 + c * 8) = *(const short8*)&At[r][c * 8];
    }
}

// ---------- node linear via MFMA: [N x K] @ [K x 512] (= [wl|wr]) + bias ----------
// 16 nodes/block, 4 waves; wave w owns 8 n-tiles (128 cols) of the 512.
template <int K, typename T>
__global__ __launch_bounds__(256) void node_linear_mfma_k(
    const T* __restrict__ x, const short* __restrict__ ws,
    const float* __restrict__ bl, const float* __restrict__ br,
    bf16* __restrict__ xl, bf16* __restrict__ xr, int N) {
    __shared__ short At[16][K + 8];
    __shared__ short Ot[16][520];
    int t = threadIdx.x;
    long long n0 = (long long)blockIdx.x * 16;
    if (sizeof(T) == 4) {  // fp32 input -> convert
        for (int i = t; i < 16 * (K / 4); i += 256) {
            int r = i / (K / 4), c = i % (K / 4);
            long long n = n0 + r;
            float4 v = {0.f, 0.f, 0.f, 0.f};
            if (n < N) v = *(const float4*)((const float*)x + n * K + c * 4);
            union { ushort4 u4; unsigned short s[4]; } pk;
            pk.s[0] = f2bf(v.x); pk.s[1] = f2bf(v.y); pk.s[2] = f2bf(v.z); pk.s[3] = f2bf(v.w);
            *(ushort4*)&At[r][c * 4] = pk.u4;
        }
    } else {               // bf16 input
        for (int i = t; i < 16 * (K / 8); i += 256) {
            int r = i / (K / 8), c = i % (K / 8);
            long long n = n0 + r;
            short8 v = {0, 0, 0, 0, 0, 0, 0, 0};
            if (n < N) v = *(const short8*)(const void*)((const bf16*)x + n * K + c * 8);
            *(short8*)&At[r][c * 8] = v;
        }
    }
    __syncthreads();

    int w = t >> 6, lane = t & 63;
    int nq = w * 8;
    int lr = lane & 15, lq = lane >> 4;

    floatx4 acc[8];
    for (int i = 0; i < 8; ++i) acc[i] = (floatx4){0.f, 0.f, 0.f, 0.f};
    for (int kk = 0; kk < K / 32; ++kk) {
        short8 a = *(const short8*)&At[lr][kk * 32 + lq * 8];
        for (int tt = 0; tt < 8; ++tt) {
            short8 b = *(const short8*)(ws + ((long long)((kk * 32 + nq + tt) * 64 + lane)) * 8);
            acc[tt] = __builtin_amdgcn_mfma_f32_16x16x32_bf16(a, b, acc[tt], 0, 0, 0);
        }
    }
    for (int tt = 0; tt < 8; ++tt) {
        int col = (nq + tt) * 16 + lr;
        float bv = (col < 256) ? bl[col] : br[col - 256];
        for (int r = 0; r < 4; ++r)
            Ot[lq * 4 + r][col] = (short)f2bf(acc[tt][r] + bv);
    }
    __syncthreads();
    for (int i = t; i < 1024; i += 256) {
        int r = i >> 6, c = i & 63;
        long long n = n0 + r;
        if (n < N) {
            short8 v = *(const short8*)&Ot[r][c * 8];
            if (c < 32) *(short8*)(void*)(xl + n * 256 + c * 8) = v;
            else        *(short8*)(void*)(xr + n * 256 + (c - 32) * 8) = v;
        }
    }
}

// ---------- ee GEMM (half channels): ee[slot][0:128] = ea[e] @ ew[:, PASS*128 : +128] ----------
template <int PASS>
__global__ __launch_bounds__(256) void gemm_ee_k(
    const bf16* __restrict__ ea, const short* __restrict__ ews,
    const int* __restrict__ slot_of, bf16* __restrict__ eeh, int E) {
    __shared__ short At[32][136];
    __shared__ short Et[32][136];
    __shared__ int slt[32];
    int t = threadIdx.x;
    long long e0 = (long long)blockIdx.x * 32;
    if (t < 32) {
        long long e = e0 + t;
        slt[t] = (e < E) ? slot_of[e] : -1;
    }
    for (int i = t; i < 32 * 16; i += 256) {
        int r = i >> 4, c = i & 15;
        long long e = e0 + r;
        short8 v = {0, 0, 0, 0, 0, 0, 0, 0};
        if (e < E) v = *(const short8*)(const void*)(ea + e * 128 + c * 8);
        *(short8*)&At[r][c * 8] = v;
    }
    __syncthreads();

    int w = t >> 6, lane = t & 63;
    int m0 = (w & 1) * 16, nq = (w >> 1) * 4;
    int lr = lane & 15, lq = lane >> 4;

    floatx4 acc[4];
    for (int i = 0; i < 4; ++i) acc[i] = (floatx4){0.f, 0.f, 0.f, 0.f};
    for (int kk = 0; kk < 4; ++kk) {
        short8 a = *(const short8*)&At[m0 + lr][kk * 32 + lq * 8];
        for (int tt = 0; tt < 4; ++tt) {
            short8 b = *(const short8*)(ews + ((long long)((kk * 16 + PASS * 8 + nq + tt) * 64 + lane)) * 8);
            acc[tt] = __builtin_amdgcn_mfma_f32_16x16x32_bf16(a, b, acc[tt], 0, 0, 0);
        }
    }
    for (int tt = 0; tt < 4; ++tt) {
        int col = (nq + tt) * 16 + lr;
        for (int r = 0; r < 4; ++r)
            Et[m0 + lq * 4 + r][col] = (short)f2bf(acc[tt][r]);
    }
    __syncthreads();
    {
        int r = t >> 3, c = t & 7;
        int s = slt[r];
        if (s >= 0)
            *(short8*)(void*)(eeh + (long long)s * 128 + c * 8) = *(const short8*)&Et[r][c * 8];
    }
}

// ---------- self-loop ee = mean of incoming ee rows ----------
__global__ __launch_bounds__(256) void loop_ee_k(bf16* __restrict__ eeh,
                                                 const int* __restrict__ off, int N) {
    int t = threadIdx.x;
    int w = t >> 6, lane = t & 63;
    int n = blockIdx.x * 4 + w;
    if (n >= N) return;
    int beg = off[n], end = off[n + 1] - 1;
    float a0 = 0.f, a1 = 0.f;
    for (int i = beg; i < end; ++i) {
        unsigned pk = *(const unsigned*)(const void*)(eeh + (long long)i * 128 + lane * 2);
        a0 += bflo(pk);
        a1 += bfhi(pk);
    }
    float dv = fmaxf((float)(end - beg), 1.f);
    unsigned o = ((unsigned)f2bf(a1 / dv) << 16) | (unsigned)f2bf(a0 / dv);
    *(unsigned*)(void*)(eeh + (long long)end * 128 + lane * 2) = o;
}

// ---------- Fused GATv2 attention + aggregation + finalize (half channels / 2 heads) ----------
template <int PASS, bool L1>
__global__ __launch_bounds__(256) void gat_fused_k(
    const bf16* __restrict__ eeh, const bf16* __restrict__ xl, const bf16* __restrict__ xr,
    const int* __restrict__ off, const int* __restrict__ csr_src,
    const float* __restrict__ att, const float* __restrict__ bias,
    const float* __restrict__ bng, const float* __restrict__ bnb,
    const int* __restrict__ batch,
    bf16* __restrict__ x1bn, float* __restrict__ pooled, int N) {
    int t = threadIdx.x;
    int w = t >> 6, lane = t & 63;
    int n = blockIdx.x * 4 + w;
    if (n >= N) return;
    int c = lane * 2;
    int gc = PASS * 128 + c;
    unsigned xrp = *(const unsigned*)(const void*)(xr + (long long)n * 256 + gc);
    float xr0 = bflo(xrp), xr1 = bfhi(xrp);
    float at0 = att[gc], at1 = att[gc + 1];
    float a0 = 0.f, a1 = 0.f, dacc = 0.f;
    int beg = off[n], end = off[n + 1];
    for (int i = beg; i < end; ++i) {
        int sid = csr_src[i];
        unsigned xlp = *(const unsigned*)(const void*)(xl + (long long)sid * 256 + gc);
        unsigned eep = *(const unsigned*)(const void*)(eeh + (long long)i * 128 + c);
        float x0 = bflo(xlp), x1v = bfhi(xlp);
        float m0 = x0 + xr0 + bflo(eep);
        float m1 = x1v + xr1 + bfhi(eep);
        m0 = m0 > 0.f ? m0 : 0.2f * m0;
        m1 = m1 > 0.f ? m1 : 0.2f * m1;
        float p = at0 * m0 + at1 * m1;
        p += __shfl_xor(p, 1, 64);
        p += __shfl_xor(p, 2, 64);
        p += __shfl_xor(p, 4, 64);
        p += __shfl_xor(p, 8, 64);
        p += __shfl_xor(p, 16, 64);
        float ex = expf(p);
        a0 += ex * x0; a1 += ex * x1v; dacc += ex;
    }
    float inv = 1.f / dacc;
    float o0 = fmaxf(a0 * inv + bias[gc],     0.f);
    float o1 = fmaxf(a1 * inv + bias[gc + 1], 0.f);
    long long pb = (long long)batch[n] * 256 + gc;
    atomicAdd(&pooled[pb],     o0);
    atomicAdd(&pooled[pb + 1], o1);
    if (L1) {
        unsigned pk = ((unsigned)f2bf(bng[gc + 1] * (o1 * INVS) + bnb[gc + 1]) << 16)
                    | (unsigned)f2bf(bng[gc] * (o0 * INVS) + bnb[gc]);
        *(unsigned*)(void*)(x1bn + (long long)n * 256 + gc) = pk;
    }
}

// ---------- global MLP layer1 ----------
__global__ void global_mlp1_k(const float* __restrict__ pooled,
                              const float* __restrict__ w1, const float* __restrict__ b1,
                              const float* __restrict__ w2, const float* __restrict__ b2,
                              const float* __restrict__ bng, const float* __restrict__ bnb,
                              float* __restrict__ u1bn) {
    __shared__ float pr[256];
    __shared__ float h[256];
    int t = threadIdx.x, g = blockIdx.x;
    pr[t] = pooled[g * 256 + t];
    __syncthreads();
    float acc = b1[t];
    for (int k = 0; k < 256; ++k) acc += pr[k] * w1[(256 + k) * 256 + t];
    h[t] = fmaxf(acc, 0.f);
    __syncthreads();
    float a2 = b2[t];
    for (int k = 0; k < 256; ++k) a2 += h[k] * w2[k * 256 + t];
    u1bn[g * 256 + t] = bng[t] * (a2 * INVS) + bnb[t];
}

// ---------- weight prep for MFMA edge MLP2 ----------
__global__ void conv_weights_k(const float* __restrict__ w1, const float* __restrict__ w2,
                               const float* __restrict__ b1,
                               const float* __restrict__ bg, const float* __restrict__ bb,
                               short* __restrict__ w1s, short* __restrict__ w2s,
                               float* __restrict__ b1f) {
    int gid = blockIdx.x * 256 + threadIdx.x;
    if (gid < 10240) {
        int f = gid >> 6, lane = gid & 63;
        int kk = f >> 3, tt = f & 7;
        int n = tt * 16 + (lane & 15);
        int k0 = kk * 32 + (lane >> 4) * 8;
        short8 v;
        for (int j = 0; j < 8; ++j) {
            int k = k0 + j;
            float x = w1[k * 128 + n];
            if (k >= 512) x *= bg[k - 512] * INVS;
            v[j] = (short)f2bf(x);
        }
        *(short8*)(w1s + (long long)gid * 8) = v;
    } else if (gid < 12288) {
        int g2 = gid - 10240;
        int f = g2 >> 6, lane = g2 & 63;
        int kk = f >> 3, tt = f & 7;
        int n = tt * 16 + (lane & 15);
        int k0 = kk * 32 + (lane >> 4) * 8;
        short8 v;
        for (int j = 0; j < 8; ++j) v[j] = (short)f2bf(w2[(k0 + j) * 128 + n]);
        *(short8*)(w2s + (long long)g2 * 8) = v;
    } else if (gid < 12416) {
        int j = gid - 12288;
        float acc = b1[j];
        for (int c = 0; c < 128; ++c) acc += bb[c] * w1[(512 + c) * 128 + j];
        b1f[j] = acc;
    }
}

// ---------- Edge MLP 2 via MFMA ----------
__global__ __launch_bounds__(256) void edge_mlp2_mfma_k(
    const bf16* __restrict__ xb, const bf16* __restrict__ ea1,
    const int* __restrict__ src, const int* __restrict__ dst,
    const short* __restrict__ w1s, const float* __restrict__ b1f,
    const short* __restrict__ w2s, const float* __restrict__ b2,
    bf16* __restrict__ out, int E) {
    __shared__ short At[32][648];
    __shared__ short Ht[32][136];
    __shared__ int sdv[32][2];
    int t = threadIdx.x;
    long long e0 = (long long)blockIdx.x * 32;
    if (t < 64) {
        int r = t & 31;
        long long e = e0 + r;
        int v = 0;
        if (e < E) v = (t < 32) ? src[e] : dst[e];
        sdv[r][t >> 5] = v;
    }
    __syncthreads();
    for (int i = t; i < 32 * 80; i += 256) {
        int r = i / 80, c = i - r * 80;
        long long e = e0 + r;
        short8 v = {0, 0, 0, 0, 0, 0, 0, 0};
        if (e < E) {
            if (c < 32)      v = *(const short8*)(const void*)(xb + (long long)sdv[r][0] * 256 + c * 8);
            else if (c < 64) v = *(const short8*)(const void*)(xb + (long long)sdv[r][1] * 256 + (c - 32) * 8);
            else             v = *(const short8*)(const void*)(ea1 + e * 128 + (c - 64) * 8);
        }
        *(short8*)&At[r][c * 8] = v;
    }
    __syncthreads();

    int w = t >> 6, lane = t & 63;
    int m0 = (w & 1) * 16;
    int nq = (w >> 1) * 4;
    int lr = lane & 15, lq = lane >> 4;

    floatx4 acc[4];
    for (int i = 0; i < 4; ++i) acc[i] = (floatx4){0.f, 0.f, 0.f, 0.f};
    for (int kk = 0; kk < 20; ++kk) {
        short8 a = *(const short8*)&At[m0 + lr][kk * 32 + lq * 8];
        for (int tt = 0; tt < 4; ++tt) {
            short8 b = *(const short8*)(w1s + ((long long)((kk * 8 + nq + tt) * 64 + lane)) * 8);
            acc[tt] = __builtin_amdgcn_mfma_f32_16x16x32_bf16(a, b, acc[tt], 0, 0, 0);
        }
    }
    for (int tt = 0; tt < 4; ++tt) {
        int col = (nq + tt) * 16 + lr;
        float bv = b1f[col];
        for (int r = 0; r < 4; ++r)
            Ht[m0 + lq * 4 + r][col] = (short)f2bf(fmaxf(acc[tt][r] + bv, 0.f));
    }
    __syncthreads();

    floatx4 acc2[4];
    for (int i = 0; i < 4; ++i) acc2[i] = (floatx4){0.f, 0.f, 0.f, 0.f};
    for (int kk = 0; kk < 4; ++kk) {
        short8 a = *(const short8*)&Ht[m0 + lr][kk * 32 + lq * 8];
        for (int tt = 0; tt < 4; ++tt) {
            short8 b = *(const short8*)(w2s + ((long long)((kk * 8 + nq + tt) * 64 + lane)) * 8);
            acc2[tt] = __builtin_amdgcn_mfma_f32_16x16x32_bf16(a, b, acc2[tt], 0, 0, 0);
        }
    }
    for (int tt = 0; tt < 4; ++tt) {
        int col = (nq + tt) * 16 + lr;
        float bv = b2[col];
        for (int r = 0; r < 4; ++r)
            At[m0 + lq * 4 + r][col] = (short)f2bf(acc2[tt][r] + bv);
    }
    __syncthreads();
    for (int i = t; i < 512; i += 256) {
        int r = i >> 4, c = i & 15;
        long long e = e0 + r;
        if (e < E) *(short8*)(void*)(out + e * 128 + c * 8) = *(const short8*)&At[r][c * 8];
    }
}

// ---------- final global MLP + head ----------
__global__ void final_mlp_k(const float* __restrict__ u1bn, const float* __restrict__ pooled,
                            const float* __restrict__ w1, const float* __restrict__ b1,
                            const float* __restrict__ w2, const float* __restrict__ b2,
                            const float* __restrict__ f1w, const float* __restrict__ f1b,
                            const float* __restrict__ f2w, const float* __restrict__ f2b,
                            float* __restrict__ out) {
    __shared__ float ub[256], pb[256], h[256], u2[256];
    int t = threadIdx.x, g = blockIdx.x;
    ub[t] = u1bn[g * 256 + t];
    pb[t] = pooled[g * 256 + t];
    __syncthreads();
    float acc = b1[t];
    for (int k = 0; k < 256; ++k)
        acc += ub[k] * w1[k * 256 + t] + pb[k] * w1[(256 + k) * 256 + t];
    h[t] = fmaxf(acc, 0.f);
    __syncthreads();
    float a2 = b2[t];
    for (int k = 0; k < 256; ++k) a2 += h[k] * w2[k * 256 + t];
    u2[t] = a2;
    __syncthreads();
    float fv = 0.f;
    if (t < 64) {
        float a3 = f1b[t];
        for (int k = 0; k < 256; ++k) a3 += u2[k] * f1w[k * 64 + t];
        fv = fmaxf(a3, 0.f) * f2w[t];
    }
    for (int off = 32; off; off >>= 1) fv += __shfl_down(fv, off, 64);
    if (t == 0) out[g] = fv + f2b[0];
}

// ---------- launch ----------
extern "C" void kernel_launch(void* const* d_in, const int* in_sizes, int n_in,
                              void* d_out, int out_size, void* d_ws, size_t ws_size,
                              hipStream_t stream) {
    const float* x         = (const float*)d_in[0];
    const float* edge_attr = (const float*)d_in[1];
    const float* e1_w1 = (const float*)d_in[2];
    const float* e1_b1 = (const float*)d_in[3];
    const float* e1_w2 = (const float*)d_in[4];
    const float* e1_b2 = (const float*)d_in[5];
    const float* g1_lw = (const float*)d_in[6];
    const float* g1_lb = (const float*)d_in[7];
    const float* g1_rw = (const float*)d_in[8];
    const float* g1_rb = (const float*)d_in[9];
    const float* g1_ew = (const float*)d_in[10];
    const float* g1_att = (const float*)d_in[11];
    const float* g1_bias = (const float*)d_in[12];
    const float* u1_w1 = (const float*)d_in[13];
    const float* u1_b1 = (const float*)d_in[14];
    const float* u1_w2 = (const float*)d_in[15];
    const float* u1_b2 = (const float*)d_in[16];
    const float* bn_n_g = (const float*)d_in[17];
    const float* bn_n_b = (const float*)d_in[18];
    const float* bn_e_g = (const float*)d_in[19];
    const float* bn_e_b = (const float*)d_in[20];
    const float* bn_u_g = (const float*)d_in[21];
    const float* bn_u_b = (const float*)d_in[22];
    const float* e2_w1 = (const float*)d_in[23];
    const float* e2_b1 = (const float*)d_in[24];
    const float* e2_w2 = (const float*)d_in[25];
    const float* e2_b2 = (const float*)d_in[26];
    const float* g2_lw = (const float*)d_in[27];
    const float* g2_lb = (const float*)d_in[28];
    const float* g2_rw = (const float*)d_in[29];
    const float* g2_rb = (const float*)d_in[30];
    const float* g2_ew = (const float*)d_in[31];
    const float* g2_att = (const float*)d_in[32];
    const float* g2_bias = (const float*)d_in[33];
    const float* u2_w1 = (const float*)d_in[34];
    const float* u2_b1 = (const float*)d_in[35];
    const float* u2_w2 = (const float*)d_in[36];
    const float* u2_b2 = (const float*)d_in[37];
    const float* fc1_w = (const float*)d_in[38];
    const float* fc1_b = (const float*)d_in[39];
    const float* fc2_w = (const float*)d_in[40];
    const float* fc2_b = (const float*)d_in[41];
    const int* edge_index = (const int*)d_in[42];
    const int* batch = (const int*)d_in[43];

    const int N = in_sizes[0] / 64;
    const int E = in_sizes[1] / 16;
    const int NT = E + N;
    const int G = G_GRAPHS;
    const int* src = edge_index;
    const int* dst = edge_index + E;

    // workspace carve (~254 MB)
    char* p = (char*)d_ws;
    auto alloc = [&](size_t bytes) { char* r = p; p += (bytes + 255) & ~(size_t)255; return r; };
    bf16* eabuf = (bf16*)alloc((size_t)E * 128 * 2);
    bf16* xl    = (bf16*)alloc((size_t)N * 256 * 2);
    bf16* xr    = (bf16*)alloc((size_t)N * 256 * 2);
    bf16* x1bn  = (bf16*)alloc((size_t)N * 256 * 2);
    bf16* eeh   = (bf16*)alloc((size_t)NT * 128 * 2);
    int* degi   = (int*)alloc((size_t)N * 4);
    int* off    = (int*)alloc((size_t)(N + 1) * 4);
    int* fillc  = (int*)alloc((size_t)N * 4);
    int* csr_src = (int*)alloc((size_t)NT * 4);
    int* slot_of = (int*)alloc((size_t)E * 4);
    float* pooled = (float*)alloc((size_t)G * 256 * 4);
    float* u1bn = (float*)alloc((size_t)G * 256 * 4);
    short* w1s  = (short*)alloc((size_t)20 * 8 * 64 * 8 * 2);
    short* w2s  = (short*)alloc((size_t)4 * 8 * 64 * 8 * 2);
    float* b1f  = (float*)alloc((size_t)128 * 4);
    short* w1s1 = (short*)alloc((size_t)5 * 4 * 64 * 8 * 2);
    short* w2s1 = (short*)alloc((size_t)2 * 8 * 64 * 8 * 2);
    short* ews1 = (short*)alloc((size_t)4 * 16 * 64 * 8 * 2);
    short* ews2 = (short*)alloc((size_t)4 * 16 * 64 * 8 * 2);
    short* nw1  = (short*)alloc((size_t)2 * 32 * 64 * 8 * 2);   // node weights L1 (K=64)
    short* nw2  = (short*)alloc((size_t)8 * 32 * 64 * 8 * 2);   // node weights L2 (K=256)

    // ===== CSR build =====
    hipMemsetAsync(degi, 0, (size_t)N * 4, stream);
    hipMemsetAsync(fillc, 0, (size_t)N * 4, stream);
    hipMemsetAsync(pooled, 0, (size_t)G * 256 * 4, stream);
    degi_k<<<(E + 255) / 256, 256, 0, stream>>>(dst, degi, E);
    scan_k<<<1, 1024, 0, stream>>>(degi, off, N);
    fill_csr_k<<<(max(E, N) + 255) / 256, 256, 0, stream>>>(src, dst, off, fillc,
                                                            csr_src, slot_of, E, N);

    // ===== layer 1 =====
    conv_weights1_k<<<9, 256, 0, stream>>>(e1_w1, e1_w2, w1s1, w2s1);
    conv_ew_k<<<16, 256, 0, stream>>>(g1_ew, ews1);
    conv_ew_k<<<16, 256, 0, stream>>>(g2_ew, ews2);
    conv_nodew_k<64><<<16, 256, 0, stream>>>(g1_lw, g1_rw, nw1);
    conv_nodew_k<256><<<64, 256, 0, stream>>>(g2_lw, g2_rw, nw2);
    edge_mlp1_mfma_k<<<(E + 31) / 32, 256, 0, stream>>>(x, edge_attr, src, dst,
                                                        w1s1, e1_b1, w2s1, e1_b2, eabuf, E);
    node_linear_mfma_k<64, float><<<(N + 15) / 16, 256, 0, stream>>>(x, nw1, g1_lb, g1_rb, xl, xr, N);
    // pass 0 (heads 0,1)
    gemm_ee_k<0><<<(E + 31) / 32, 256, 0, stream>>>(eabuf, ews1, slot_of, eeh, E);
    loop_ee_k<<<(N + 3) / 4, 256, 0, stream>>>(eeh, off, N);
    gat_fused_k<0, true><<<(N + 3) / 4, 256, 0, stream>>>(eeh, xl, xr, off, csr_src,
                                                          g1_att, g1_bias, bn_n_g, bn_n_b,
                                                          batch, x1bn, pooled, N);
    // pass 1 (heads 2,3)
    gemm_ee_k<1><<<(E + 31) / 32, 256, 0, stream>>>(eabuf, ews1, slot_of, eeh, E);
    loop_ee_k<<<(N + 3) / 4, 256, 0, stream>>>(eeh, off, N);
    gat_fused_k<1, true><<<(N + 3) / 4, 256, 0, stream>>>(eeh, xl, xr, off, csr_src,
                                                          g1_att, g1_bias, bn_n_g, bn_n_b,
                                                          batch, x1bn, pooled, N);
    global_mlp1_k<<<G, 256, 0, stream>>>(pooled, u1_w1, u1_b1, u1_w2, u1_b2, bn_u_g, bn_u_b, u1bn);

    // ===== layer 2 =====
    conv_weights_k<<<49, 256, 0, stream>>>(e2_w1, e2_w2, e2_b1, bn_e_g, bn_e_b, w1s, w2s, b1f);
    edge_mlp2_mfma_k<<<(E + 31) / 32, 256, 0, stream>>>(x1bn, eabuf, src, dst,
                                                        w1s, b1f, w2s, e2_b2, eabuf, E);
    node_linear_mfma_k<256, bf16><<<(N + 15) / 16, 256, 0, stream>>>(x1bn, nw2, g2_lb, g2_rb, xl, xr, N);
    hipMemsetAsync(pooled, 0, (size_t)G * 256 * 4, stream);
    // pass 0
    gemm_ee_k<0><<<(E + 31) / 32, 256, 0, stream>>>(eabuf, ews2, slot_of, eeh, E);
    loop_ee_k<<<(N + 3) / 4, 256, 0, stream>>>(eeh, off, N);
    gat_fused_k<0, false><<<(N + 3) / 4, 256, 0, stream>>>(eeh, xl, xr, off, csr_src,
                                                           g2_att, g2_bias, nullptr, nullptr,
                                                           batch, nullptr, pooled, N);
    // pass 1
    gemm_ee_k<1><<<(E + 31) / 32, 256, 0, stream>>>(eabuf, ews2, slot_of, eeh, E);
    loop_ee_k<<<(N + 3) / 4, 256, 0, stream>>>(eeh, off, N);
    gat_fused_k<1, false><<<(N + 3) / 4, 256, 0, stream>>>(eeh, xl, xr, off, csr_src,
                                                           g2_att, g2_bias, nullptr, nullptr,
                                                           batch, nullptr, pooled, N);
    final_mlp_k<<<G, 256, 0, stream>>>(u1bn, pooled, u2_w1, u2_b1, u2_w2, u2_b2,
                                       fc1_w, fc1_b, fc2_w, fc2_b, (float*)d_out);
}